// Round 10
// baseline (447.464 us; speedup 1.0000x reference)
//
#include <hip/hip_runtime.h>
#include <math.h>

#define S_ 2048
#define B_ 2
#define H_ 16
#define E_ 2048
#define QR_ 1536
#define NOPE_ 128
#define ROPE_ 64
#define C_ 512
#define VH_ 128
#define T_ 1024
#define LN1E4 9.210340371976184f
#define SCALE_ 0.07216878364870323f  // 192^-0.5

typedef _Float16 half8 __attribute__((ext_vector_type(8)));
typedef _Float16 half4 __attribute__((ext_vector_type(4)));
typedef __fp16 fp16x2 __attribute__((ext_vector_type(2)));
typedef float floatx4 __attribute__((ext_vector_type(4)));
#define MFMA16(a, b, c) __builtin_amdgcn_mfma_f32_16x16x32_f16(a, b, c, 0, 0, 0)

__device__ __forceinline__ void gload16(const _Float16* g, _Float16* l) {
  __builtin_amdgcn_global_load_lds(
      (__attribute__((address_space(1))) const void*)g,
      (__attribute__((address_space(3))) void*)l, 16, 0, 0);
}

// bijective XCD-chunked swizzle (m204)
__device__ __forceinline__ int xcd_swizzle(int orig, int nwg) {
  int q8 = nwg >> 3, r8 = nwg & 7, xcd = orig & 7, base = orig >> 3;
  return (xcd < r8 ? xcd * (q8 + 1) : r8 * (q8 + 1) + (xcd - r8) * q8) + base;
}

// ------- fused f32 -> f16 conversion for 8 tensors + wkvb split (W1c scaled, W2c) -------
__global__ __launch_bounds__(256) void conv_all(
    const float* __restrict__ q, const float* __restrict__ k,
    const float* __restrict__ wqa, const float* __restrict__ wqb,
    const float* __restrict__ wkva, const float* __restrict__ wo,
    const float* __restrict__ fcc, const float* __restrict__ fcp,
    const float* __restrict__ wkvb,
    _Float16* q16, _Float16* k16, _Float16* wqa16, _Float16* wqb16,
    _Float16* wkva16, _Float16* wo16, _Float16* fcc16, _Float16* fcp16,
    _Float16* W1c, _Float16* W2c)
{
  size_t i = (size_t)blockIdx.x * 256 + threadIdx.x;  // half8-chunk index
  if (i >= 3768320) {
    // wkvb ranges: W1c (scaled) then W2c
    bool isW1 = i < 3899392;
    size_t j = i - (isW1 ? 3768320 : 3899392);
    int cch = j & 63, hd = (int)(j >> 6);
    int hh = hd >> 7, dd = hd & 127;
    const float* src = wkvb + ((size_t)(hh * 256 + (isW1 ? 0 : 128) + dd)) * 512 + cch * 8;
    float sc = isW1 ? SCALE_ : 1.f;
    float4 a = *(const float4*)src;
    float4 b = *(const float4*)(src + 4);
    half8 h = {(_Float16)(a.x * sc), (_Float16)(a.y * sc), (_Float16)(a.z * sc),
               (_Float16)(a.w * sc), (_Float16)(b.x * sc), (_Float16)(b.y * sc),
               (_Float16)(b.z * sc), (_Float16)(b.w * sc)};
    *(half8*)((isW1 ? W1c : W2c) + j * 8) = h;
    return;
  }
  const float* in; _Float16* out; size_t off;
  if      (i < 1048576) { in = q;    out = q16;    off = i; }
  else if (i < 2097152) { in = k;    out = k16;    off = i - 1048576; }
  else if (i < 2490368) { in = wqa;  out = wqa16;  off = i - 2097152; }
  else if (i < 3080192) { in = wqb;  out = wqb16;  off = i - 2490368; }
  else if (i < 3227648) { in = wkva; out = wkva16; off = i - 3080192; }
  else if (i < 3751936) { in = wo;   out = wo16;   off = i - 3227648; }
  else if (i < 3760128) { in = fcc;  out = fcc16;  off = i - 3751936; }
  else                  { in = fcp;  out = fcp16;  off = i - 3760128; }
  float4 a = ((const float4*)in)[2 * off];
  float4 b = ((const float4*)in)[2 * off + 1];
  half8 h = {(_Float16)a.x, (_Float16)a.y, (_Float16)a.z, (_Float16)a.w,
             (_Float16)b.x, (_Float16)b.y, (_Float16)b.z, (_Float16)b.w};
  *(half8*)(out + 8 * off) = h;
}

// ------- f16 MFMA GEMM: global_load_lds + XOR swizzle + DOUBLE-BUFFER counted vmcnt -------
template<bool OUT16, bool NB, bool BIAS, bool TRANSC>
__global__ __launch_bounds__(256) void gemm16(
    const _Float16* __restrict__ A, const _Float16* __restrict__ Bm,
    const float* __restrict__ bias, float* __restrict__ Cf,
    _Float16* __restrict__ Ch, int N, int K, int lda, int ldb, int ldc,
    long sAb, long sAh, long sBb, long sBh, long sCb, long sCh)
{
  __shared__ __align__(16) _Float16 Asl[2][128 * 64];
  __shared__ __align__(16) _Float16 Bsl[2][128 * 64];
  const int z = blockIdx.z, zb = z >> 4, zh = z & 15;
  A  += (size_t)zb * sAb + (size_t)zh * sAh;
  Bm += (size_t)zb * sBb + (size_t)zh * sBh;
  if (OUT16) Ch += (size_t)zb * sCb + (size_t)zh * sCh;
  else       Cf += (size_t)zb * sCb + (size_t)zh * sCh;
  const int gx = gridDim.x;
  const int nwg = gx * gridDim.y;
  const int f = xcd_swizzle(blockIdx.y * gx + blockIdx.x, nwg);
  const int bm = (f / gx) * 128, bn = (f % gx) * 128;
  const int tid = threadIdx.x;
  const int w = tid >> 6, lane = tid & 63, l15 = lane & 15, g = lane >> 4;
  const int wm = (w >> 1) * 64, wn = (w & 1) * 64;
  const int srow = w * 32 + (lane >> 3);
  const int sch  = (lane & 7) ^ (lane >> 3);   // inverse-swizzled global chunk
  floatx4 acc[4][4];
  #pragma unroll
  for (int i = 0; i < 4; ++i)
    #pragma unroll
    for (int j = 0; j < 4; ++j) acc[i][j] = (floatx4){0.f, 0.f, 0.f, 0.f};

  auto STAGE = [&](int buf, int k0) {
    _Float16* al = &Asl[buf][w * 2048];
    _Float16* bl = &Bsl[buf][w * 2048];
    #pragma unroll
    for (int i = 0; i < 4; ++i)
      gload16(A + (size_t)(bm + srow + i * 8) * lda + k0 + sch * 8, al + i * 512);
    #pragma unroll
    for (int i = 0; i < 4; ++i)
      gload16(Bm + (size_t)(bn + srow + i * 8) * ldb + k0 + sch * 8, bl + i * 512);
  };

  STAGE(0, 0);
  int cur = 0;
  const int nIter = K >> 6;
  for (int it = 0; it < nIter; ++it) {
    const bool pf = (it + 1 < nIter);
    if (pf) STAGE(cur ^ 1, (it + 1) << 6);
    if (pf) asm volatile("s_waitcnt vmcnt(8)" ::: "memory");
    else    asm volatile("s_waitcnt vmcnt(0)" ::: "memory");
    __builtin_amdgcn_sched_barrier(0);
    __builtin_amdgcn_s_barrier();
    __builtin_amdgcn_sched_barrier(0);
    #pragma unroll
    for (int kk = 0; kk < 2; ++kk) {
      half8 af[4], bf[4];
      const int sw = ((kk * 4 + g) ^ (l15 & 7)) * 8;
      #pragma unroll
      for (int i = 0; i < 4; ++i) {
        af[i] = *(const half8*)&Asl[cur][(wm + i * 16 + l15) * 64 + sw];
        bf[i] = *(const half8*)&Bsl[cur][(wn + i * 16 + l15) * 64 + sw];
      }
      #pragma unroll
      for (int i = 0; i < 4; ++i)
        #pragma unroll
        for (int j = 0; j < 4; ++j)
          acc[i][j] = MFMA16(af[i], bf[j], acc[i][j]);
    }
    asm volatile("s_waitcnt lgkmcnt(0)" ::: "memory");
    __builtin_amdgcn_sched_barrier(0);
    __builtin_amdgcn_s_barrier();
    __builtin_amdgcn_sched_barrier(0);
    cur ^= 1;
  }

  if (TRANSC) {
    #pragma unroll
    for (int i = 0; i < 4; ++i)
      #pragma unroll
      for (int j = 0; j < 4; ++j) {
        int row = bm + wm + i * 16 + g * 4;
        int col = bn + wn + j * 16 + l15;
        half4 v = {(_Float16)acc[i][j][0], (_Float16)acc[i][j][1],
                   (_Float16)acc[i][j][2], (_Float16)acc[i][j][3]};
        *(half4*)(Ch + (size_t)col * ldc + row) = v;
      }
  } else {
    #pragma unroll
    for (int i = 0; i < 4; ++i)
      #pragma unroll
      for (int j = 0; j < 4; ++j)
        #pragma unroll
        for (int r = 0; r < 4; ++r) {
          int row = bm + wm + i * 16 + g * 4 + r;
          int col = bn + wn + j * 16 + l15;
          if (!NB || col < N) {
            float v = acc[i][j][r];
            if (BIAS) v += bias[col];
            if (OUT16) Ch[(size_t)row * ldc + col] = (_Float16)v;
            else       Cf[(size_t)row * ldc + col] = v;
          }
        }
  }
}

// ---------------- row LayerNorm (templated in/out) ----------------
template<typename TIN, bool OUT16>
__global__ __launch_bounds__(256) void ln_rows(
    const TIN* __restrict__ in, float* __restrict__ outf, _Float16* __restrict__ outh,
    const float* __restrict__ g, const float* __restrict__ bb,
    int L, int ldin, int ldout)
{
  const int row = blockIdx.x;
  const TIN* x = in + (size_t)row * ldin;
  float s = 0.f, s2 = 0.f;
  for (int i = threadIdx.x; i < L; i += 256) {
    float v = (float)x[i]; s += v; s2 += v * v;
  }
  #pragma unroll
  for (int off = 32; off; off >>= 1) {
    s  += __shfl_xor(s, off, 64);
    s2 += __shfl_xor(s2, off, 64);
  }
  __shared__ float rs[4], rs2[4];
  int lane = threadIdx.x & 63, w = threadIdx.x >> 6;
  if (lane == 0) { rs[w] = s; rs2[w] = s2; }
  __syncthreads();
  s  = rs[0] + rs[1] + rs[2] + rs[3];
  s2 = rs2[0] + rs2[1] + rs2[2] + rs2[3];
  float mean = s / L;
  float var = s2 / L - mean * mean;
  float inv = rsqrtf(var + 1e-5f);
  for (int i = threadIdx.x; i < L; i += 256) {
    float v = ((float)x[i] - mean) * inv * g[i] + bb[i];
    if (OUT16) outh[(size_t)row * ldout + i] = (_Float16)v;
    else       outf[(size_t)row * ldout + i] = v;
  }
}

// ------- rope + normalize q_pe in place (f16), fold ps*scale -------
__global__ __launch_bounds__(64) void rope_q16(_Float16* __restrict__ qb,
                                               const float* __restrict__ ps_ptr)
{
  const int idx = blockIdx.x;
  const int h = idx & (H_ - 1);
  const int row = idx >> 4;
  const int s = row & (S_ - 1);
  _Float16* p = qb + (size_t)row * 3072 + h * 192 + NOPE_;
  const int j = threadIdx.x;
  float o1 = 0.f, o2 = 0.f;
  if (j < 32) {
    float invf = expf(-(float)j * (LN1E4 / 32.f));
    float ang = (float)(S_ - 1 + s) * invf;
    float sn, cs; sincosf(ang, &sn, &cs);
    float x1 = (float)p[2 * j], x2 = (float)p[2 * j + 1];
    o1 = x1 * cs - x2 * sn;
    o2 = x1 * sn + x2 * cs;
  }
  float ss = o1 * o1 + o2 * o2;
  #pragma unroll
  for (int off = 32; off; off >>= 1) ss += __shfl_xor(ss, off, 64);
  float inv = ps_ptr[0] * SCALE_ / fmaxf(sqrtf(ss), 1e-12f);
  if (j < 32) {
    p[2 * j]     = (_Float16)(o1 * inv);
    p[2 * j + 1] = (_Float16)(o2 * inv);
  }
}

// ------- rope + normalize k_pe (odd rows) -> keff[b][h][t][128..192] all h -------
__global__ __launch_bounds__(64) void rope_k16(
    const _Float16* __restrict__ kvf16, _Float16* __restrict__ keff)
{
  const int t = blockIdx.x, b = blockIdx.y;
  const int srow = 2 * t + 1;
  const _Float16* p = kvf16 + ((size_t)(b * S_ + srow)) * 576 + C_;
  const int j = threadIdx.x;
  float o1 = 0.f, o2 = 0.f;
  if (j < 32) {
    float invf = expf(-(float)j * (LN1E4 / 32.f));
    float ang = (float)(S_ - 1 + srow) * invf;
    float sn, cs; sincosf(ang, &sn, &cs);
    float x1 = (float)p[2 * j], x2 = (float)p[2 * j + 1];
    o1 = x1 * cs - x2 * sn;
    o2 = x1 * sn + x2 * cs;
  }
  float ss = o1 * o1 + o2 * o2;
  #pragma unroll
  for (int off = 32; off; off >>= 1) ss += __shfl_xor(ss, off, 64);
  float nrm = fmaxf(sqrtf(ss), 1e-12f);
  if (j < 32) {
    _Float16 h1 = (_Float16)(o1 / nrm), h2 = (_Float16)(o2 / nrm);
    #pragma unroll
    for (int h = 0; h < H_; ++h) {
      _Float16* o = keff + ((size_t)((b * H_ + h) * T_) + t) * 192 + NOPE_;
      o[2 * j] = h1; o[2 * j + 1] = h2;
    }
  }
}

// ---------------- sinusoidal PE table (f16) ----------------
__global__ __launch_bounds__(256) void pe16(_Float16* __restrict__ Cpe16)
{
  const int t = blockIdx.x;
  const int i = threadIdx.x;
  float dv = expf(-(float)(2 * i) * (LN1E4 / 512.f));
  float ang = (float)t * dv;
  float sn, cs; sincosf(ang, &sn, &cs);
  Cpe16[(size_t)t * C_ + 2 * i]     = (_Float16)sn;
  Cpe16[(size_t)t * C_ + 2 * i + 1] = (_Float16)cs;
}

// ---------------- gate: pkv16[b][t] = w0*kvn[2t] + w1*kvn[2t+1] (all f16 in) ----------------
__global__ __launch_bounds__(64) void gate_kernel(
    const _Float16* __restrict__ C2, const _Float16* __restrict__ P2,
    const _Float16* __restrict__ kvn16, _Float16* __restrict__ pkv16)
{
  const int t = blockIdx.x, b = blockIdx.y;
  const int j = threadIdx.x;
  const _Float16* c2 = C2 + (size_t)t * 128;
  const _Float16* p0 = P2 + ((size_t)(b * S_ + 2 * t)) * 128;
  const _Float16* p1 = p0 + 128;
  float d0 = (float)c2[j] * (float)p0[j] + (float)c2[j + 64] * (float)p0[j + 64];
  float d1 = (float)c2[j] * (float)p1[j] + (float)c2[j + 64] * (float)p1[j + 64];
  #pragma unroll
  for (int off = 32; off; off >>= 1) {
    d0 += __shfl_xor(d0, off, 64);
    d1 += __shfl_xor(d1, off, 64);
  }
  float w0 = 1.f / (1.f + expf(-d0));
  float w1 = 1.f / (1.f + expf(-d1));
  const _Float16* k0 = kvn16 + ((size_t)(b * S_ + 2 * t)) * C_;
  const _Float16* k1 = k0 + C_;
  _Float16* o = pkv16 + ((size_t)(b * T_ + t)) * C_;
  #pragma unroll
  for (int it = 0; it < 2; ++it) {
    int c = j * 4 + it * 256;
    #pragma unroll
    for (int u = 0; u < 4; ++u)
      o[c + u] = (_Float16)(w0 * (float)k0[c + u] + w1 * (float)k1[c + u]);
  }
}

// ------- flash attention, swapped-QK^T register softmax, T2-swizzled K/V LDS -------
// grid = 1024 flat blocks (XCD-chunk-swizzled), 4 waves x 16 q-rows, 4 blocks/CU.
__global__ __launch_bounds__(256, 4) void attn_flash(
    const _Float16* __restrict__ qb16, const _Float16* __restrict__ keff,
    const _Float16* __restrict__ vT, _Float16* __restrict__ x216)
{
  __shared__ __align__(16) _Float16 K_lds[64 * 192];  // 24 KB, chunk-XOR swizzled
  __shared__ __align__(16) _Float16 V_lds[128 * 64];  // 16 KB, chunk-XOR swizzled
  const int f = xcd_swizzle(blockIdx.x, 1024);
  const int st = f & 31, h = (f >> 5) & 15, b = f >> 9;
  const int tid = threadIdx.x, w = tid >> 6, lane = tid & 63;
  const int l15 = lane & 15, g = lane >> 4, l7 = lane & 7;
  const int rq = b * S_ + st * 64 + w * 16;
  const _Float16* qrow = qb16 + (size_t)(rq + l15) * 3072 + h * 192;
  half8 qB[6];   // B-fragment: lane holds q-row = l15, k-chunk kk*32+g*8
  #pragma unroll
  for (int kk = 0; kk < 6; ++kk) qB[kk] = *(const half8*)(qrow + kk * 32 + g * 8);
  floatx4 O[8];  // O[cc][r] = O[q = g*4+r][d = cc*16+l15]
  #pragma unroll
  for (int i = 0; i < 8; ++i) O[i] = (floatx4){0.f, 0.f, 0.f, 0.f};
  float m = -3e38f, l = 0.f;   // per-lane softmax state for q = l15
  const _Float16* kb = keff + (size_t)(b * H_ + h) * T_ * 192;
  const _Float16* vb = vT   + (size_t)(b * H_ + h) * 128 * T_;

  // staging lane assignments (swizzled LDS slot = data-chunk ^ (row&7))
  int ksrc[6], ksw[6], vsrc[4], vsw[4];
  #pragma unroll
  for (int p = 0; p < 6; ++p) {
    int c = tid + p * 256;
    int r = c / 24, dc = c % 24;
    ksrc[p] = r * 192 + dc * 8;
    ksw[p]  = r * 192 + ((dc ^ (r & 7)) * 8);
  }
  #pragma unroll
  for (int p = 0; p < 4; ++p) {
    int c = tid + p * 256;
    int r = c >> 3, dc = c & 7;
    vsrc[p] = r * T_ + dc * 8;
    vsw[p]  = r * 64 + ((dc ^ (r & 7)) * 8);
  }
  // swizzled read chunk offsets
  int kswr[6], vswr[2];
  #pragma unroll
  for (int kk = 0; kk < 6; ++kk) kswr[kk] = ((kk * 4 + g) ^ l7) * 8;
  #pragma unroll
  for (int kc = 0; kc < 2; ++kc) vswr[kc] = ((kc * 4 + g) ^ l7) * 8;

  half8 kreg[6], vreg[4];
  #pragma unroll
  for (int p = 0; p < 6; ++p) kreg[p] = *(const half8*)(kb + ksrc[p]);
  #pragma unroll
  for (int p = 0; p < 4; ++p) vreg[p] = *(const half8*)(vb + vsrc[p]);
  #pragma unroll
  for (int p = 0; p < 6; ++p) *(half8*)&K_lds[ksw[p]] = kreg[p];
  #pragma unroll
  for (int p = 0; p < 4; ++p) *(half8*)&V_lds[vsw[p]] = vreg[p];
  __syncthreads();

  const int srcA = l15 + ((g & 1) << 5);  // lane of group 2*(g&1)
  const int srcB = srcA + 16;             // lane of group 2*(g&1)+1
  const bool hi = (g >> 1) != 0;

  for (int kt = 0; kt < 16; ++kt) {
    if (kt < 15) {
      const int t1 = (kt + 1) * 64;
      #pragma unroll
      for (int p = 0; p < 6; ++p)
        kreg[p] = *(const half8*)(kb + (size_t)t1 * 192 + ksrc[p]);
      #pragma unroll
      for (int p = 0; p < 4; ++p)
        vreg[p] = *(const half8*)(vb + t1 + vsrc[p]);
    }
    // swapped scores: sc[ct][r] = S[t = ct*16+g*4+r][q = l15]
    floatx4 sc[4];
    #pragma unroll
    for (int i = 0; i < 4; ++i) sc[i] = (floatx4){0.f, 0.f, 0.f, 0.f};
    __builtin_amdgcn_s_setprio(1);
    #pragma unroll
    for (int kk = 0; kk < 6; ++kk)
      #pragma unroll
      for (int ct = 0; ct < 4; ++ct)
        sc[ct] = MFMA16(
            *(const half8*)&K_lds[(ct * 16 + l15) * 192 + kswr[kk]],
            qB[kk], sc[ct]);
    __builtin_amdgcn_s_setprio(0);
    // per-lane (q = l15) online softmax; cross-group reduce = 2 shfls
    float pm = sc[0][0];
    #pragma unroll
    for (int ct = 0; ct < 4; ++ct)
      #pragma unroll
      for (int r = 0; r < 4; ++r) pm = fmaxf(pm, sc[ct][r]);
    pm = fmaxf(pm, __shfl_xor(pm, 16, 64));
    pm = fmaxf(pm, __shfl_xor(pm, 32, 64));
    int ok = pm <= m + 8.f;
    if (!__all(ok)) {
      float mn = fmaxf(m, pm);
      float sf = __expf(m - mn);
      m = mn; l *= sf;
      float sfO[4];
      #pragma unroll
      for (int r = 0; r < 4; ++r) sfO[r] = __shfl(sf, g * 4 + r, 64);
      #pragma unroll
      for (int cc = 0; cc < 8; ++cc) {
        O[cc][0] *= sfO[0]; O[cc][1] *= sfO[1];
        O[cc][2] *= sfO[2]; O[cc][3] *= sfO[3];
      }
    }
    float rs = 0.f;
    #pragma unroll
    for (int ct = 0; ct < 4; ++ct)
      #pragma unroll
      for (int r = 0; r < 4; ++r) {
        float e = __expf(sc[ct][r] - m);
        sc[ct][r] = e; rs += e;
      }
    rs += __shfl_xor(rs, 16, 64);
    rs += __shfl_xor(rs, 32, 64);
    l += rs;
    // pack P to f16 pairs
    unsigned pk[4][2];
    #pragma unroll
    for (int ct = 0; ct < 4; ++ct) {
      union { fp16x2 h; unsigned u; } c0, c1;
      c0.h = __builtin_amdgcn_cvt_pkrtz(sc[ct][0], sc[ct][1]);
      c1.h = __builtin_amdgcn_cvt_pkrtz(sc[ct][2], sc[ct][3]);
      pk[ct][0] = c0.u; pk[ct][1] = c1.u;
    }
    // PV: assemble PA fragment via shfl
    __builtin_amdgcn_s_setprio(1);
    #pragma unroll
    for (int kc = 0; kc < 2; ++kc) {
      unsigned a0 = __shfl((int)pk[2 * kc][0], srcA, 64);
      unsigned b0 = __shfl((int)pk[2 * kc + 1][0], srcA, 64);
      unsigned a1 = __shfl((int)pk[2 * kc][1], srcA, 64);
      unsigned b1 = __shfl((int)pk[2 * kc + 1][1], srcA, 64);
      unsigned a2 = __shfl((int)pk[2 * kc][0], srcB, 64);
      unsigned b2 = __shfl((int)pk[2 * kc + 1][0], srcB, 64);
      unsigned a3 = __shfl((int)pk[2 * kc][1], srcB, 64);
      unsigned b3 = __shfl((int)pk[2 * kc + 1][1], srcB, 64);
      union { unsigned u[4]; half8 h; } pa;
      pa.u[0] = hi ? b0 : a0;
      pa.u[1] = hi ? b1 : a1;
      pa.u[2] = hi ? b2 : a2;
      pa.u[3] = hi ? b3 : a3;
      #pragma unroll
      for (int cc = 0; cc < 8; ++cc)
        O[cc] = MFMA16(pa.h,
            *(const half8*)&V_lds[(cc * 16 + l15) * 64 + vswr[kc]], O[cc]);
    }
    __builtin_amdgcn_s_setprio(0);
    if (kt < 15) {
      __syncthreads();
      #pragma unroll
      for (int p = 0; p < 6; ++p) *(half8*)&K_lds[ksw[p]] = kreg[p];
      #pragma unroll
      for (int p = 0; p < 4; ++p) *(half8*)&V_lds[vsw[p]] = vreg[p];
      __syncthreads();
    }
  }
  float il = 1.f / l;
  float ilO[4];
  #pragma unroll
  for (int r = 0; r < 4; ++r) ilO[r] = __shfl(il, g * 4 + r, 64);
  #pragma unroll
  for (int cc = 0; cc < 8; ++cc)
    #pragma unroll
    for (int r = 0; r < 4; ++r)
      x216[(size_t)(rq + g * 4 + r) * 2048 + h * 128 + cc * 16 + l15] =
          (_Float16)(O[cc][r] * ilO[r]);
}

extern "C" void kernel_launch(void* const* d_in, const int* in_sizes, int n_in,
                              void* d_out, int out_size, void* d_ws, size_t ws_size,
                              hipStream_t stream)
{
  (void)in_sizes; (void)n_in; (void)out_size; (void)ws_size;
  const float* query  = (const float*)d_in[0];
  const float* key    = (const float*)d_in[1];
  const float* wq_a   = (const float*)d_in[3];
  const float* q_ln_g = (const float*)d_in[4];
  const float* q_ln_b = (const float*)d_in[5];
  const float* wq_b   = (const float*)d_in[6];
  const float* wkv_a  = (const float*)d_in[7];
  const float* kv_ln_g= (const float*)d_in[8];
  const float* kv_ln_b= (const float*)d_in[9];
  const float* wkvb   = (const float*)d_in[10];
  const float* wo     = (const float*)d_in[11];
  const float* fc_c_w = (const float*)d_in[12];
  const float* fc_c_b = (const float*)d_in[13];
  const float* fc_p_w = (const float*)d_in[14];
  const float* fc_p_b = (const float*)d_in[15];
  const float* ps     = (const float*)d_in[16];
  float* out = (float*)d_out;

  const int M = B_ * S_; // 4096
  // ---- workspace layout (halves), ~111 MB ----
  _Float16* hws   = (_Float16*)d_ws;
  _Float16* q16   = hws;                      // 8,388,608   (later: x216)
  _Float16* key16 = q16   + (size_t)8388608;  // 8,388,608   (later: keff 6,291,456)
  _Float16* wqa16 = key16 + (size_t)8388608;  // 3,145,728
  _Float16* wqb16 = wqa16 + (size_t)3145728;  // 4,718,592   (later: Cpe16/C2h/P2h)
  _Float16* wkva16= wqb16 + (size_t)4718592;  // 1,179,648   (later: pkv16 1,048,576)
  _Float16* wo16  = wkva16+ (size_t)1179648;  // 4,194,304
  _Float16* ql16  = wo16  + (size_t)4194304;  // 6,291,456   (later: vT 4,194,304)
  _Float16* qb16  = ql16  + (size_t)6291456;  // 12,582,912
  _Float16* kvf16 = qb16  + (size_t)12582912; // 2,359,296
  _Float16* kvn16 = kvf16 + (size_t)2359296;  // 2,097,152
  _Float16* fcc16 = kvn16 + (size_t)2097152;  // 65,536
  _Float16* fcp16 = fcc16 + (size_t)65536;    // 65,536
  _Float16* W1c   = fcp16 + (size_t)65536;    // 1,048,576
  _Float16* W2c   = W1c   + (size_t)1048576;  // 1,048,576
  // aliases
  _Float16* x216  = q16;
  _Float16* keff  = key16;
  _Float16* Cpe16 = wqb16;
  _Float16* C2h   = Cpe16 + (size_t)T_ * C_;
  _Float16* P2h   = C2h + (size_t)T_ * 128;
  _Float16* pkv16 = wkva16;
  _Float16* vT    = ql16;
  float*    qlp   = out;  // d_out as fp32 scratch (dead after LN)

  // 0. all f32->f16 conversions + wkvb split (W1c/W2c non-aliased now)
  conv_all<<<15744, 256, 0, stream>>>(query, key, wq_a, wq_b, wkv_a, wo, fc_c_w, fc_p_w,
                                      wkvb, q16, key16, wqa16, wqb16, wkva16, wo16,
                                      fcc16, fcp16, W1c, W2c);
  // 1. qlp = query @ wq_a^T (fp32 out in d_out)
  gemm16<false,false,false,false><<<dim3(QR_/128, M/128), 256, 0, stream>>>(
      q16, wqa16, nullptr, qlp, nullptr, QR_, E_, E_, E_, QR_, 0,0,0,0,0,0);
  // 2. LN -> ql16
  ln_rows<float,true><<<M, 256, 0, stream>>>(qlp, nullptr, ql16, q_ln_g, q_ln_b,
                                             QR_, QR_, QR_);
  // 3. qb16 = ql16 @ wq_b^T
  gemm16<true,false,false,false><<<dim3(3072/128, M/128), 256, 0, stream>>>(
      ql16, wqb16, nullptr, nullptr, qb16, 3072, QR_, QR_, QR_, 3072, 0,0,0,0,0,0);
  // 4. rope q_pe in place
  rope_q16<<<M * H_, 64, 0, stream>>>(qb16, ps);
  // 5. kvf16 = key @ wkv_a^T (N=576; B-overreads stay inside d_ws)
  gemm16<true,true,false,false><<<dim3(5, M/128), 256, 0, stream>>>(
      key16, wkva16, nullptr, nullptr, kvf16, 576, E_, E_, E_, 576, 0,0,0,0,0,0);
  // 6. kvn16 = LN(kvf16[:, :512])
  ln_rows<_Float16,true><<<M, 256, 0, stream>>>(kvf16, nullptr, kvn16, kv_ln_g, kv_ln_b,
                                                C_, 576, C_);
  // 7. kpe -> keff[...,128:192] (key16 dead)
  rope_k16<<<dim3(T_, B_), 64, 0, stream>>>(kvf16, keff);
  // 8. PE table f16 (wqb16 dead)
  pe16<<<T_, 256, 0, stream>>>(Cpe16);
  // 9. C2h = Cpe16 @ fcc16^T + fc_c_b
  gemm16<true,false,true,false><<<dim3(1, T_/128), 256, 0, stream>>>(
      Cpe16, fcc16, fc_c_b, nullptr, C2h, 128, C_, C_, C_, 128, 0,0,0,0,0,0);
  // 10. P2h = kvn16 @ fcp16^T + fc_p_b
  gemm16<true,false,true,false><<<dim3(1, M/128), 256, 0, stream>>>(
      kvn16, fcp16, fc_p_b, nullptr, P2h, 128, C_, C_, C_, 128, 0,0,0,0,0,0);
  // 11. gate -> pkv16 (wkva16 dead)
  gate_kernel<<<dim3(T_, B_), 64, 0, stream>>>(C2h, P2h, kvn16, pkv16);
  // 12a. khead: keff[b][h][:, 0:128] = pkv[b] @ W1c[h]^T  (z = b*16+h, ql16 dead)
  gemm16<true,false,false,false><<<dim3(1, T_/128, 32), 256, 0, stream>>>(
      pkv16, W1c, nullptr, nullptr, keff, 128, C_, C_, C_, 192,
      (long)T_*C_, 0L, 0L, (long)128*C_, (long)H_*T_*192, (long)T_*192);
  // 12b. vT[b][h] = (pkv[b] @ W2c[h]^T)^T
  gemm16<true,false,false,true><<<dim3(1, T_/128, 32), 256, 0, stream>>>(
      pkv16, W2c, nullptr, nullptr, vT, 128, C_, C_, C_, T_,
      (long)T_*C_, 0L, 0L, (long)128*C_, (long)H_*128*T_, (long)128*T_);
  // 13. flash attention (swizzled K/V LDS) -> x216 (q16 dead)
  attn_flash<<<dim3(1024), 256, 0, stream>>>(qb16, keff, vT, x216);
  // 14. out = x216 @ wo16^T (fp32 out)
  gemm16<false,false,false,false><<<dim3(E_/128, M/128), 256, 0, stream>>>(
      x216, wo16, nullptr, out, nullptr, E_, E_, E_, E_, E_, 0,0,0,0,0,0);
}

// Round 11
// 369.137 us; speedup vs baseline: 1.2122x; 1.2122x over previous
//
#include <hip/hip_runtime.h>
#include <math.h>

#define S_ 2048
#define B_ 2
#define H_ 16
#define E_ 2048
#define QR_ 1536
#define NOPE_ 128
#define ROPE_ 64
#define C_ 512
#define VH_ 128
#define T_ 1024
#define LN1E4 9.210340371976184f
#define SCALE_ 0.07216878364870323f  // 192^-0.5

typedef _Float16 half8 __attribute__((ext_vector_type(8)));
typedef _Float16 half4 __attribute__((ext_vector_type(4)));
typedef __fp16 fp16x2 __attribute__((ext_vector_type(2)));
typedef float floatx4 __attribute__((ext_vector_type(4)));
#define MFMA16(a, b, c) __builtin_amdgcn_mfma_f32_16x16x32_f16(a, b, c, 0, 0, 0)

__device__ __forceinline__ void gload16(const _Float16* g, _Float16* l) {
  __builtin_amdgcn_global_load_lds(
      (__attribute__((address_space(1))) const void*)g,
      (__attribute__((address_space(3))) void*)l, 16, 0, 0);
}

// bijective XCD-chunked swizzle (m204)
__device__ __forceinline__ int xcd_swizzle(int orig, int nwg) {
  int q8 = nwg >> 3, r8 = nwg & 7, xcd = orig & 7, base = orig >> 3;
  return (xcd < r8 ? xcd * (q8 + 1) : r8 * (q8 + 1) + (xcd - r8) * q8) + base;
}

// ------- fused f32 -> f16 conversion for 8 tensors + wkvb split (W1c scaled, W2c) -------
__global__ __launch_bounds__(256) void conv_all(
    const float* __restrict__ q, const float* __restrict__ k,
    const float* __restrict__ wqa, const float* __restrict__ wqb,
    const float* __restrict__ wkva, const float* __restrict__ wo,
    const float* __restrict__ fcc, const float* __restrict__ fcp,
    const float* __restrict__ wkvb,
    _Float16* q16, _Float16* k16, _Float16* wqa16, _Float16* wqb16,
    _Float16* wkva16, _Float16* wo16, _Float16* fcc16, _Float16* fcp16,
    _Float16* W1c, _Float16* W2c)
{
  size_t i = (size_t)blockIdx.x * 256 + threadIdx.x;  // half8-chunk index
  if (i >= 3768320) {
    // wkvb ranges: W1c (scaled) then W2c
    bool isW1 = i < 3899392;
    size_t j = i - (isW1 ? 3768320 : 3899392);
    int cch = j & 63, hd = (int)(j >> 6);
    int hh = hd >> 7, dd = hd & 127;
    const float* src = wkvb + ((size_t)(hh * 256 + (isW1 ? 0 : 128) + dd)) * 512 + cch * 8;
    float sc = isW1 ? SCALE_ : 1.f;
    float4 a = *(const float4*)src;
    float4 b = *(const float4*)(src + 4);
    half8 h = {(_Float16)(a.x * sc), (_Float16)(a.y * sc), (_Float16)(a.z * sc),
               (_Float16)(a.w * sc), (_Float16)(b.x * sc), (_Float16)(b.y * sc),
               (_Float16)(b.z * sc), (_Float16)(b.w * sc)};
    *(half8*)((isW1 ? W1c : W2c) + j * 8) = h;
    return;
  }
  const float* in; _Float16* out; size_t off;
  if      (i < 1048576) { in = q;    out = q16;    off = i; }
  else if (i < 2097152) { in = k;    out = k16;    off = i - 1048576; }
  else if (i < 2490368) { in = wqa;  out = wqa16;  off = i - 2097152; }
  else if (i < 3080192) { in = wqb;  out = wqb16;  off = i - 2490368; }
  else if (i < 3227648) { in = wkva; out = wkva16; off = i - 3080192; }
  else if (i < 3751936) { in = wo;   out = wo16;   off = i - 3227648; }
  else if (i < 3760128) { in = fcc;  out = fcc16;  off = i - 3751936; }
  else                  { in = fcp;  out = fcp16;  off = i - 3760128; }
  float4 a = ((const float4*)in)[2 * off];
  float4 b = ((const float4*)in)[2 * off + 1];
  half8 h = {(_Float16)a.x, (_Float16)a.y, (_Float16)a.z, (_Float16)a.w,
             (_Float16)b.x, (_Float16)b.y, (_Float16)b.z, (_Float16)b.w};
  *(half8*)(out + 8 * off) = h;
}

// ------- f16 MFMA GEMM: global_load_lds + XOR swizzle + DOUBLE-BUFFER counted vmcnt -------
template<bool OUT16, bool NB, bool BIAS, bool TRANSC>
__global__ __launch_bounds__(256) void gemm16(
    const _Float16* __restrict__ A, const _Float16* __restrict__ Bm,
    const float* __restrict__ bias, float* __restrict__ Cf,
    _Float16* __restrict__ Ch, int N, int K, int lda, int ldb, int ldc,
    long sAb, long sAh, long sBb, long sBh, long sCb, long sCh)
{
  __shared__ __align__(16) _Float16 Asl[2][128 * 64];
  __shared__ __align__(16) _Float16 Bsl[2][128 * 64];
  const int z = blockIdx.z, zb = z >> 4, zh = z & 15;
  A  += (size_t)zb * sAb + (size_t)zh * sAh;
  Bm += (size_t)zb * sBb + (size_t)zh * sBh;
  if (OUT16) Ch += (size_t)zb * sCb + (size_t)zh * sCh;
  else       Cf += (size_t)zb * sCb + (size_t)zh * sCh;
  const int gx = gridDim.x;
  const int nwg = gx * gridDim.y;
  const int f = xcd_swizzle(blockIdx.y * gx + blockIdx.x, nwg);
  const int bm = (f / gx) * 128, bn = (f % gx) * 128;
  const int tid = threadIdx.x;
  const int w = tid >> 6, lane = tid & 63, l15 = lane & 15, g = lane >> 4;
  const int wm = (w >> 1) * 64, wn = (w & 1) * 64;
  const int srow = w * 32 + (lane >> 3);
  const int sch  = (lane & 7) ^ (lane >> 3);   // inverse-swizzled global chunk
  floatx4 acc[4][4];
  #pragma unroll
  for (int i = 0; i < 4; ++i)
    #pragma unroll
    for (int j = 0; j < 4; ++j) acc[i][j] = (floatx4){0.f, 0.f, 0.f, 0.f};

  auto STAGE = [&](int buf, int k0) {
    _Float16* al = &Asl[buf][w * 2048];
    _Float16* bl = &Bsl[buf][w * 2048];
    #pragma unroll
    for (int i = 0; i < 4; ++i)
      gload16(A + (size_t)(bm + srow + i * 8) * lda + k0 + sch * 8, al + i * 512);
    #pragma unroll
    for (int i = 0; i < 4; ++i)
      gload16(Bm + (size_t)(bn + srow + i * 8) * ldb + k0 + sch * 8, bl + i * 512);
  };

  STAGE(0, 0);
  int cur = 0;
  const int nIter = K >> 6;
  for (int it = 0; it < nIter; ++it) {
    const bool pf = (it + 1 < nIter);
    if (pf) STAGE(cur ^ 1, (it + 1) << 6);
    if (pf) asm volatile("s_waitcnt vmcnt(8)" ::: "memory");
    else    asm volatile("s_waitcnt vmcnt(0)" ::: "memory");
    __builtin_amdgcn_sched_barrier(0);
    __builtin_amdgcn_s_barrier();
    __builtin_amdgcn_sched_barrier(0);
    #pragma unroll
    for (int kk = 0; kk < 2; ++kk) {
      half8 af[4], bf[4];
      const int sw = ((kk * 4 + g) ^ (l15 & 7)) * 8;
      #pragma unroll
      for (int i = 0; i < 4; ++i) {
        af[i] = *(const half8*)&Asl[cur][(wm + i * 16 + l15) * 64 + sw];
        bf[i] = *(const half8*)&Bsl[cur][(wn + i * 16 + l15) * 64 + sw];
      }
      #pragma unroll
      for (int i = 0; i < 4; ++i)
        #pragma unroll
        for (int j = 0; j < 4; ++j)
          acc[i][j] = MFMA16(af[i], bf[j], acc[i][j]);
    }
    asm volatile("s_waitcnt lgkmcnt(0)" ::: "memory");
    __builtin_amdgcn_sched_barrier(0);
    __builtin_amdgcn_s_barrier();
    __builtin_amdgcn_sched_barrier(0);
    cur ^= 1;
  }

  if (TRANSC) {
    #pragma unroll
    for (int i = 0; i < 4; ++i)
      #pragma unroll
      for (int j = 0; j < 4; ++j) {
        int row = bm + wm + i * 16 + g * 4;
        int col = bn + wn + j * 16 + l15;
        half4 v = {(_Float16)acc[i][j][0], (_Float16)acc[i][j][1],
                   (_Float16)acc[i][j][2], (_Float16)acc[i][j][3]};
        *(half4*)(Ch + (size_t)col * ldc + row) = v;
      }
  } else {
    #pragma unroll
    for (int i = 0; i < 4; ++i)
      #pragma unroll
      for (int j = 0; j < 4; ++j)
        #pragma unroll
        for (int r = 0; r < 4; ++r) {
          int row = bm + wm + i * 16 + g * 4 + r;
          int col = bn + wn + j * 16 + l15;
          if (!NB || col < N) {
            float v = acc[i][j][r];
            if (BIAS) v += bias[col];
            if (OUT16) Ch[(size_t)row * ldc + col] = (_Float16)v;
            else       Cf[(size_t)row * ldc + col] = v;
          }
        }
  }
}

// ---------------- row LayerNorm (templated in/out) ----------------
template<typename TIN, bool OUT16>
__global__ __launch_bounds__(256) void ln_rows(
    const TIN* __restrict__ in, float* __restrict__ outf, _Float16* __restrict__ outh,
    const float* __restrict__ g, const float* __restrict__ bb,
    int L, int ldin, int ldout)
{
  const int row = blockIdx.x;
  const TIN* x = in + (size_t)row * ldin;
  float s = 0.f, s2 = 0.f;
  for (int i = threadIdx.x; i < L; i += 256) {
    float v = (float)x[i]; s += v; s2 += v * v;
  }
  #pragma unroll
  for (int off = 32; off; off >>= 1) {
    s  += __shfl_xor(s, off, 64);
    s2 += __shfl_xor(s2, off, 64);
  }
  __shared__ float rs[4], rs2[4];
  int lane = threadIdx.x & 63, w = threadIdx.x >> 6;
  if (lane == 0) { rs[w] = s; rs2[w] = s2; }
  __syncthreads();
  s  = rs[0] + rs[1] + rs[2] + rs[3];
  s2 = rs2[0] + rs2[1] + rs2[2] + rs2[3];
  float mean = s / L;
  float var = s2 / L - mean * mean;
  float inv = rsqrtf(var + 1e-5f);
  for (int i = threadIdx.x; i < L; i += 256) {
    float v = ((float)x[i] - mean) * inv * g[i] + bb[i];
    if (OUT16) outh[(size_t)row * ldout + i] = (_Float16)v;
    else       outf[(size_t)row * ldout + i] = v;
  }
}

// ------- rope + normalize q_pe in place (f16), fold ps*scale -------
__global__ __launch_bounds__(64) void rope_q16(_Float16* __restrict__ qb,
                                               const float* __restrict__ ps_ptr)
{
  const int idx = blockIdx.x;
  const int h = idx & (H_ - 1);
  const int row = idx >> 4;
  const int s = row & (S_ - 1);
  _Float16* p = qb + (size_t)row * 3072 + h * 192 + NOPE_;
  const int j = threadIdx.x;
  float o1 = 0.f, o2 = 0.f;
  if (j < 32) {
    float invf = expf(-(float)j * (LN1E4 / 32.f));
    float ang = (float)(S_ - 1 + s) * invf;
    float sn, cs; sincosf(ang, &sn, &cs);
    float x1 = (float)p[2 * j], x2 = (float)p[2 * j + 1];
    o1 = x1 * cs - x2 * sn;
    o2 = x1 * sn + x2 * cs;
  }
  float ss = o1 * o1 + o2 * o2;
  #pragma unroll
  for (int off = 32; off; off >>= 1) ss += __shfl_xor(ss, off, 64);
  float inv = ps_ptr[0] * SCALE_ / fmaxf(sqrtf(ss), 1e-12f);
  if (j < 32) {
    p[2 * j]     = (_Float16)(o1 * inv);
    p[2 * j + 1] = (_Float16)(o2 * inv);
  }
}

// ------- rope + normalize k_pe (odd rows) -> keff[b][h][t][128..192] all h -------
__global__ __launch_bounds__(64) void rope_k16(
    const _Float16* __restrict__ kvf16, _Float16* __restrict__ keff)
{
  const int t = blockIdx.x, b = blockIdx.y;
  const int srow = 2 * t + 1;
  const _Float16* p = kvf16 + ((size_t)(b * S_ + srow)) * 576 + C_;
  const int j = threadIdx.x;
  float o1 = 0.f, o2 = 0.f;
  if (j < 32) {
    float invf = expf(-(float)j * (LN1E4 / 32.f));
    float ang = (float)(S_ - 1 + srow) * invf;
    float sn, cs; sincosf(ang, &sn, &cs);
    float x1 = (float)p[2 * j], x2 = (float)p[2 * j + 1];
    o1 = x1 * cs - x2 * sn;
    o2 = x1 * sn + x2 * cs;
  }
  float ss = o1 * o1 + o2 * o2;
  #pragma unroll
  for (int off = 32; off; off >>= 1) ss += __shfl_xor(ss, off, 64);
  float nrm = fmaxf(sqrtf(ss), 1e-12f);
  if (j < 32) {
    _Float16 h1 = (_Float16)(o1 / nrm), h2 = (_Float16)(o2 / nrm);
    #pragma unroll
    for (int h = 0; h < H_; ++h) {
      _Float16* o = keff + ((size_t)((b * H_ + h) * T_) + t) * 192 + NOPE_;
      o[2 * j] = h1; o[2 * j + 1] = h2;
    }
  }
}

// ---------------- sinusoidal PE table (f16) ----------------
__global__ __launch_bounds__(256) void pe16(_Float16* __restrict__ Cpe16)
{
  const int t = blockIdx.x;
  const int i = threadIdx.x;
  float dv = expf(-(float)(2 * i) * (LN1E4 / 512.f));
  float ang = (float)t * dv;
  float sn, cs; sincosf(ang, &sn, &cs);
  Cpe16[(size_t)t * C_ + 2 * i]     = (_Float16)sn;
  Cpe16[(size_t)t * C_ + 2 * i + 1] = (_Float16)cs;
}

// ---------------- gate: pkv16[b][t] = w0*kvn[2t] + w1*kvn[2t+1] (all f16 in) ----------------
__global__ __launch_bounds__(64) void gate_kernel(
    const _Float16* __restrict__ C2, const _Float16* __restrict__ P2,
    const _Float16* __restrict__ kvn16, _Float16* __restrict__ pkv16)
{
  const int t = blockIdx.x, b = blockIdx.y;
  const int j = threadIdx.x;
  const _Float16* c2 = C2 + (size_t)t * 128;
  const _Float16* p0 = P2 + ((size_t)(b * S_ + 2 * t)) * 128;
  const _Float16* p1 = p0 + 128;
  float d0 = (float)c2[j] * (float)p0[j] + (float)c2[j + 64] * (float)p0[j + 64];
  float d1 = (float)c2[j] * (float)p1[j] + (float)c2[j + 64] * (float)p1[j + 64];
  #pragma unroll
  for (int off = 32; off; off >>= 1) {
    d0 += __shfl_xor(d0, off, 64);
    d1 += __shfl_xor(d1, off, 64);
  }
  float w0 = 1.f / (1.f + expf(-d0));
  float w1 = 1.f / (1.f + expf(-d1));
  const _Float16* k0 = kvn16 + ((size_t)(b * S_ + 2 * t)) * C_;
  const _Float16* k1 = k0 + C_;
  _Float16* o = pkv16 + ((size_t)(b * T_ + t)) * C_;
  #pragma unroll
  for (int it = 0; it < 2; ++it) {
    int c = j * 4 + it * 256;
    #pragma unroll
    for (int u = 0; u < 4; ++u)
      o[c + u] = (_Float16)(w0 * (float)k0[c + u] + w1 * (float)k1[c + u]);
  }
}

// ------- flash attention, swapped-QK^T register softmax, T2-swizzled K/V LDS -------
// grid = 1024 flat blocks (XCD-chunk-swizzled), 4 waves x 16 q-rows.
__global__ __launch_bounds__(256, 3) void attn_flash(
    const _Float16* __restrict__ qb16, const _Float16* __restrict__ keff,
    const _Float16* __restrict__ vT, _Float16* __restrict__ x216)
{
  __shared__ __align__(16) _Float16 K_lds[64 * 192];  // 24 KB, chunk-XOR swizzled
  __shared__ __align__(16) _Float16 V_lds[128 * 64];  // 16 KB, chunk-XOR swizzled
  const int f = xcd_swizzle(blockIdx.x, 1024);
  const int st = f & 31, h = (f >> 5) & 15, b = f >> 9;
  const int tid = threadIdx.x, w = tid >> 6, lane = tid & 63;
  const int l15 = lane & 15, g = lane >> 4, l7 = lane & 7;
  const int rq = b * S_ + st * 64 + w * 16;
  const _Float16* qrow = qb16 + (size_t)(rq + l15) * 3072 + h * 192;
  half8 qB[6];   // B-fragment: lane holds q-row = l15, k-chunk kk*32+g*8
  #pragma unroll
  for (int kk = 0; kk < 6; ++kk) qB[kk] = *(const half8*)(qrow + kk * 32 + g * 8);
  floatx4 O[8];  // O[cc][r] = O[q = g*4+r][d = cc*16+l15]
  #pragma unroll
  for (int i = 0; i < 8; ++i) O[i] = (floatx4){0.f, 0.f, 0.f, 0.f};
  float m = -3e38f, l = 0.f;   // per-lane softmax state for q = l15
  const _Float16* kb = keff + (size_t)(b * H_ + h) * T_ * 192;
  const _Float16* vb = vT   + (size_t)(b * H_ + h) * 128 * T_;

  // staging lane assignments (swizzled LDS slot = data-chunk ^ (row&7))
  int ksrc[6], ksw[6], vsrc[4], vsw[4];
  #pragma unroll
  for (int p = 0; p < 6; ++p) {
    int c = tid + p * 256;
    int r = c / 24, dc = c % 24;
    ksrc[p] = r * 192 + dc * 8;
    ksw[p]  = r * 192 + ((dc ^ (r & 7)) * 8);
  }
  #pragma unroll
  for (int p = 0; p < 4; ++p) {
    int c = tid + p * 256;
    int r = c >> 3, dc = c & 7;
    vsrc[p] = r * T_ + dc * 8;
    vsw[p]  = r * 64 + ((dc ^ (r & 7)) * 8);
  }
  // swizzled read chunk offsets
  int kswr[6], vswr[2];
  #pragma unroll
  for (int kk = 0; kk < 6; ++kk) kswr[kk] = ((kk * 4 + g) ^ l7) * 8;
  #pragma unroll
  for (int kc = 0; kc < 2; ++kc) vswr[kc] = ((kc * 4 + g) ^ l7) * 8;

  half8 kreg[6], vreg[4];
  #pragma unroll
  for (int p = 0; p < 6; ++p) kreg[p] = *(const half8*)(kb + ksrc[p]);
  #pragma unroll
  for (int p = 0; p < 4; ++p) vreg[p] = *(const half8*)(vb + vsrc[p]);
  #pragma unroll
  for (int p = 0; p < 6; ++p) *(half8*)&K_lds[ksw[p]] = kreg[p];
  #pragma unroll
  for (int p = 0; p < 4; ++p) *(half8*)&V_lds[vsw[p]] = vreg[p];
  __syncthreads();

  const int srcA = l15 + ((g & 1) << 5);  // lane of group 2*(g&1)
  const int srcB = srcA + 16;             // lane of group 2*(g&1)+1
  const bool hi = (g >> 1) != 0;

  for (int kt = 0; kt < 16; ++kt) {
    if (kt < 15) {
      const int t1 = (kt + 1) * 64;
      #pragma unroll
      for (int p = 0; p < 6; ++p)
        kreg[p] = *(const half8*)(kb + (size_t)t1 * 192 + ksrc[p]);
      #pragma unroll
      for (int p = 0; p < 4; ++p)
        vreg[p] = *(const half8*)(vb + t1 + vsrc[p]);
    }
    // swapped scores: sc[ct][r] = S[t = ct*16+g*4+r][q = l15]
    floatx4 sc[4];
    #pragma unroll
    for (int i = 0; i < 4; ++i) sc[i] = (floatx4){0.f, 0.f, 0.f, 0.f};
    __builtin_amdgcn_s_setprio(1);
    #pragma unroll
    for (int kk = 0; kk < 6; ++kk)
      #pragma unroll
      for (int ct = 0; ct < 4; ++ct)
        sc[ct] = MFMA16(
            *(const half8*)&K_lds[(ct * 16 + l15) * 192 + kswr[kk]],
            qB[kk], sc[ct]);
    __builtin_amdgcn_s_setprio(0);
    // per-lane (q = l15) online softmax; cross-group reduce = 2 shfls
    float pm = sc[0][0];
    #pragma unroll
    for (int ct = 0; ct < 4; ++ct)
      #pragma unroll
      for (int r = 0; r < 4; ++r) pm = fmaxf(pm, sc[ct][r]);
    pm = fmaxf(pm, __shfl_xor(pm, 16, 64));
    pm = fmaxf(pm, __shfl_xor(pm, 32, 64));
    int ok = pm <= m + 8.f;
    if (!__all(ok)) {
      float mn = fmaxf(m, pm);
      float sf = __expf(m - mn);
      m = mn; l *= sf;
      float sfO[4];
      #pragma unroll
      for (int r = 0; r < 4; ++r) sfO[r] = __shfl(sf, g * 4 + r, 64);
      #pragma unroll
      for (int cc = 0; cc < 8; ++cc) {
        O[cc][0] *= sfO[0]; O[cc][1] *= sfO[1];
        O[cc][2] *= sfO[2]; O[cc][3] *= sfO[3];
      }
    }
    float rs = 0.f;
    #pragma unroll
    for (int ct = 0; ct < 4; ++ct)
      #pragma unroll
      for (int r = 0; r < 4; ++r) {
        float e = __expf(sc[ct][r] - m);
        sc[ct][r] = e; rs += e;
      }
    rs += __shfl_xor(rs, 16, 64);
    rs += __shfl_xor(rs, 32, 64);
    l += rs;
    // pack P to f16 pairs
    unsigned pk[4][2];
    #pragma unroll
    for (int ct = 0; ct < 4; ++ct) {
      union { fp16x2 h; unsigned u; } c0, c1;
      c0.h = __builtin_amdgcn_cvt_pkrtz(sc[ct][0], sc[ct][1]);
      c1.h = __builtin_amdgcn_cvt_pkrtz(sc[ct][2], sc[ct][3]);
      pk[ct][0] = c0.u; pk[ct][1] = c1.u;
    }
    // PV: assemble PA fragment via shfl
    __builtin_amdgcn_s_setprio(1);
    #pragma unroll
    for (int kc = 0; kc < 2; ++kc) {
      unsigned a0 = __shfl((int)pk[2 * kc][0], srcA, 64);
      unsigned b0 = __shfl((int)pk[2 * kc + 1][0], srcA, 64);
      unsigned a1 = __shfl((int)pk[2 * kc][1], srcA, 64);
      unsigned b1 = __shfl((int)pk[2 * kc + 1][1], srcA, 64);
      unsigned a2 = __shfl((int)pk[2 * kc][0], srcB, 64);
      unsigned b2 = __shfl((int)pk[2 * kc + 1][0], srcB, 64);
      unsigned a3 = __shfl((int)pk[2 * kc][1], srcB, 64);
      unsigned b3 = __shfl((int)pk[2 * kc + 1][1], srcB, 64);
      union { unsigned u[4]; half8 h; } pa;
      pa.u[0] = hi ? b0 : a0;
      pa.u[1] = hi ? b1 : a1;
      pa.u[2] = hi ? b2 : a2;
      pa.u[3] = hi ? b3 : a3;
      #pragma unroll
      for (int cc = 0; cc < 8; ++cc)
        O[cc] = MFMA16(pa.h,
            *(const half8*)&V_lds[(cc * 16 + l15) * 64 + vswr[kc]], O[cc]);
    }
    __builtin_amdgcn_s_setprio(0);
    if (kt < 15) {
      __syncthreads();
      #pragma unroll
      for (int p = 0; p < 6; ++p) *(half8*)&K_lds[ksw[p]] = kreg[p];
      #pragma unroll
      for (int p = 0; p < 4; ++p) *(half8*)&V_lds[vsw[p]] = vreg[p];
      __syncthreads();
    }
  }
  float il = 1.f / l;
  float ilO[4];
  #pragma unroll
  for (int r = 0; r < 4; ++r) ilO[r] = __shfl(il, g * 4 + r, 64);
  #pragma unroll
  for (int cc = 0; cc < 8; ++cc)
    #pragma unroll
    for (int r = 0; r < 4; ++r)
      x216[(size_t)(rq + g * 4 + r) * 2048 + h * 128 + cc * 16 + l15] =
          (_Float16)(O[cc][r] * ilO[r]);
}

extern "C" void kernel_launch(void* const* d_in, const int* in_sizes, int n_in,
                              void* d_out, int out_size, void* d_ws, size_t ws_size,
                              hipStream_t stream)
{
  (void)in_sizes; (void)n_in; (void)out_size; (void)ws_size;
  const float* query  = (const float*)d_in[0];
  const float* key    = (const float*)d_in[1];
  const float* wq_a   = (const float*)d_in[3];
  const float* q_ln_g = (const float*)d_in[4];
  const float* q_ln_b = (const float*)d_in[5];
  const float* wq_b   = (const float*)d_in[6];
  const float* wkv_a  = (const float*)d_in[7];
  const float* kv_ln_g= (const float*)d_in[8];
  const float* kv_ln_b= (const float*)d_in[9];
  const float* wkvb   = (const float*)d_in[10];
  const float* wo     = (const float*)d_in[11];
  const float* fc_c_w = (const float*)d_in[12];
  const float* fc_c_b = (const float*)d_in[13];
  const float* fc_p_w = (const float*)d_in[14];
  const float* fc_p_b = (const float*)d_in[15];
  const float* ps     = (const float*)d_in[16];
  float* out = (float*)d_out;

  const int M = B_ * S_; // 4096
  // ---- workspace layout (halves), ~111 MB ----
  _Float16* hws   = (_Float16*)d_ws;
  _Float16* q16   = hws;                      // 8,388,608   (later: x216)
  _Float16* key16 = q16   + (size_t)8388608;  // 8,388,608   (later: keff 6,291,456)
  _Float16* wqa16 = key16 + (size_t)8388608;  // 3,145,728
  _Float16* wqb16 = wqa16 + (size_t)3145728;  // 4,718,592   (later: Cpe16/C2h/P2h)
  _Float16* wkva16= wqb16 + (size_t)4718592;  // 1,179,648   (later: pkv16 1,048,576)
  _Float16* wo16  = wkva16+ (size_t)1179648;  // 4,194,304
  _Float16* ql16  = wo16  + (size_t)4194304;  // 6,291,456   (later: vT 4,194,304)
  _Float16* qb16  = ql16  + (size_t)6291456;  // 12,582,912
  _Float16* kvf16 = qb16  + (size_t)12582912; // 2,359,296
  _Float16* kvn16 = kvf16 + (size_t)2359296;  // 2,097,152
  _Float16* fcc16 = kvn16 + (size_t)2097152;  // 65,536
  _Float16* fcp16 = fcc16 + (size_t)65536;    // 65,536
  _Float16* W1c   = fcp16 + (size_t)65536;    // 1,048,576
  _Float16* W2c   = W1c   + (size_t)1048576;  // 1,048,576
  // aliases
  _Float16* x216  = q16;
  _Float16* keff  = key16;
  _Float16* Cpe16 = wqb16;
  _Float16* C2h   = Cpe16 + (size_t)T_ * C_;
  _Float16* P2h   = C2h + (size_t)T_ * 128;
  _Float16* pkv16 = wkva16;
  _Float16* vT    = ql16;
  float*    qlp   = out;  // d_out as fp32 scratch (dead after LN)

  // 0. all f32->f16 conversions + wkvb split
  conv_all<<<15744, 256, 0, stream>>>(query, key, wq_a, wq_b, wkv_a, wo, fc_c_w, fc_p_w,
                                      wkvb, q16, key16, wqa16, wqb16, wkva16, wo16,
                                      fcc16, fcp16, W1c, W2c);
  // 1. qlp = query @ wq_a^T (fp32 out in d_out)
  gemm16<false,false,false,false><<<dim3(QR_/128, M/128), 256, 0, stream>>>(
      q16, wqa16, nullptr, qlp, nullptr, QR_, E_, E_, E_, QR_, 0,0,0,0,0,0);
  // 2. LN -> ql16
  ln_rows<float,true><<<M, 256, 0, stream>>>(qlp, nullptr, ql16, q_ln_g, q_ln_b,
                                             QR_, QR_, QR_);
  // 3. qb16 = ql16 @ wq_b^T
  gemm16<true,false,false,false><<<dim3(3072/128, M/128), 256, 0, stream>>>(
      ql16, wqb16, nullptr, nullptr, qb16, 3072, QR_, QR_, QR_, 3072, 0,0,0,0,0,0);
  // 4. rope q_pe in place
  rope_q16<<<M * H_, 64, 0, stream>>>(qb16, ps);
  // 5. kvf16 = key @ wkv_a^T (N=576; B-overreads stay inside d_ws)
  gemm16<true,true,false,false><<<dim3(5, M/128), 256, 0, stream>>>(
      key16, wkva16, nullptr, nullptr, kvf16, 576, E_, E_, E_, 576, 0,0,0,0,0,0);
  // 6. kvn16 = LN(kvf16[:, :512])
  ln_rows<_Float16,true><<<M, 256, 0, stream>>>(kvf16, nullptr, kvn16, kv_ln_g, kv_ln_b,
                                                C_, 576, C_);
  // 7. kpe -> keff[...,128:192] (key16 dead)
  rope_k16<<<dim3(T_, B_), 64, 0, stream>>>(kvf16, keff);
  // 8. PE table f16 (wqb16 dead)
  pe16<<<T_, 256, 0, stream>>>(Cpe16);
  // 9. C2h = Cpe16 @ fcc16^T + fc_c_b
  gemm16<true,false,true,false><<<dim3(1, T_/128), 256, 0, stream>>>(
      Cpe16, fcc16, fc_c_b, nullptr, C2h, 128, C_, C_, C_, 128, 0,0,0,0,0,0);
  // 10. P2h = kvn16 @ fcp16^T + fc_p_b
  gemm16<true,false,true,false><<<dim3(1, M/128), 256, 0, stream>>>(
      kvn16, fcp16, fc_p_b, nullptr, P2h, 128, C_, C_, C_, 128, 0,0,0,0,0,0);
  // 11. gate -> pkv16 (wkva16 dead)
  gate_kernel<<<dim3(T_, B_), 64, 0, stream>>>(C2h, P2h, kvn16, pkv16);
  // 12a. khead: keff[b][h][:, 0:128] = pkv[b] @ W1c[h]^T  (z = b*16+h, ql16 dead)
  gemm16<true,false,false,false><<<dim3(1, T_/128, 32), 256, 0, stream>>>(
      pkv16, W1c, nullptr, nullptr, keff, 128, C_, C_, C_, 192,
      (long)T_*C_, 0L, 0L, (long)128*C_, (long)H_*T_*192, (long)T_*192);
  // 12b. vT[b][h] = (pkv[b] @ W2c[h]^T)^T
  gemm16<true,false,false,true><<<dim3(1, T_/128, 32), 256, 0, stream>>>(
      pkv16, W2c, nullptr, nullptr, vT, 128, C_, C_, C_, T_,
      (long)T_*C_, 0L, 0L, (long)128*C_, (long)H_*128*T_, (long)128*T_);
  // 13. flash attention (swizzled K/V LDS) -> x216 (q16 dead)
  attn_flash<<<dim3(1024), 256, 0, stream>>>(qb16, keff, vT, x216);
  // 14. out = x216 @ wo16^T (fp32 out)
  gemm16<false,false,false,false><<<dim3(E_/128, M/128), 256, 0, stream>>>(
      x216, wo16, nullptr, out, nullptr, E_, E_, E_, E_, E_, 0,0,0,0,0,0);
}

// Round 12
// 350.419 us; speedup vs baseline: 1.2769x; 1.0534x over previous
//
#include <hip/hip_runtime.h>
#include <math.h>

#define S_ 2048
#define B_ 2
#define H_ 16
#define E_ 2048
#define QR_ 1536
#define NOPE_ 128
#define ROPE_ 64
#define C_ 512
#define VH_ 128
#define T_ 1024
#define LN1E4 9.210340371976184f
#define SCALE_ 0.07216878364870323f  // 192^-0.5

typedef _Float16 half8 __attribute__((ext_vector_type(8)));
typedef _Float16 half4 __attribute__((ext_vector_type(4)));
typedef __fp16 fp16x2 __attribute__((ext_vector_type(2)));
typedef float floatx4 __attribute__((ext_vector_type(4)));
#define MFMA16(a, b, c) __builtin_amdgcn_mfma_f32_16x16x32_f16(a, b, c, 0, 0, 0)

__device__ __forceinline__ void gload16(const _Float16* g, _Float16* l) {
  __builtin_amdgcn_global_load_lds(
      (__attribute__((address_space(1))) const void*)g,
      (__attribute__((address_space(3))) void*)l, 16, 0, 0);
}

// bijective XCD-chunked swizzle (m204)
__device__ __forceinline__ int xcd_swizzle(int orig, int nwg) {
  int q8 = nwg >> 3, r8 = nwg & 7, xcd = orig & 7, base = orig >> 3;
  return (xcd < r8 ? xcd * (q8 + 1) : r8 * (q8 + 1) + (xcd - r8) * q8) + base;
}

// ------- fused f32 -> f16 conversion for 8 tensors + wkvb split (W1c scaled, W2c) -------
__global__ __launch_bounds__(256) void conv_all(
    const float* __restrict__ q, const float* __restrict__ k,
    const float* __restrict__ wqa, const float* __restrict__ wqb,
    const float* __restrict__ wkva, const float* __restrict__ wo,
    const float* __restrict__ fcc, const float* __restrict__ fcp,
    const float* __restrict__ wkvb,
    _Float16* q16, _Float16* k16, _Float16* wqa16, _Float16* wqb16,
    _Float16* wkva16, _Float16* wo16, _Float16* fcc16, _Float16* fcp16,
    _Float16* W1c, _Float16* W2c)
{
  size_t i = (size_t)blockIdx.x * 256 + threadIdx.x;  // half8-chunk index
  if (i >= 3768320) {
    // wkvb ranges: W1c (scaled) then W2c
    bool isW1 = i < 3899392;
    size_t j = i - (isW1 ? 3768320 : 3899392);
    int cch = j & 63, hd = (int)(j >> 6);
    int hh = hd >> 7, dd = hd & 127;
    const float* src = wkvb + ((size_t)(hh * 256 + (isW1 ? 0 : 128) + dd)) * 512 + cch * 8;
    float sc = isW1 ? SCALE_ : 1.f;
    float4 a = *(const float4*)src;
    float4 b = *(const float4*)(src + 4);
    half8 h = {(_Float16)(a.x * sc), (_Float16)(a.y * sc), (_Float16)(a.z * sc),
               (_Float16)(a.w * sc), (_Float16)(b.x * sc), (_Float16)(b.y * sc),
               (_Float16)(b.z * sc), (_Float16)(b.w * sc)};
    *(half8*)((isW1 ? W1c : W2c) + j * 8) = h;
    return;
  }
  const float* in; _Float16* out; size_t off;
  if      (i < 1048576) { in = q;    out = q16;    off = i; }
  else if (i < 2097152) { in = k;    out = k16;    off = i - 1048576; }
  else if (i < 2490368) { in = wqa;  out = wqa16;  off = i - 2097152; }
  else if (i < 3080192) { in = wqb;  out = wqb16;  off = i - 2490368; }
  else if (i < 3227648) { in = wkva; out = wkva16; off = i - 3080192; }
  else if (i < 3751936) { in = wo;   out = wo16;   off = i - 3227648; }
  else if (i < 3760128) { in = fcc;  out = fcc16;  off = i - 3751936; }
  else                  { in = fcp;  out = fcp16;  off = i - 3760128; }
  float4 a = ((const float4*)in)[2 * off];
  float4 b = ((const float4*)in)[2 * off + 1];
  half8 h = {(_Float16)a.x, (_Float16)a.y, (_Float16)a.z, (_Float16)a.w,
             (_Float16)b.x, (_Float16)b.y, (_Float16)b.z, (_Float16)b.w};
  *(half8*)(out + 8 * off) = h;
}

// ------- f16 MFMA GEMM: global_load_lds + XOR swizzle + DOUBLE-BUFFER counted vmcnt -------
// BIAS mode (only used by the merged C2/P2 GEMM, N=256): col<128 -> bias, else bias2.
template<bool OUT16, bool NB, bool BIAS, bool TRANSC>
__global__ __launch_bounds__(256) void gemm16(
    const _Float16* __restrict__ A, const _Float16* __restrict__ Bm,
    const float* __restrict__ bias, const float* __restrict__ bias2,
    float* __restrict__ Cf, _Float16* __restrict__ Ch,
    int N, int K, int lda, int ldb, int ldc,
    long sAb, long sAh, long sBb, long sBh, long sCb, long sCh)
{
  __shared__ __align__(16) _Float16 Asl[2][128 * 64];
  __shared__ __align__(16) _Float16 Bsl[2][128 * 64];
  const int z = blockIdx.z, zb = z >> 4, zh = z & 15;
  A  += (size_t)zb * sAb + (size_t)zh * sAh;
  Bm += (size_t)zb * sBb + (size_t)zh * sBh;
  if (OUT16) Ch += (size_t)zb * sCb + (size_t)zh * sCh;
  else       Cf += (size_t)zb * sCb + (size_t)zh * sCh;
  const int gx = gridDim.x;
  const int nwg = gx * gridDim.y;
  const int f = xcd_swizzle(blockIdx.y * gx + blockIdx.x, nwg);
  const int bm = (f / gx) * 128, bn = (f % gx) * 128;
  const int tid = threadIdx.x;
  const int w = tid >> 6, lane = tid & 63, l15 = lane & 15, g = lane >> 4;
  const int wm = (w >> 1) * 64, wn = (w & 1) * 64;
  const int srow = w * 32 + (lane >> 3);
  const int sch  = (lane & 7) ^ (lane >> 3);   // inverse-swizzled global chunk
  floatx4 acc[4][4];
  #pragma unroll
  for (int i = 0; i < 4; ++i)
    #pragma unroll
    for (int j = 0; j < 4; ++j) acc[i][j] = (floatx4){0.f, 0.f, 0.f, 0.f};

  auto STAGE = [&](int buf, int k0) {
    _Float16* al = &Asl[buf][w * 2048];
    _Float16* bl = &Bsl[buf][w * 2048];
    #pragma unroll
    for (int i = 0; i < 4; ++i)
      gload16(A + (size_t)(bm + srow + i * 8) * lda + k0 + sch * 8, al + i * 512);
    #pragma unroll
    for (int i = 0; i < 4; ++i)
      gload16(Bm + (size_t)(bn + srow + i * 8) * ldb + k0 + sch * 8, bl + i * 512);
  };

  STAGE(0, 0);
  int cur = 0;
  const int nIter = K >> 6;
  for (int it = 0; it < nIter; ++it) {
    const bool pf = (it + 1 < nIter);
    if (pf) STAGE(cur ^ 1, (it + 1) << 6);
    if (pf) asm volatile("s_waitcnt vmcnt(8)" ::: "memory");
    else    asm volatile("s_waitcnt vmcnt(0)" ::: "memory");
    __builtin_amdgcn_sched_barrier(0);
    __builtin_amdgcn_s_barrier();
    __builtin_amdgcn_sched_barrier(0);
    #pragma unroll
    for (int kk = 0; kk < 2; ++kk) {
      half8 af[4], bf[4];
      const int sw = ((kk * 4 + g) ^ (l15 & 7)) * 8;
      #pragma unroll
      for (int i = 0; i < 4; ++i) {
        af[i] = *(const half8*)&Asl[cur][(wm + i * 16 + l15) * 64 + sw];
        bf[i] = *(const half8*)&Bsl[cur][(wn + i * 16 + l15) * 64 + sw];
      }
      #pragma unroll
      for (int i = 0; i < 4; ++i)
        #pragma unroll
        for (int j = 0; j < 4; ++j)
          acc[i][j] = MFMA16(af[i], bf[j], acc[i][j]);
    }
    asm volatile("s_waitcnt lgkmcnt(0)" ::: "memory");
    __builtin_amdgcn_sched_barrier(0);
    __builtin_amdgcn_s_barrier();
    __builtin_amdgcn_sched_barrier(0);
    cur ^= 1;
  }

  if (TRANSC) {
    #pragma unroll
    for (int i = 0; i < 4; ++i)
      #pragma unroll
      for (int j = 0; j < 4; ++j) {
        int row = bm + wm + i * 16 + g * 4;
        int col = bn + wn + j * 16 + l15;
        half4 v = {(_Float16)acc[i][j][0], (_Float16)acc[i][j][1],
                   (_Float16)acc[i][j][2], (_Float16)acc[i][j][3]};
        *(half4*)(Ch + (size_t)col * ldc + row) = v;
      }
  } else {
    #pragma unroll
    for (int i = 0; i < 4; ++i)
      #pragma unroll
      for (int j = 0; j < 4; ++j)
        #pragma unroll
        for (int r = 0; r < 4; ++r) {
          int row = bm + wm + i * 16 + g * 4 + r;
          int col = bn + wn + j * 16 + l15;
          if (!NB || col < N) {
            float v = acc[i][j][r];
            if (BIAS) v += (col < 128) ? bias[col] : bias2[col - 128];
            if (OUT16) Ch[(size_t)row * ldc + col] = (_Float16)v;
            else       Cf[(size_t)row * ldc + col] = v;
          }
        }
  }
}

// ---------------- row LayerNorm (templated in/out) ----------------
template<typename TIN, bool OUT16>
__global__ __launch_bounds__(256) void ln_rows(
    const TIN* __restrict__ in, float* __restrict__ outf, _Float16* __restrict__ outh,
    const float* __restrict__ g, const float* __restrict__ bb,
    int L, int ldin, int ldout)
{
  const int row = blockIdx.x;
  const TIN* x = in + (size_t)row * ldin;
  float s = 0.f, s2 = 0.f;
  for (int i = threadIdx.x; i < L; i += 256) {
    float v = (float)x[i]; s += v; s2 += v * v;
  }
  #pragma unroll
  for (int off = 32; off; off >>= 1) {
    s  += __shfl_xor(s, off, 64);
    s2 += __shfl_xor(s2, off, 64);
  }
  __shared__ float rs[4], rs2[4];
  int lane = threadIdx.x & 63, w = threadIdx.x >> 6;
  if (lane == 0) { rs[w] = s; rs2[w] = s2; }
  __syncthreads();
  s  = rs[0] + rs[1] + rs[2] + rs[3];
  s2 = rs2[0] + rs2[1] + rs2[2] + rs2[3];
  float mean = s / L;
  float var = s2 / L - mean * mean;
  float inv = rsqrtf(var + 1e-5f);
  for (int i = threadIdx.x; i < L; i += 256) {
    float v = ((float)x[i] - mean) * inv * g[i] + bb[i];
    if (OUT16) outh[(size_t)row * ldout + i] = (_Float16)v;
    else       outf[(size_t)row * ldout + i] = v;
  }
}

// ------- rope + normalize q_pe in place (f16): block = row, wave handles 4 heads -------
__global__ __launch_bounds__(256) void rope_q16(_Float16* __restrict__ qb,
                                                const float* __restrict__ ps_ptr)
{
  const int row = blockIdx.x;
  const int s = row & (S_ - 1);
  const int lane = threadIdx.x & 63, w = threadIdx.x >> 6;
  float sn = 0.f, cs = 0.f;
  if (lane < 32) {
    float invf = expf(-(float)lane * (LN1E4 / 32.f));
    float ang = (float)(S_ - 1 + s) * invf;
    sincosf(ang, &sn, &cs);
  }
  const float psc = ps_ptr[0] * SCALE_;
  #pragma unroll
  for (int hh = 0; hh < 4; ++hh) {
    const int h = w + hh * 4;
    _Float16* p = qb + (size_t)row * 3072 + h * 192 + NOPE_;
    float o1 = 0.f, o2 = 0.f;
    if (lane < 32) {
      float x1 = (float)p[2 * lane], x2 = (float)p[2 * lane + 1];
      o1 = x1 * cs - x2 * sn;
      o2 = x1 * sn + x2 * cs;
    }
    float ss = o1 * o1 + o2 * o2;
    #pragma unroll
    for (int off = 32; off; off >>= 1) ss += __shfl_xor(ss, off, 64);
    float inv = psc / fmaxf(sqrtf(ss), 1e-12f);
    if (lane < 32) {
      p[2 * lane]     = (_Float16)(o1 * inv);
      p[2 * lane + 1] = (_Float16)(o2 * inv);
    }
  }
}

// ------- rope + normalize k_pe (odd rows) -> keff[b][h][t][128..192] all h -------
__global__ __launch_bounds__(64) void rope_k16(
    const _Float16* __restrict__ kvf16, _Float16* __restrict__ keff)
{
  const int t = blockIdx.x, b = blockIdx.y;
  const int srow = 2 * t + 1;
  const _Float16* p = kvf16 + ((size_t)(b * S_ + srow)) * 576 + C_;
  const int j = threadIdx.x;
  float o1 = 0.f, o2 = 0.f;
  if (j < 32) {
    float invf = expf(-(float)j * (LN1E4 / 32.f));
    float ang = (float)(S_ - 1 + srow) * invf;
    float sn, cs; sincosf(ang, &sn, &cs);
    float x1 = (float)p[2 * j], x2 = (float)p[2 * j + 1];
    o1 = x1 * cs - x2 * sn;
    o2 = x1 * sn + x2 * cs;
  }
  float ss = o1 * o1 + o2 * o2;
  #pragma unroll
  for (int off = 32; off; off >>= 1) ss += __shfl_xor(ss, off, 64);
  float nrm = fmaxf(sqrtf(ss), 1e-12f);
  if (j < 32) {
    _Float16 h1 = (_Float16)(o1 / nrm), h2 = (_Float16)(o2 / nrm);
    #pragma unroll
    for (int h = 0; h < H_; ++h) {
      _Float16* o = keff + ((size_t)((b * H_ + h) * T_) + t) * 192 + NOPE_;
      o[2 * j] = h1; o[2 * j + 1] = h2;
    }
  }
}

// ---------------- sinusoidal PE table (f16) ----------------
__global__ __launch_bounds__(256) void pe16(_Float16* __restrict__ Cpe16)
{
  const int t = blockIdx.x;
  const int i = threadIdx.x;
  float dv = expf(-(float)(2 * i) * (LN1E4 / 512.f));
  float ang = (float)t * dv;
  float sn, cs; sincosf(ang, &sn, &cs);
  Cpe16[(size_t)t * C_ + 2 * i]     = (_Float16)sn;
  Cpe16[(size_t)t * C_ + 2 * i + 1] = (_Float16)cs;
}

// ------- gate: pkv16[b][t] = w0*kvn[2t] + w1*kvn[2t+1]; C2/P2 read from merged Ccat -------
// Ccat rows: 0..1023 = [C2h | *], 1024..5119 = [* | P2h] (ld 256)
__global__ __launch_bounds__(64) void gate_kernel(
    const _Float16* __restrict__ Ccat, const _Float16* __restrict__ kvn16,
    _Float16* __restrict__ pkv16)
{
  const int t = blockIdx.x, b = blockIdx.y;
  const int j = threadIdx.x;
  const _Float16* c2 = Ccat + (size_t)t * 256;
  const _Float16* p0 = Ccat + (size_t)(1024 + b * S_ + 2 * t) * 256 + 128;
  const _Float16* p1 = p0 + 256;
  float d0 = (float)c2[j] * (float)p0[j] + (float)c2[j + 64] * (float)p0[j + 64];
  float d1 = (float)c2[j] * (float)p1[j] + (float)c2[j + 64] * (float)p1[j + 64];
  #pragma unroll
  for (int off = 32; off; off >>= 1) {
    d0 += __shfl_xor(d0, off, 64);
    d1 += __shfl_xor(d1, off, 64);
  }
  float w0 = 1.f / (1.f + expf(-d0));
  float w1 = 1.f / (1.f + expf(-d1));
  const _Float16* k0 = kvn16 + ((size_t)(b * S_ + 2 * t)) * C_;
  const _Float16* k1 = k0 + C_;
  _Float16* o = pkv16 + ((size_t)(b * T_ + t)) * C_;
  #pragma unroll
  for (int it = 0; it < 2; ++it) {
    int c = j * 4 + it * 256;
    half4 a = *(const half4*)(k0 + c);
    half4 bb = *(const half4*)(k1 + c);
    half4 r;
    #pragma unroll
    for (int u = 0; u < 4; ++u)
      r[u] = (_Float16)(w0 * (float)a[u] + w1 * (float)bb[u]);
    *(half4*)(o + c) = r;
  }
}

// ------- flash attention, swapped-QK^T register softmax, T2-swizzled K/V LDS -------
__global__ __launch_bounds__(256, 3) void attn_flash(
    const _Float16* __restrict__ qb16, const _Float16* __restrict__ keff,
    const _Float16* __restrict__ vT, _Float16* __restrict__ x216)
{
  __shared__ __align__(16) _Float16 K_lds[64 * 192];  // 24 KB, chunk-XOR swizzled
  __shared__ __align__(16) _Float16 V_lds[128 * 64];  // 16 KB, chunk-XOR swizzled
  const int f = xcd_swizzle(blockIdx.x, 1024);
  const int st = f & 31, h = (f >> 5) & 15, b = f >> 9;
  const int tid = threadIdx.x, w = tid >> 6, lane = tid & 63;
  const int l15 = lane & 15, g = lane >> 4, l7 = lane & 7;
  const int rq = b * S_ + st * 64 + w * 16;
  const _Float16* qrow = qb16 + (size_t)(rq + l15) * 3072 + h * 192;
  half8 qB[6];   // B-fragment: lane holds q-row = l15, k-chunk kk*32+g*8
  #pragma unroll
  for (int kk = 0; kk < 6; ++kk) qB[kk] = *(const half8*)(qrow + kk * 32 + g * 8);
  floatx4 O[8];  // O[cc][r] = O[q = g*4+r][d = cc*16+l15]
  #pragma unroll
  for (int i = 0; i < 8; ++i) O[i] = (floatx4){0.f, 0.f, 0.f, 0.f};
  float m = -3e38f, l = 0.f;   // per-lane softmax state for q = l15
  const _Float16* kb = keff + (size_t)(b * H_ + h) * T_ * 192;
  const _Float16* vb = vT   + (size_t)(b * H_ + h) * 128 * T_;

  // staging lane assignments (swizzled LDS slot = data-chunk ^ (row&7))
  int ksrc[6], ksw[6], vsrc[4], vsw[4];
  #pragma unroll
  for (int p = 0; p < 6; ++p) {
    int c = tid + p * 256;
    int r = c / 24, dc = c % 24;
    ksrc[p] = r * 192 + dc * 8;
    ksw[p]  = r * 192 + ((dc ^ (r & 7)) * 8);
  }
  #pragma unroll
  for (int p = 0; p < 4; ++p) {
    int c = tid + p * 256;
    int r = c >> 3, dc = c & 7;
    vsrc[p] = r * T_ + dc * 8;
    vsw[p]  = r * 64 + ((dc ^ (r & 7)) * 8);
  }
  // swizzled read chunk offsets
  int kswr[6], vswr[2];
  #pragma unroll
  for (int kk = 0; kk < 6; ++kk) kswr[kk] = ((kk * 4 + g) ^ l7) * 8;
  #pragma unroll
  for (int kc = 0; kc < 2; ++kc) vswr[kc] = ((kc * 4 + g) ^ l7) * 8;

  half8 kreg[6], vreg[4];
  #pragma unroll
  for (int p = 0; p < 6; ++p) kreg[p] = *(const half8*)(kb + ksrc[p]);
  #pragma unroll
  for (int p = 0; p < 4; ++p) vreg[p] = *(const half8*)(vb + vsrc[p]);
  #pragma unroll
  for (int p = 0; p < 6; ++p) *(half8*)&K_lds[ksw[p]] = kreg[p];
  #pragma unroll
  for (int p = 0; p < 4; ++p) *(half8*)&V_lds[vsw[p]] = vreg[p];
  __syncthreads();

  const int srcA = l15 + ((g & 1) << 5);  // lane of group 2*(g&1)
  const int srcB = srcA + 16;             // lane of group 2*(g&1)+1
  const bool hi = (g >> 1) != 0;

  for (int kt = 0; kt < 16; ++kt) {
    if (kt < 15) {
      const int t1 = (kt + 1) * 64;
      #pragma unroll
      for (int p = 0; p < 6; ++p)
        kreg[p] = *(const half8*)(kb + (size_t)t1 * 192 + ksrc[p]);
      #pragma unroll
      for (int p = 0; p < 4; ++p)
        vreg[p] = *(const half8*)(vb + t1 + vsrc[p]);
    }
    // swapped scores: sc[ct][r] = S[t = ct*16+g*4+r][q = l15]
    floatx4 sc[4];
    #pragma unroll
    for (int i = 0; i < 4; ++i) sc[i] = (floatx4){0.f, 0.f, 0.f, 0.f};
    __builtin_amdgcn_s_setprio(1);
    #pragma unroll
    for (int kk = 0; kk < 6; ++kk)
      #pragma unroll
      for (int ct = 0; ct < 4; ++ct)
        sc[ct] = MFMA16(
            *(const half8*)&K_lds[(ct * 16 + l15) * 192 + kswr[kk]],
            qB[kk], sc[ct]);
    __builtin_amdgcn_s_setprio(0);
    // per-lane (q = l15) online softmax; cross-group reduce = 2 shfls
    float pm = sc[0][0];
    #pragma unroll
    for (int ct = 0; ct < 4; ++ct)
      #pragma unroll
      for (int r = 0; r < 4; ++r) pm = fmaxf(pm, sc[ct][r]);
    pm = fmaxf(pm, __shfl_xor(pm, 16, 64));
    pm = fmaxf(pm, __shfl_xor(pm, 32, 64));
    int ok = pm <= m + 8.f;
    if (!__all(ok)) {
      float mn = fmaxf(m, pm);
      float sf = __expf(m - mn);
      m = mn; l *= sf;
      float sfO[4];
      #pragma unroll
      for (int r = 0; r < 4; ++r) sfO[r] = __shfl(sf, g * 4 + r, 64);
      #pragma unroll
      for (int cc = 0; cc < 8; ++cc) {
        O[cc][0] *= sfO[0]; O[cc][1] *= sfO[1];
        O[cc][2] *= sfO[2]; O[cc][3] *= sfO[3];
      }
    }
    float rs = 0.f;
    #pragma unroll
    for (int ct = 0; ct < 4; ++ct)
      #pragma unroll
      for (int r = 0; r < 4; ++r) {
        float e = __expf(sc[ct][r] - m);
        sc[ct][r] = e; rs += e;
      }
    rs += __shfl_xor(rs, 16, 64);
    rs += __shfl_xor(rs, 32, 64);
    l += rs;
    // pack P to f16 pairs
    unsigned pk[4][2];
    #pragma unroll
    for (int ct = 0; ct < 4; ++ct) {
      union { fp16x2 h; unsigned u; } c0, c1;
      c0.h = __builtin_amdgcn_cvt_pkrtz(sc[ct][0], sc[ct][1]);
      c1.h = __builtin_amdgcn_cvt_pkrtz(sc[ct][2], sc[ct][3]);
      pk[ct][0] = c0.u; pk[ct][1] = c1.u;
    }
    // PV: assemble PA fragment via shfl
    __builtin_amdgcn_s_setprio(1);
    #pragma unroll
    for (int kc = 0; kc < 2; ++kc) {
      unsigned a0 = __shfl((int)pk[2 * kc][0], srcA, 64);
      unsigned b0 = __shfl((int)pk[2 * kc + 1][0], srcA, 64);
      unsigned a1 = __shfl((int)pk[2 * kc][1], srcA, 64);
      unsigned b1 = __shfl((int)pk[2 * kc + 1][1], srcA, 64);
      unsigned a2 = __shfl((int)pk[2 * kc][0], srcB, 64);
      unsigned b2 = __shfl((int)pk[2 * kc + 1][0], srcB, 64);
      unsigned a3 = __shfl((int)pk[2 * kc][1], srcB, 64);
      unsigned b3 = __shfl((int)pk[2 * kc + 1][1], srcB, 64);
      union { unsigned u[4]; half8 h; } pa;
      pa.u[0] = hi ? b0 : a0;
      pa.u[1] = hi ? b1 : a1;
      pa.u[2] = hi ? b2 : a2;
      pa.u[3] = hi ? b3 : a3;
      #pragma unroll
      for (int cc = 0; cc < 8; ++cc)
        O[cc] = MFMA16(pa.h,
            *(const half8*)&V_lds[(cc * 16 + l15) * 64 + vswr[kc]], O[cc]);
    }
    __builtin_amdgcn_s_setprio(0);
    if (kt < 15) {
      __syncthreads();
      #pragma unroll
      for (int p = 0; p < 6; ++p) *(half8*)&K_lds[ksw[p]] = kreg[p];
      #pragma unroll
      for (int p = 0; p < 4; ++p) *(half8*)&V_lds[vsw[p]] = vreg[p];
      __syncthreads();
    }
  }
  float il = 1.f / l;
  float ilO[4];
  #pragma unroll
  for (int r = 0; r < 4; ++r) ilO[r] = __shfl(il, g * 4 + r, 64);
  #pragma unroll
  for (int cc = 0; cc < 8; ++cc)
    #pragma unroll
    for (int r = 0; r < 4; ++r)
      x216[(size_t)(rq + g * 4 + r) * 2048 + h * 128 + cc * 16 + l15] =
          (_Float16)(O[cc][r] * ilO[r]);
}

extern "C" void kernel_launch(void* const* d_in, const int* in_sizes, int n_in,
                              void* d_out, int out_size, void* d_ws, size_t ws_size,
                              hipStream_t stream)
{
  (void)in_sizes; (void)n_in; (void)out_size; (void)ws_size;
  const float* query  = (const float*)d_in[0];
  const float* key    = (const float*)d_in[1];
  const float* wq_a   = (const float*)d_in[3];
  const float* q_ln_g = (const float*)d_in[4];
  const float* q_ln_b = (const float*)d_in[5];
  const float* wq_b   = (const float*)d_in[6];
  const float* wkv_a  = (const float*)d_in[7];
  const float* kv_ln_g= (const float*)d_in[8];
  const float* kv_ln_b= (const float*)d_in[9];
  const float* wkvb   = (const float*)d_in[10];
  const float* wo     = (const float*)d_in[11];
  const float* fc_c_w = (const float*)d_in[12];
  const float* fc_c_b = (const float*)d_in[13];
  const float* fc_p_w = (const float*)d_in[14];
  const float* fc_p_b = (const float*)d_in[15];
  const float* ps     = (const float*)d_in[16];
  float* out = (float*)d_out;

  const int M = B_ * S_; // 4096
  // ---- workspace layout (halves), ~111 MB ----
  _Float16* hws   = (_Float16*)d_ws;
  _Float16* q16   = hws;                      // 8,388,608   (later: x216)
  _Float16* key16 = q16   + (size_t)8388608;  // 8,388,608   (later: keff 6,291,456)
  _Float16* wqa16 = key16 + (size_t)8388608;  // 3,145,728
  _Float16* wqb16 = wqa16 + (size_t)3145728;  // 4,718,592   (later: Ccat 1,310,720)
  _Float16* wkva16= wqb16 + (size_t)4718592;  // 1,179,648   (later: pkv16 1,048,576)
  _Float16* wo16  = wkva16+ (size_t)1179648;  // 4,194,304
  _Float16* ql16  = wo16  + (size_t)4194304;  // 6,291,456   (later: vT 4,194,304)
  _Float16* qb16  = ql16  + (size_t)6291456;  // 12,582,912
  _Float16* kvf16 = qb16  + (size_t)12582912; // 2,359,296   (tail reused by Cpe16)
  _Float16* kvn16 = kvf16 + (size_t)2359296;  // 2,097,152
  _Float16* fcc16 = kvn16 + (size_t)2097152;  // 65,536  (fcc||fcp adjacent = merged B)
  _Float16* fcp16 = fcc16 + (size_t)65536;    // 65,536
  _Float16* W1c   = fcp16 + (size_t)65536;    // 1,048,576
  _Float16* W2c   = W1c   + (size_t)1048576;  // 1,048,576
  // aliases
  _Float16* x216  = q16;
  _Float16* keff  = key16;
  _Float16* Cpe16 = kvn16 - (size_t)524288;   // kvf tail (dead); Acat = [Cpe16; kvn16]
  _Float16* Ccat  = wqb16;                    // 5120 x 256 merged C2|P2 (wqb dead)
  _Float16* pkv16 = wkva16;
  _Float16* vT    = ql16;
  float*    qlp   = out;  // d_out as fp32 scratch (dead after LN)

  // 0. all f32->f16 conversions + wkvb split
  conv_all<<<15744, 256, 0, stream>>>(query, key, wq_a, wq_b, wkv_a, wo, fc_c_w, fc_p_w,
                                      wkvb, q16, key16, wqa16, wqb16, wkva16, wo16,
                                      fcc16, fcp16, W1c, W2c);
  // 1. qlp = query @ wq_a^T (fp32 out in d_out)
  gemm16<false,false,false,false><<<dim3(QR_/128, M/128), 256, 0, stream>>>(
      q16, wqa16, nullptr, nullptr, qlp, nullptr, QR_, E_, E_, E_, QR_, 0,0,0,0,0,0);
  // 2. LN -> ql16
  ln_rows<float,true><<<M, 256, 0, stream>>>(qlp, nullptr, ql16, q_ln_g, q_ln_b,
                                             QR_, QR_, QR_);
  // 3. qb16 = ql16 @ wq_b^T
  gemm16<true,false,false,false><<<dim3(3072/128, M/128), 256, 0, stream>>>(
      ql16, wqb16, nullptr, nullptr, nullptr, qb16, 3072, QR_, QR_, QR_, 3072, 0,0,0,0,0,0);
  // 4. rope q_pe in place (block = row)
  rope_q16<<<M, 256, 0, stream>>>(qb16, ps);
  // 5. kvf16 = key @ wkv_a^T (N=576; B-overreads stay inside d_ws)
  gemm16<true,true,false,false><<<dim3(5, M/128), 256, 0, stream>>>(
      key16, wkva16, nullptr, nullptr, nullptr, kvf16, 576, E_, E_, E_, 576, 0,0,0,0,0,0);
  // 6. kvn16 = LN(kvf16[:, :512])
  ln_rows<_Float16,true><<<M, 256, 0, stream>>>(kvf16, nullptr, kvn16, kv_ln_g, kv_ln_b,
                                                C_, 576, C_);
  // 7. kpe -> keff[...,128:192] (key16 dead)
  rope_k16<<<dim3(T_, B_), 64, 0, stream>>>(kvf16, keff);
  // 8. PE table f16 into kvf tail (kvf dead after step 7)
  pe16<<<T_, 256, 0, stream>>>(Cpe16);
  // 9. merged: Ccat = [Cpe16;kvn16] @ [fcc;fcp]^T + [fc_c_b|fc_p_b]  (M=5120, N=256)
  gemm16<true,false,true,false><<<dim3(2, 5120/128), 256, 0, stream>>>(
      Cpe16, fcc16, fc_c_b, fc_p_b, nullptr, Ccat, 256, C_, C_, C_, 256, 0,0,0,0,0,0);
  // 10. gate -> pkv16 (wkva16 dead)
  gate_kernel<<<dim3(T_, B_), 64, 0, stream>>>(Ccat, kvn16, pkv16);
  // 11a. khead: keff[b][h][:, 0:128] = pkv[b] @ W1c[h]^T  (z = b*16+h, ql16 dead)
  gemm16<true,false,false,false><<<dim3(1, T_/128, 32), 256, 0, stream>>>(
      pkv16, W1c, nullptr, nullptr, nullptr, keff, 128, C_, C_, C_, 192,
      (long)T_*C_, 0L, 0L, (long)128*C_, (long)H_*T_*192, (long)T_*192);
  // 11b. vT[b][h] = (pkv[b] @ W2c[h]^T)^T
  gemm16<true,false,false,true><<<dim3(1, T_/128, 32), 256, 0, stream>>>(
      pkv16, W2c, nullptr, nullptr, nullptr, vT, 128, C_, C_, C_, T_,
      (long)T_*C_, 0L, 0L, (long)128*C_, (long)H_*128*T_, (long)128*T_);
  // 12. flash attention (swizzled K/V LDS) -> x216 (q16 dead)
  attn_flash<<<dim3(1024), 256, 0, stream>>>(qb16, keff, vT, x216);
  // 13. out = x216 @ wo16^T (fp32 out)
  gemm16<false,false,false,false><<<dim3(E_/128, M/128), 256, 0, stream>>>(
      x216, wo16, nullptr, nullptr, out, nullptr, E_, E_, E_, E_, E_, 0,0,0,0,0,0);
}

// Round 13
// 345.152 us; speedup vs baseline: 1.2964x; 1.0153x over previous
//
#include <hip/hip_runtime.h>
#include <math.h>

#define S_ 2048
#define B_ 2
#define H_ 16
#define E_ 2048
#define QR_ 1536
#define NOPE_ 128
#define ROPE_ 64
#define C_ 512
#define VH_ 128
#define T_ 1024
#define LN1E4 9.210340371976184f
#define SCALE_ 0.07216878364870323f  // 192^-0.5

typedef _Float16 half8 __attribute__((ext_vector_type(8)));
typedef _Float16 half4 __attribute__((ext_vector_type(4)));
typedef __fp16 fp16x2 __attribute__((ext_vector_type(2)));
typedef float floatx4 __attribute__((ext_vector_type(4)));
#define MFMA16(a, b, c) __builtin_amdgcn_mfma_f32_16x16x32_f16(a, b, c, 0, 0, 0)

__device__ __forceinline__ void gload16(const _Float16* g, _Float16* l) {
  __builtin_amdgcn_global_load_lds(
      (__attribute__((address_space(1))) const void*)g,
      (__attribute__((address_space(3))) void*)l, 16, 0, 0);
}

// bijective XCD-chunked swizzle (m204)
__device__ __forceinline__ int xcd_swizzle(int orig, int nwg) {
  int q8 = nwg >> 3, r8 = nwg & 7, xcd = orig & 7, base = orig >> 3;
  return (xcd < r8 ? xcd * (q8 + 1) : r8 * (q8 + 1) + (xcd - r8) * q8) + base;
}

// ------- fused f32 -> f16 conversion for 8 tensors + wkvb split (W1c scaled, W2c) -------
__global__ __launch_bounds__(256) void conv_all(
    const float* __restrict__ q, const float* __restrict__ k,
    const float* __restrict__ wqa, const float* __restrict__ wqb,
    const float* __restrict__ wkva, const float* __restrict__ wo,
    const float* __restrict__ fcc, const float* __restrict__ fcp,
    const float* __restrict__ wkvb,
    _Float16* q16, _Float16* k16, _Float16* wqa16, _Float16* wqb16,
    _Float16* wkva16, _Float16* wo16, _Float16* fcc16, _Float16* fcp16,
    _Float16* W1c, _Float16* W2c)
{
  size_t i = (size_t)blockIdx.x * 256 + threadIdx.x;  // half8-chunk index
  if (i >= 3768320) {
    // wkvb ranges: W1c (scaled) then W2c
    bool isW1 = i < 3899392;
    size_t j = i - (isW1 ? 3768320 : 3899392);
    int cch = j & 63, hd = (int)(j >> 6);
    int hh = hd >> 7, dd = hd & 127;
    const float* src = wkvb + ((size_t)(hh * 256 + (isW1 ? 0 : 128) + dd)) * 512 + cch * 8;
    float sc = isW1 ? SCALE_ : 1.f;
    float4 a = *(const float4*)src;
    float4 b = *(const float4*)(src + 4);
    half8 h = {(_Float16)(a.x * sc), (_Float16)(a.y * sc), (_Float16)(a.z * sc),
               (_Float16)(a.w * sc), (_Float16)(b.x * sc), (_Float16)(b.y * sc),
               (_Float16)(b.z * sc), (_Float16)(b.w * sc)};
    *(half8*)((isW1 ? W1c : W2c) + j * 8) = h;
    return;
  }
  const float* in; _Float16* out; size_t off;
  if      (i < 1048576) { in = q;    out = q16;    off = i; }
  else if (i < 2097152) { in = k;    out = k16;    off = i - 1048576; }
  else if (i < 2490368) { in = wqa;  out = wqa16;  off = i - 2097152; }
  else if (i < 3080192) { in = wqb;  out = wqb16;  off = i - 2490368; }
  else if (i < 3227648) { in = wkva; out = wkva16; off = i - 3080192; }
  else if (i < 3751936) { in = wo;   out = wo16;   off = i - 3227648; }
  else if (i < 3760128) { in = fcc;  out = fcc16;  off = i - 3751936; }
  else                  { in = fcp;  out = fcp16;  off = i - 3760128; }
  float4 a = ((const float4*)in)[2 * off];
  float4 b = ((const float4*)in)[2 * off + 1];
  half8 h = {(_Float16)a.x, (_Float16)a.y, (_Float16)a.z, (_Float16)a.w,
             (_Float16)b.x, (_Float16)b.y, (_Float16)b.z, (_Float16)b.w};
  *(half8*)(out + 8 * off) = h;
}

// ------- f16 MFMA GEMM: global_load_lds + XOR swizzle + DOUBLE-BUFFER counted vmcnt -------
// BIAS (merged C2/P2 GEMM only): col<128 -> bias, else bias2.
// DUAL (merged prep-K/V): z>=32 -> B=(W2c via bias2), transposed store into vT (via Cf).
template<bool OUT16, bool NB, bool BIAS, bool TRANSC, bool DUAL = false>
__global__ __launch_bounds__(256) void gemm16(
    const _Float16* __restrict__ A, const _Float16* __restrict__ Bm,
    const float* __restrict__ bias, const float* __restrict__ bias2,
    float* __restrict__ Cf, _Float16* __restrict__ Ch,
    int N, int K, int lda, int ldb, int ldc,
    long sAb, long sAh, long sBb, long sBh, long sCb, long sCh)
{
  __shared__ __align__(16) _Float16 Asl[2][128 * 64];
  __shared__ __align__(16) _Float16 Bsl[2][128 * 64];
  int mode = 0;
  if (DUAL) {
    int zz = blockIdx.z;
    mode = zz >> 5;
    int z2 = zz & 31;
    int zb2 = z2 >> 4, zh2 = z2 & 15;
    A += (size_t)zb2 * sAb;
    const _Float16* Bsel = mode ? (const _Float16*)bias2 : Bm;
    Bm = Bsel + (size_t)zh2 * (128 * C_);
    if (mode) Ch = ((_Float16*)Cf) + ((size_t)(zb2 * H_ + zh2) * 128) * T_;
    else      Ch += ((size_t)(zb2 * H_ + zh2) * T_) * 192;
  } else {
    const int z = blockIdx.z, zb = z >> 4, zh = z & 15;
    A  += (size_t)zb * sAb + (size_t)zh * sAh;
    Bm += (size_t)zb * sBb + (size_t)zh * sBh;
    if (OUT16) Ch += (size_t)zb * sCb + (size_t)zh * sCh;
    else       Cf += (size_t)zb * sCb + (size_t)zh * sCh;
  }
  const int gx = gridDim.x;
  const int nwg = gx * gridDim.y;
  const int f = xcd_swizzle(blockIdx.y * gx + blockIdx.x, nwg);
  const int bm = (f / gx) * 128, bn = (f % gx) * 128;
  const int tid = threadIdx.x;
  const int w = tid >> 6, lane = tid & 63, l15 = lane & 15, g = lane >> 4;
  const int wm = (w >> 1) * 64, wn = (w & 1) * 64;
  const int srow = w * 32 + (lane >> 3);
  const int sch  = (lane & 7) ^ (lane >> 3);   // inverse-swizzled global chunk
  floatx4 acc[4][4];
  #pragma unroll
  for (int i = 0; i < 4; ++i)
    #pragma unroll
    for (int j = 0; j < 4; ++j) acc[i][j] = (floatx4){0.f, 0.f, 0.f, 0.f};

  auto STAGE = [&](int buf, int k0) {
    _Float16* al = &Asl[buf][w * 2048];
    _Float16* bl = &Bsl[buf][w * 2048];
    #pragma unroll
    for (int i = 0; i < 4; ++i)
      gload16(A + (size_t)(bm + srow + i * 8) * lda + k0 + sch * 8, al + i * 512);
    #pragma unroll
    for (int i = 0; i < 4; ++i)
      gload16(Bm + (size_t)(bn + srow + i * 8) * ldb + k0 + sch * 8, bl + i * 512);
  };

  STAGE(0, 0);
  int cur = 0;
  const int nIter = K >> 6;
  for (int it = 0; it < nIter; ++it) {
    const bool pf = (it + 1 < nIter);
    if (pf) STAGE(cur ^ 1, (it + 1) << 6);
    if (pf) asm volatile("s_waitcnt vmcnt(8)" ::: "memory");
    else    asm volatile("s_waitcnt vmcnt(0)" ::: "memory");
    __builtin_amdgcn_sched_barrier(0);
    __builtin_amdgcn_s_barrier();
    __builtin_amdgcn_sched_barrier(0);
    #pragma unroll
    for (int kk = 0; kk < 2; ++kk) {
      half8 af[4], bf[4];
      const int sw = ((kk * 4 + g) ^ (l15 & 7)) * 8;
      #pragma unroll
      for (int i = 0; i < 4; ++i) {
        af[i] = *(const half8*)&Asl[cur][(wm + i * 16 + l15) * 64 + sw];
        bf[i] = *(const half8*)&Bsl[cur][(wn + i * 16 + l15) * 64 + sw];
      }
      #pragma unroll
      for (int i = 0; i < 4; ++i)
        #pragma unroll
        for (int j = 0; j < 4; ++j)
          acc[i][j] = MFMA16(af[i], bf[j], acc[i][j]);
    }
    asm volatile("s_waitcnt lgkmcnt(0)" ::: "memory");
    __builtin_amdgcn_sched_barrier(0);
    __builtin_amdgcn_s_barrier();
    __builtin_amdgcn_sched_barrier(0);
    cur ^= 1;
  }

  if (DUAL) {
    if (mode) {
      // transposed store into vT [128][T_]
      #pragma unroll
      for (int i = 0; i < 4; ++i)
        #pragma unroll
        for (int j = 0; j < 4; ++j) {
          int row = bm + wm + i * 16 + g * 4;
          int col = wn + j * 16 + l15;
          half4 v = {(_Float16)acc[i][j][0], (_Float16)acc[i][j][1],
                     (_Float16)acc[i][j][2], (_Float16)acc[i][j][3]};
          *(half4*)(Ch + (size_t)col * T_ + row) = v;
        }
    } else {
      // normal store into keff [T_][192]
      #pragma unroll
      for (int i = 0; i < 4; ++i)
        #pragma unroll
        for (int j = 0; j < 4; ++j)
          #pragma unroll
          for (int r = 0; r < 4; ++r) {
            int row = bm + wm + i * 16 + g * 4 + r;
            int col = wn + j * 16 + l15;
            Ch[(size_t)row * 192 + col] = (_Float16)acc[i][j][r];
          }
    }
  } else if (TRANSC) {
    #pragma unroll
    for (int i = 0; i < 4; ++i)
      #pragma unroll
      for (int j = 0; j < 4; ++j) {
        int row = bm + wm + i * 16 + g * 4;
        int col = bn + wn + j * 16 + l15;
        half4 v = {(_Float16)acc[i][j][0], (_Float16)acc[i][j][1],
                   (_Float16)acc[i][j][2], (_Float16)acc[i][j][3]};
        *(half4*)(Ch + (size_t)col * ldc + row) = v;
      }
  } else {
    #pragma unroll
    for (int i = 0; i < 4; ++i)
      #pragma unroll
      for (int j = 0; j < 4; ++j)
        #pragma unroll
        for (int r = 0; r < 4; ++r) {
          int row = bm + wm + i * 16 + g * 4 + r;
          int col = bn + wn + j * 16 + l15;
          if (!NB || col < N) {
            float v = acc[i][j][r];
            if (BIAS) v += (col < 128) ? bias[col] : bias2[col - 128];
            if (OUT16) Ch[(size_t)row * ldc + col] = (_Float16)v;
            else       Cf[(size_t)row * ldc + col] = v;
          }
        }
  }
}

// ---------------- row LayerNorm (templated in/out; in-place safe) ----------------
template<typename TIN, bool OUT16>
__global__ __launch_bounds__(256) void ln_rows(
    const TIN* __restrict__ in, float* __restrict__ outf, _Float16* __restrict__ outh,
    const float* __restrict__ g, const float* __restrict__ bb,
    int L, int ldin, int ldout)
{
  const int row = blockIdx.x;
  const TIN* x = in + (size_t)row * ldin;
  float s = 0.f, s2 = 0.f;
  for (int i = threadIdx.x; i < L; i += 256) {
    float v = (float)x[i]; s += v; s2 += v * v;
  }
  #pragma unroll
  for (int off = 32; off; off >>= 1) {
    s  += __shfl_xor(s, off, 64);
    s2 += __shfl_xor(s2, off, 64);
  }
  __shared__ float rs[4], rs2[4];
  int lane = threadIdx.x & 63, w = threadIdx.x >> 6;
  if (lane == 0) { rs[w] = s; rs2[w] = s2; }
  __syncthreads();
  s  = rs[0] + rs[1] + rs[2] + rs[3];
  s2 = rs2[0] + rs2[1] + rs2[2] + rs2[3];
  float mean = s / L;
  float var = s2 / L - mean * mean;
  float inv = rsqrtf(var + 1e-5f);
  for (int i = threadIdx.x; i < L; i += 256) {
    float v = ((float)x[i] - mean) * inv * g[i] + bb[i];
    if (OUT16) outh[(size_t)row * ldout + i] = (_Float16)v;
    else       outf[(size_t)row * ldout + i] = v;
  }
}

// ------- rope + normalize q_pe in place (f16): block = row, wave handles 4 heads -------
__global__ __launch_bounds__(256) void rope_q16(_Float16* __restrict__ qb,
                                                const float* __restrict__ ps_ptr)
{
  const int row = blockIdx.x;
  const int s = row & (S_ - 1);
  const int lane = threadIdx.x & 63, w = threadIdx.x >> 6;
  float sn = 0.f, cs = 0.f;
  if (lane < 32) {
    float invf = expf(-(float)lane * (LN1E4 / 32.f));
    float ang = (float)(S_ - 1 + s) * invf;
    sincosf(ang, &sn, &cs);
  }
  const float psc = ps_ptr[0] * SCALE_;
  #pragma unroll
  for (int hh = 0; hh < 4; ++hh) {
    const int h = w + hh * 4;
    _Float16* p = qb + (size_t)row * 3072 + h * 192 + NOPE_;
    float o1 = 0.f, o2 = 0.f;
    if (lane < 32) {
      float x1 = (float)p[2 * lane], x2 = (float)p[2 * lane + 1];
      o1 = x1 * cs - x2 * sn;
      o2 = x1 * sn + x2 * cs;
    }
    float ss = o1 * o1 + o2 * o2;
    #pragma unroll
    for (int off = 32; off; off >>= 1) ss += __shfl_xor(ss, off, 64);
    float inv = psc / fmaxf(sqrtf(ss), 1e-12f);
    if (lane < 32) {
      p[2 * lane]     = (_Float16)(o1 * inv);
      p[2 * lane + 1] = (_Float16)(o2 * inv);
    }
  }
}

// ------- rope + normalize k_pe (odd rows) -> keff[b][h][t][128..192] all h -------
__global__ __launch_bounds__(64) void rope_k16(
    const _Float16* __restrict__ kvf16, _Float16* __restrict__ keff)
{
  const int t = blockIdx.x, b = blockIdx.y;
  const int srow = 2 * t + 1;
  const _Float16* p = kvf16 + ((size_t)(b * S_ + srow)) * 576 + C_;
  const int j = threadIdx.x;
  float o1 = 0.f, o2 = 0.f;
  if (j < 32) {
    float invf = expf(-(float)j * (LN1E4 / 32.f));
    float ang = (float)(S_ - 1 + srow) * invf;
    float sn, cs; sincosf(ang, &sn, &cs);
    float x1 = (float)p[2 * j], x2 = (float)p[2 * j + 1];
    o1 = x1 * cs - x2 * sn;
    o2 = x1 * sn + x2 * cs;
  }
  float ss = o1 * o1 + o2 * o2;
  #pragma unroll
  for (int off = 32; off; off >>= 1) ss += __shfl_xor(ss, off, 64);
  float nrm = fmaxf(sqrtf(ss), 1e-12f);
  if (j < 32) {
    _Float16 h1 = (_Float16)(o1 / nrm), h2 = (_Float16)(o2 / nrm);
    #pragma unroll
    for (int h = 0; h < H_; ++h) {
      _Float16* o = keff + ((size_t)((b * H_ + h) * T_) + t) * 192 + NOPE_;
      o[2 * j] = h1; o[2 * j + 1] = h2;
    }
  }
}

// ---------------- sinusoidal PE table (f16) ----------------
__global__ __launch_bounds__(256) void pe16(_Float16* __restrict__ Cpe16)
{
  const int t = blockIdx.x;
  const int i = threadIdx.x;
  float dv = expf(-(float)(2 * i) * (LN1E4 / 512.f));
  float ang = (float)t * dv;
  float sn, cs; sincosf(ang, &sn, &cs);
  Cpe16[(size_t)t * C_ + 2 * i]     = (_Float16)sn;
  Cpe16[(size_t)t * C_ + 2 * i + 1] = (_Float16)cs;
}

// ------- gate: pkv16[b][t] = w0*kvn[2t] + w1*kvn[2t+1]; C2/P2 read from merged Ccat -------
__global__ __launch_bounds__(64) void gate_kernel(
    const _Float16* __restrict__ Ccat, const _Float16* __restrict__ kvn16,
    _Float16* __restrict__ pkv16)
{
  const int t = blockIdx.x, b = blockIdx.y;
  const int j = threadIdx.x;
  const _Float16* c2 = Ccat + (size_t)t * 256;
  const _Float16* p0 = Ccat + (size_t)(1024 + b * S_ + 2 * t) * 256 + 128;
  const _Float16* p1 = p0 + 256;
  float d0 = (float)c2[j] * (float)p0[j] + (float)c2[j + 64] * (float)p0[j + 64];
  float d1 = (float)c2[j] * (float)p1[j] + (float)c2[j + 64] * (float)p1[j + 64];
  #pragma unroll
  for (int off = 32; off; off >>= 1) {
    d0 += __shfl_xor(d0, off, 64);
    d1 += __shfl_xor(d1, off, 64);
  }
  float w0 = 1.f / (1.f + expf(-d0));
  float w1 = 1.f / (1.f + expf(-d1));
  const _Float16* k0 = kvn16 + ((size_t)(b * S_ + 2 * t)) * C_;
  const _Float16* k1 = k0 + C_;
  _Float16* o = pkv16 + ((size_t)(b * T_ + t)) * C_;
  #pragma unroll
  for (int it = 0; it < 2; ++it) {
    int c = j * 4 + it * 256;
    half4 a = *(const half4*)(k0 + c);
    half4 bb = *(const half4*)(k1 + c);
    half4 r;
    #pragma unroll
    for (int u = 0; u < 4; ++u)
      r[u] = (_Float16)(w0 * (float)a[u] + w1 * (float)bb[u]);
    *(half4*)(o + c) = r;
  }
}

// ------- flash attention, swapped-QK^T register softmax, T2-swizzled K/V LDS -------
__global__ __launch_bounds__(256, 3) void attn_flash(
    const _Float16* __restrict__ qb16, const _Float16* __restrict__ keff,
    const _Float16* __restrict__ vT, _Float16* __restrict__ x216)
{
  __shared__ __align__(16) _Float16 K_lds[64 * 192];  // 24 KB, chunk-XOR swizzled
  __shared__ __align__(16) _Float16 V_lds[128 * 64];  // 16 KB, chunk-XOR swizzled
  const int f = xcd_swizzle(blockIdx.x, 1024);
  const int st = f & 31, h = (f >> 5) & 15, b = f >> 9;
  const int tid = threadIdx.x, w = tid >> 6, lane = tid & 63;
  const int l15 = lane & 15, g = lane >> 4, l7 = lane & 7;
  const int rq = b * S_ + st * 64 + w * 16;
  const _Float16* qrow = qb16 + (size_t)(rq + l15) * 3072 + h * 192;
  half8 qB[6];   // B-fragment: lane holds q-row = l15, k-chunk kk*32+g*8
  #pragma unroll
  for (int kk = 0; kk < 6; ++kk) qB[kk] = *(const half8*)(qrow + kk * 32 + g * 8);
  floatx4 O[8];  // O[cc][r] = O[q = g*4+r][d = cc*16+l15]
  #pragma unroll
  for (int i = 0; i < 8; ++i) O[i] = (floatx4){0.f, 0.f, 0.f, 0.f};
  float m = -3e38f, l = 0.f;   // per-lane softmax state for q = l15
  const _Float16* kb = keff + (size_t)(b * H_ + h) * T_ * 192;
  const _Float16* vb = vT   + (size_t)(b * H_ + h) * 128 * T_;

  // staging lane assignments (swizzled LDS slot = data-chunk ^ (row&7))
  int ksrc[6], ksw[6], vsrc[4], vsw[4];
  #pragma unroll
  for (int p = 0; p < 6; ++p) {
    int c = tid + p * 256;
    int r = c / 24, dc = c % 24;
    ksrc[p] = r * 192 + dc * 8;
    ksw[p]  = r * 192 + ((dc ^ (r & 7)) * 8);
  }
  #pragma unroll
  for (int p = 0; p < 4; ++p) {
    int c = tid + p * 256;
    int r = c >> 3, dc = c & 7;
    vsrc[p] = r * T_ + dc * 8;
    vsw[p]  = r * 64 + ((dc ^ (r & 7)) * 8);
  }
  // swizzled read chunk offsets
  int kswr[6], vswr[2];
  #pragma unroll
  for (int kk = 0; kk < 6; ++kk) kswr[kk] = ((kk * 4 + g) ^ l7) * 8;
  #pragma unroll
  for (int kc = 0; kc < 2; ++kc) vswr[kc] = ((kc * 4 + g) ^ l7) * 8;

  half8 kreg[6], vreg[4];
  #pragma unroll
  for (int p = 0; p < 6; ++p) kreg[p] = *(const half8*)(kb + ksrc[p]);
  #pragma unroll
  for (int p = 0; p < 4; ++p) vreg[p] = *(const half8*)(vb + vsrc[p]);
  #pragma unroll
  for (int p = 0; p < 6; ++p) *(half8*)&K_lds[ksw[p]] = kreg[p];
  #pragma unroll
  for (int p = 0; p < 4; ++p) *(half8*)&V_lds[vsw[p]] = vreg[p];
  __syncthreads();

  const int srcA = l15 + ((g & 1) << 5);  // lane of group 2*(g&1)
  const int srcB = srcA + 16;             // lane of group 2*(g&1)+1
  const bool hi = (g >> 1) != 0;

  for (int kt = 0; kt < 16; ++kt) {
    if (kt < 15) {
      const int t1 = (kt + 1) * 64;
      #pragma unroll
      for (int p = 0; p < 6; ++p)
        kreg[p] = *(const half8*)(kb + (size_t)t1 * 192 + ksrc[p]);
      #pragma unroll
      for (int p = 0; p < 4; ++p)
        vreg[p] = *(const half8*)(vb + t1 + vsrc[p]);
    }
    // swapped scores: sc[ct][r] = S[t = ct*16+g*4+r][q = l15]
    floatx4 sc[4];
    #pragma unroll
    for (int i = 0; i < 4; ++i) sc[i] = (floatx4){0.f, 0.f, 0.f, 0.f};
    __builtin_amdgcn_s_setprio(1);
    #pragma unroll
    for (int kk = 0; kk < 6; ++kk)
      #pragma unroll
      for (int ct = 0; ct < 4; ++ct)
        sc[ct] = MFMA16(
            *(const half8*)&K_lds[(ct * 16 + l15) * 192 + kswr[kk]],
            qB[kk], sc[ct]);
    __builtin_amdgcn_s_setprio(0);
    // per-lane (q = l15) online softmax; cross-group reduce = 2 shfls
    float pm = sc[0][0];
    #pragma unroll
    for (int ct = 0; ct < 4; ++ct)
      #pragma unroll
      for (int r = 0; r < 4; ++r) pm = fmaxf(pm, sc[ct][r]);
    pm = fmaxf(pm, __shfl_xor(pm, 16, 64));
    pm = fmaxf(pm, __shfl_xor(pm, 32, 64));
    int ok = pm <= m + 8.f;
    if (!__all(ok)) {
      float mn = fmaxf(m, pm);
      float sf = __expf(m - mn);
      m = mn; l *= sf;
      float sfO[4];
      #pragma unroll
      for (int r = 0; r < 4; ++r) sfO[r] = __shfl(sf, g * 4 + r, 64);
      #pragma unroll
      for (int cc = 0; cc < 8; ++cc) {
        O[cc][0] *= sfO[0]; O[cc][1] *= sfO[1];
        O[cc][2] *= sfO[2]; O[cc][3] *= sfO[3];
      }
    }
    float rs = 0.f;
    #pragma unroll
    for (int ct = 0; ct < 4; ++ct)
      #pragma unroll
      for (int r = 0; r < 4; ++r) {
        float e = __expf(sc[ct][r] - m);
        sc[ct][r] = e; rs += e;
      }
    rs += __shfl_xor(rs, 16, 64);
    rs += __shfl_xor(rs, 32, 64);
    l += rs;
    // pack P to f16 pairs
    unsigned pk[4][2];
    #pragma unroll
    for (int ct = 0; ct < 4; ++ct) {
      union { fp16x2 h; unsigned u; } c0, c1;
      c0.h = __builtin_amdgcn_cvt_pkrtz(sc[ct][0], sc[ct][1]);
      c1.h = __builtin_amdgcn_cvt_pkrtz(sc[ct][2], sc[ct][3]);
      pk[ct][0] = c0.u; pk[ct][1] = c1.u;
    }
    // PV: assemble PA fragment via shfl
    __builtin_amdgcn_s_setprio(1);
    #pragma unroll
    for (int kc = 0; kc < 2; ++kc) {
      unsigned a0 = __shfl((int)pk[2 * kc][0], srcA, 64);
      unsigned b0 = __shfl((int)pk[2 * kc + 1][0], srcA, 64);
      unsigned a1 = __shfl((int)pk[2 * kc][1], srcA, 64);
      unsigned b1 = __shfl((int)pk[2 * kc + 1][1], srcA, 64);
      unsigned a2 = __shfl((int)pk[2 * kc][0], srcB, 64);
      unsigned b2 = __shfl((int)pk[2 * kc + 1][0], srcB, 64);
      unsigned a3 = __shfl((int)pk[2 * kc][1], srcB, 64);
      unsigned b3 = __shfl((int)pk[2 * kc + 1][1], srcB, 64);
      union { unsigned u[4]; half8 h; } pa;
      pa.u[0] = hi ? b0 : a0;
      pa.u[1] = hi ? b1 : a1;
      pa.u[2] = hi ? b2 : a2;
      pa.u[3] = hi ? b3 : a3;
      #pragma unroll
      for (int cc = 0; cc < 8; ++cc)
        O[cc] = MFMA16(pa.h,
            *(const half8*)&V_lds[(cc * 16 + l15) * 64 + vswr[kc]], O[cc]);
    }
    __builtin_amdgcn_s_setprio(0);
    if (kt < 15) {
      __syncthreads();
      #pragma unroll
      for (int p = 0; p < 6; ++p) *(half8*)&K_lds[ksw[p]] = kreg[p];
      #pragma unroll
      for (int p = 0; p < 4; ++p) *(half8*)&V_lds[vsw[p]] = vreg[p];
      __syncthreads();
    }
  }
  float il = 1.f / l;
  float ilO[4];
  #pragma unroll
  for (int r = 0; r < 4; ++r) ilO[r] = __shfl(il, g * 4 + r, 64);
  #pragma unroll
  for (int cc = 0; cc < 8; ++cc)
    #pragma unroll
    for (int r = 0; r < 4; ++r)
      x216[(size_t)(rq + g * 4 + r) * 2048 + h * 128 + cc * 16 + l15] =
          (_Float16)(O[cc][r] * ilO[r]);
}

extern "C" void kernel_launch(void* const* d_in, const int* in_sizes, int n_in,
                              void* d_out, int out_size, void* d_ws, size_t ws_size,
                              hipStream_t stream)
{
  (void)in_sizes; (void)n_in; (void)out_size; (void)ws_size;
  const float* query  = (const float*)d_in[0];
  const float* key    = (const float*)d_in[1];
  const float* wq_a   = (const float*)d_in[3];
  const float* q_ln_g = (const float*)d_in[4];
  const float* q_ln_b = (const float*)d_in[5];
  const float* wq_b   = (const float*)d_in[6];
  const float* wkv_a  = (const float*)d_in[7];
  const float* kv_ln_g= (const float*)d_in[8];
  const float* kv_ln_b= (const float*)d_in[9];
  const float* wkvb   = (const float*)d_in[10];
  const float* wo     = (const float*)d_in[11];
  const float* fc_c_w = (const float*)d_in[12];
  const float* fc_c_b = (const float*)d_in[13];
  const float* fc_p_w = (const float*)d_in[14];
  const float* fc_p_b = (const float*)d_in[15];
  const float* ps     = (const float*)d_in[16];
  float* out = (float*)d_out;

  const int M = B_ * S_; // 4096
  // ---- workspace layout (halves), ~111 MB ----
  _Float16* hws   = (_Float16*)d_ws;
  _Float16* q16   = hws;                      // 8,388,608   (later: x216)
  _Float16* key16 = q16   + (size_t)8388608;  // 8,388,608   (later: keff 6,291,456)
  _Float16* wqa16 = key16 + (size_t)8388608;  // 3,145,728
  _Float16* wqb16 = wqa16 + (size_t)3145728;  // 4,718,592   (later: Ccat 1,310,720)
  _Float16* wkva16= wqb16 + (size_t)4718592;  // 1,179,648   (later: pkv16 1,048,576)
  _Float16* wo16  = wkva16+ (size_t)1179648;  // 4,194,304
  _Float16* ql16  = wo16  + (size_t)4194304;  // 6,291,456   (later: vT 4,194,304)
  _Float16* qb16  = ql16  + (size_t)6291456;  // 12,582,912
  _Float16* kvf16 = qb16  + (size_t)12582912; // 2,359,296   (tail reused by Cpe16)
  _Float16* kvn16 = kvf16 + (size_t)2359296;  // 2,097,152
  _Float16* fcc16 = kvn16 + (size_t)2097152;  // 65,536  (fcc||fcp adjacent = merged B)
  _Float16* fcp16 = fcc16 + (size_t)65536;    // 65,536
  _Float16* W1c   = fcp16 + (size_t)65536;    // 1,048,576
  _Float16* W2c   = W1c   + (size_t)1048576;  // 1,048,576
  // aliases
  _Float16* x216  = q16;
  _Float16* keff  = key16;
  _Float16* Cpe16 = kvn16 - (size_t)524288;   // kvf tail (dead); Acat = [Cpe16; kvn16]
  _Float16* Ccat  = wqb16;                    // 5120 x 256 merged C2|P2 (wqb dead)
  _Float16* pkv16 = wkva16;
  _Float16* vT    = ql16;

  // 0. all f32->f16 conversions + wkvb split
  conv_all<<<15744, 256, 0, stream>>>(query, key, wq_a, wq_b, wkv_a, wo, fc_c_w, fc_p_w,
                                      wkvb, q16, key16, wqa16, wqb16, wkva16, wo16,
                                      fcc16, fcp16, W1c, W2c);
  // 1. ql16 = query @ wq_a^T (f16 out, no fp32 round-trip)
  gemm16<true,false,false,false><<<dim3(QR_/128, M/128), 256, 0, stream>>>(
      q16, wqa16, nullptr, nullptr, nullptr, ql16, QR_, E_, E_, E_, QR_, 0,0,0,0,0,0);
  // 2. LN in place (f16 -> f16)
  ln_rows<_Float16,true><<<M, 256, 0, stream>>>(ql16, nullptr, ql16, q_ln_g, q_ln_b,
                                                QR_, QR_, QR_);
  // 3. qb16 = ql16 @ wq_b^T
  gemm16<true,false,false,false><<<dim3(3072/128, M/128), 256, 0, stream>>>(
      ql16, wqb16, nullptr, nullptr, nullptr, qb16, 3072, QR_, QR_, QR_, 3072, 0,0,0,0,0,0);
  // 4. rope q_pe in place (block = row)
  rope_q16<<<M, 256, 0, stream>>>(qb16, ps);
  // 5. kvf16 = key @ wkv_a^T (N=576; B-overreads stay inside d_ws)
  gemm16<true,true,false,false><<<dim3(5, M/128), 256, 0, stream>>>(
      key16, wkva16, nullptr, nullptr, nullptr, kvf16, 576, E_, E_, E_, 576, 0,0,0,0,0,0);
  // 6. kvn16 = LN(kvf16[:, :512])
  ln_rows<_Float16,true><<<M, 256, 0, stream>>>(kvf16, nullptr, kvn16, kv_ln_g, kv_ln_b,
                                                C_, 576, C_);
  // 7. kpe -> keff[...,128:192] (key16 dead)
  rope_k16<<<dim3(T_, B_), 64, 0, stream>>>(kvf16, keff);
  // 8. PE table f16 into kvf tail (kvf dead after step 7)
  pe16<<<T_, 256, 0, stream>>>(Cpe16);
  // 9. merged: Ccat = [Cpe16;kvn16] @ [fcc;fcp]^T + [fc_c_b|fc_p_b]  (M=5120, N=256)
  gemm16<true,false,true,false><<<dim3(2, 5120/128), 256, 0, stream>>>(
      Cpe16, fcc16, fc_c_b, fc_p_b, nullptr, Ccat, 256, C_, C_, C_, 256, 0,0,0,0,0,0);
  // 10. gate -> pkv16 (wkva16 dead)
  gate_kernel<<<dim3(T_, B_), 64, 0, stream>>>(Ccat, kvn16, pkv16);
  // 11. merged prep: z<32 -> keff[...,0:128] = pkv@W1c^T; z>=32 -> vT = (pkv@W2c^T)^T
  //     (ql16 dead -> vT)
  gemm16<true,false,false,false,true><<<dim3(1, T_/128, 64), 256, 0, stream>>>(
      pkv16, W1c, nullptr, (const float*)W2c, (float*)vT, keff,
      128, C_, C_, C_, 192, (long)T_*C_, 0L, 0L, 0L, 0L, 0L);
  // 12. flash attention (swizzled K/V LDS) -> x216 (q16 dead)
  attn_flash<<<dim3(1024), 256, 0, stream>>>(qb16, keff, vT, x216);
  // 13. out = x216 @ wo16^T (fp32 out)
  gemm16<false,false,false,false><<<dim3(E_/128, M/128), 256, 0, stream>>>(
      x216, wo16, nullptr, nullptr, out, nullptr, E_, E_, E_, E_, E_, 0,0,0,0,0,0);
}

// Round 14
// 326.932 us; speedup vs baseline: 1.3687x; 1.0557x over previous
//
#include <hip/hip_runtime.h>
#include <math.h>

#define S_ 2048
#define B_ 2
#define H_ 16
#define E_ 2048
#define QR_ 1536
#define NOPE_ 128
#define ROPE_ 64
#define C_ 512
#define VH_ 128
#define T_ 1024
#define LN1E4 9.210340371976184f
#define SCALE_ 0.07216878364870323f  // 192^-0.5

typedef _Float16 half8 __attribute__((ext_vector_type(8)));
typedef _Float16 half4 __attribute__((ext_vector_type(4)));
typedef __fp16 fp16x2 __attribute__((ext_vector_type(2)));
typedef float floatx4 __attribute__((ext_vector_type(4)));
#define MFMA16(a, b, c) __builtin_amdgcn_mfma_f32_16x16x32_f16(a, b, c, 0, 0, 0)

__device__ __forceinline__ void gload16(const _Float16* g, _Float16* l) {
  __builtin_amdgcn_global_load_lds(
      (__attribute__((address_space(1))) const void*)g,
      (__attribute__((address_space(3))) void*)l, 16, 0, 0);
}

// bijective XCD-chunked swizzle (m204)
__device__ __forceinline__ int xcd_swizzle(int orig, int nwg) {
  int q8 = nwg >> 3, r8 = nwg & 7, xcd = orig & 7, base = orig >> 3;
  return (xcd < r8 ? xcd * (q8 + 1) : r8 * (q8 + 1) + (xcd - r8) * q8) + base;
}

// ------- fused f32 -> f16 conversion for 8 tensors + wkvb split (W1c scaled, W2c) -------
__global__ __launch_bounds__(256) void conv_all(
    const float* __restrict__ q, const float* __restrict__ k,
    const float* __restrict__ wqa, const float* __restrict__ wqb,
    const float* __restrict__ wkva, const float* __restrict__ wo,
    const float* __restrict__ fcc, const float* __restrict__ fcp,
    const float* __restrict__ wkvb,
    _Float16* q16, _Float16* k16, _Float16* wqa16, _Float16* wqb16,
    _Float16* wkva16, _Float16* wo16, _Float16* fcc16, _Float16* fcp16,
    _Float16* W1c, _Float16* W2c)
{
  size_t i = (size_t)blockIdx.x * 256 + threadIdx.x;  // half8-chunk index
  if (i >= 3768320) {
    bool isW1 = i < 3899392;
    size_t j = i - (isW1 ? 3768320 : 3899392);
    int cch = j & 63, hd = (int)(j >> 6);
    int hh = hd >> 7, dd = hd & 127;
    const float* src = wkvb + ((size_t)(hh * 256 + (isW1 ? 0 : 128) + dd)) * 512 + cch * 8;
    float sc = isW1 ? SCALE_ : 1.f;
    float4 a = *(const float4*)src;
    float4 b = *(const float4*)(src + 4);
    half8 h = {(_Float16)(a.x * sc), (_Float16)(a.y * sc), (_Float16)(a.z * sc),
               (_Float16)(a.w * sc), (_Float16)(b.x * sc), (_Float16)(b.y * sc),
               (_Float16)(b.z * sc), (_Float16)(b.w * sc)};
    *(half8*)((isW1 ? W1c : W2c) + j * 8) = h;
    return;
  }
  const float* in; _Float16* out; size_t off;
  if      (i < 1048576) { in = q;    out = q16;    off = i; }
  else if (i < 2097152) { in = k;    out = k16;    off = i - 1048576; }
  else if (i < 2490368) { in = wqa;  out = wqa16;  off = i - 2097152; }
  else if (i < 3080192) { in = wqb;  out = wqb16;  off = i - 2490368; }
  else if (i < 3227648) { in = wkva; out = wkva16; off = i - 3080192; }
  else if (i < 3751936) { in = wo;   out = wo16;   off = i - 3227648; }
  else if (i < 3760128) { in = fcc;  out = fcc16;  off = i - 3751936; }
  else                  { in = fcp;  out = fcp16;  off = i - 3760128; }
  float4 a = ((const float4*)in)[2 * off];
  float4 b = ((const float4*)in)[2 * off + 1];
  half8 h = {(_Float16)a.x, (_Float16)a.y, (_Float16)a.z, (_Float16)a.w,
             (_Float16)b.x, (_Float16)b.y, (_Float16)b.z, (_Float16)b.w};
  *(half8*)(out + 8 * off) = h;
}

// ------- original f16 MFMA GEMM (used by prep DUAL + fp32-out final GEMM) -------
template<bool OUT16, bool NB, bool BIAS, bool TRANSC, bool DUAL = false>
__global__ __launch_bounds__(256) void gemm16(
    const _Float16* __restrict__ A, const _Float16* __restrict__ Bm,
    const float* __restrict__ bias, const float* __restrict__ bias2,
    float* __restrict__ Cf, _Float16* __restrict__ Ch,
    int N, int K, int lda, int ldb, int ldc,
    long sAb, long sAh, long sBb, long sBh, long sCb, long sCh)
{
  __shared__ __align__(16) _Float16 Asl[2][128 * 64];
  __shared__ __align__(16) _Float16 Bsl[2][128 * 64];
  int mode = 0;
  if (DUAL) {
    int zz = blockIdx.z;
    mode = zz >> 5;
    int z2 = zz & 31;
    int zb2 = z2 >> 4, zh2 = z2 & 15;
    A += (size_t)zb2 * sAb;
    const _Float16* Bsel = mode ? (const _Float16*)bias2 : Bm;
    Bm = Bsel + (size_t)zh2 * (128 * C_);
    if (mode) Ch = ((_Float16*)Cf) + ((size_t)(zb2 * H_ + zh2) * 128) * T_;
    else      Ch += ((size_t)(zb2 * H_ + zh2) * T_) * 192;
  } else {
    const int z = blockIdx.z, zb = z >> 4, zh = z & 15;
    A  += (size_t)zb * sAb + (size_t)zh * sAh;
    Bm += (size_t)zb * sBb + (size_t)zh * sBh;
    if (OUT16) Ch += (size_t)zb * sCb + (size_t)zh * sCh;
    else       Cf += (size_t)zb * sCb + (size_t)zh * sCh;
  }
  const int gx = gridDim.x;
  const int nwg = gx * gridDim.y;
  const int f = xcd_swizzle(blockIdx.y * gx + blockIdx.x, nwg);
  const int bm = (f / gx) * 128, bn = (f % gx) * 128;
  const int tid = threadIdx.x;
  const int w = tid >> 6, lane = tid & 63, l15 = lane & 15, g = lane >> 4;
  const int wm = (w >> 1) * 64, wn = (w & 1) * 64;
  const int srow = w * 32 + (lane >> 3);
  const int sch  = (lane & 7) ^ (lane >> 3);
  floatx4 acc[4][4];
  #pragma unroll
  for (int i = 0; i < 4; ++i)
    #pragma unroll
    for (int j = 0; j < 4; ++j) acc[i][j] = (floatx4){0.f, 0.f, 0.f, 0.f};

  auto STAGE = [&](int buf, int k0) {
    _Float16* al = &Asl[buf][w * 2048];
    _Float16* bl = &Bsl[buf][w * 2048];
    #pragma unroll
    for (int i = 0; i < 4; ++i)
      gload16(A + (size_t)(bm + srow + i * 8) * lda + k0 + sch * 8, al + i * 512);
    #pragma unroll
    for (int i = 0; i < 4; ++i)
      gload16(Bm + (size_t)(bn + srow + i * 8) * ldb + k0 + sch * 8, bl + i * 512);
  };

  STAGE(0, 0);
  int cur = 0;
  const int nIter = K >> 6;
  for (int it = 0; it < nIter; ++it) {
    const bool pf = (it + 1 < nIter);
    if (pf) STAGE(cur ^ 1, (it + 1) << 6);
    if (pf) asm volatile("s_waitcnt vmcnt(8)" ::: "memory");
    else    asm volatile("s_waitcnt vmcnt(0)" ::: "memory");
    __builtin_amdgcn_sched_barrier(0);
    __builtin_amdgcn_s_barrier();
    __builtin_amdgcn_sched_barrier(0);
    #pragma unroll
    for (int kk = 0; kk < 2; ++kk) {
      half8 af[4], bf[4];
      const int sw = ((kk * 4 + g) ^ (l15 & 7)) * 8;
      #pragma unroll
      for (int i = 0; i < 4; ++i) {
        af[i] = *(const half8*)&Asl[cur][(wm + i * 16 + l15) * 64 + sw];
        bf[i] = *(const half8*)&Bsl[cur][(wn + i * 16 + l15) * 64 + sw];
      }
      #pragma unroll
      for (int i = 0; i < 4; ++i)
        #pragma unroll
        for (int j = 0; j < 4; ++j)
          acc[i][j] = MFMA16(af[i], bf[j], acc[i][j]);
    }
    asm volatile("s_waitcnt lgkmcnt(0)" ::: "memory");
    __builtin_amdgcn_sched_barrier(0);
    __builtin_amdgcn_s_barrier();
    __builtin_amdgcn_sched_barrier(0);
    cur ^= 1;
  }

  if (DUAL) {
    if (mode) {
      #pragma unroll
      for (int i = 0; i < 4; ++i)
        #pragma unroll
        for (int j = 0; j < 4; ++j) {
          int row = bm + wm + i * 16 + g * 4;
          int col = wn + j * 16 + l15;
          half4 v = {(_Float16)acc[i][j][0], (_Float16)acc[i][j][1],
                     (_Float16)acc[i][j][2], (_Float16)acc[i][j][3]};
          *(half4*)(Ch + (size_t)col * T_ + row) = v;
        }
    } else {
      #pragma unroll
      for (int i = 0; i < 4; ++i)
        #pragma unroll
        for (int j = 0; j < 4; ++j)
          #pragma unroll
          for (int r = 0; r < 4; ++r) {
            int row = bm + wm + i * 16 + g * 4 + r;
            int col = wn + j * 16 + l15;
            Ch[(size_t)row * 192 + col] = (_Float16)acc[i][j][r];
          }
    }
  } else if (TRANSC) {
    #pragma unroll
    for (int i = 0; i < 4; ++i)
      #pragma unroll
      for (int j = 0; j < 4; ++j) {
        int row = bm + wm + i * 16 + g * 4;
        int col = bn + wn + j * 16 + l15;
        half4 v = {(_Float16)acc[i][j][0], (_Float16)acc[i][j][1],
                   (_Float16)acc[i][j][2], (_Float16)acc[i][j][3]};
        *(half4*)(Ch + (size_t)col * ldc + row) = v;
      }
  } else {
    #pragma unroll
    for (int i = 0; i < 4; ++i)
      #pragma unroll
      for (int j = 0; j < 4; ++j)
        #pragma unroll
        for (int r = 0; r < 4; ++r) {
          int row = bm + wm + i * 16 + g * 4 + r;
          int col = bn + wn + j * 16 + l15;
          if (!NB || col < N) {
            float v = acc[i][j][r];
            if (BIAS) v += (col < 128) ? bias[col] : bias2[col - 128];
            if (OUT16) Ch[(size_t)row * ldc + col] = (_Float16)v;
            else       Cf[(size_t)row * ldc + col] = v;
          }
        }
  }
}

// ------- paired GEMM: two independent GEMM tasks in one launch (f16 out) -------
struct GTask {
  const _Float16* A; const _Float16* B; _Float16* C;
  const float* b1; const float* b2;
  int gx, N, K, lda, ldb, ldc;
};

__global__ __launch_bounds__(256) void gemm_pair(GTask ta, GTask tb, int n0, int n1)
{
  __shared__ __align__(16) _Float16 Asl[2][128 * 64];
  __shared__ __align__(16) _Float16 Bsl[2][128 * 64];
  const bool second = blockIdx.x >= (unsigned)n0;
  GTask t = second ? tb : ta;
  const int fid = second ? blockIdx.x - n0 : blockIdx.x;
  const int nwg = second ? n1 : n0;
  const int f = xcd_swizzle(fid, nwg);
  const int bm = (f / t.gx) * 128, bn = (f % t.gx) * 128;
  const int tid = threadIdx.x;
  const int w = tid >> 6, lane = tid & 63, l15 = lane & 15, g = lane >> 4;
  const int wm = (w >> 1) * 64, wn = (w & 1) * 64;
  const int srow = w * 32 + (lane >> 3);
  const int sch  = (lane & 7) ^ (lane >> 3);
  floatx4 acc[4][4];
  #pragma unroll
  for (int i = 0; i < 4; ++i)
    #pragma unroll
    for (int j = 0; j < 4; ++j) acc[i][j] = (floatx4){0.f, 0.f, 0.f, 0.f};

  auto STAGE = [&](int buf, int k0) {
    _Float16* al = &Asl[buf][w * 2048];
    _Float16* bl = &Bsl[buf][w * 2048];
    #pragma unroll
    for (int i = 0; i < 4; ++i)
      gload16(t.A + (size_t)(bm + srow + i * 8) * t.lda + k0 + sch * 8, al + i * 512);
    #pragma unroll
    for (int i = 0; i < 4; ++i)
      gload16(t.B + (size_t)(bn + srow + i * 8) * t.ldb + k0 + sch * 8, bl + i * 512);
  };

  STAGE(0, 0);
  int cur = 0;
  const int nIter = t.K >> 6;
  for (int it = 0; it < nIter; ++it) {
    const bool pf = (it + 1 < nIter);
    if (pf) STAGE(cur ^ 1, (it + 1) << 6);
    if (pf) asm volatile("s_waitcnt vmcnt(8)" ::: "memory");
    else    asm volatile("s_waitcnt vmcnt(0)" ::: "memory");
    __builtin_amdgcn_sched_barrier(0);
    __builtin_amdgcn_s_barrier();
    __builtin_amdgcn_sched_barrier(0);
    #pragma unroll
    for (int kk = 0; kk < 2; ++kk) {
      half8 af[4], bf[4];
      const int sw = ((kk * 4 + g) ^ (l15 & 7)) * 8;
      #pragma unroll
      for (int i = 0; i < 4; ++i) {
        af[i] = *(const half8*)&Asl[cur][(wm + i * 16 + l15) * 64 + sw];
        bf[i] = *(const half8*)&Bsl[cur][(wn + i * 16 + l15) * 64 + sw];
      }
      #pragma unroll
      for (int i = 0; i < 4; ++i)
        #pragma unroll
        for (int j = 0; j < 4; ++j)
          acc[i][j] = MFMA16(af[i], bf[j], acc[i][j]);
    }
    asm volatile("s_waitcnt lgkmcnt(0)" ::: "memory");
    __builtin_amdgcn_sched_barrier(0);
    __builtin_amdgcn_s_barrier();
    __builtin_amdgcn_sched_barrier(0);
    cur ^= 1;
  }
  #pragma unroll
  for (int i = 0; i < 4; ++i)
    #pragma unroll
    for (int j = 0; j < 4; ++j)
      #pragma unroll
      for (int r = 0; r < 4; ++r) {
        int row = bm + wm + i * 16 + g * 4 + r;
        int col = bn + wn + j * 16 + l15;
        if (col < t.N) {
          float v = acc[i][j][r];
          if (t.b1) v += (col < 128) ? t.b1[col] : t.b2[col - 128];
          t.C[(size_t)row * t.ldc + col] = (_Float16)v;
        }
      }
}

// ------- fused LN(q) + LN(kv) + rope_k + PE table -------
// blocks 0..4095: LN q row (in-place, L=1536); 4096..8191: LN kv (kvf->kvnA, L=512);
// 8192..8703: rope_k (4 wave-tasks/block); 8704..9727: PE row.
__global__ __launch_bounds__(256) void fused_ln(
    _Float16* __restrict__ ql16, const _Float16* __restrict__ kvf16,
    _Float16* __restrict__ kvnA,
    const float* __restrict__ qg, const float* __restrict__ qb,
    const float* __restrict__ kg, const float* __restrict__ kb,
    _Float16* __restrict__ keff, _Float16* __restrict__ Cpe16)
{
  __shared__ float rs[4], rs2[4];
  int bid = blockIdx.x;
  const int tid = threadIdx.x;
  const int lane = tid & 63, w = tid >> 6;
  if (bid < 8192) {
    const bool isQ = bid < 4096;
    const int row = isQ ? bid : bid - 4096;
    const _Float16* x = isQ ? ql16 + (size_t)row * 1536 : kvf16 + (size_t)row * 576;
    _Float16* o = isQ ? ql16 + (size_t)row * 1536 : kvnA + (size_t)row * 512;
    const float* g_ = isQ ? qg : kg;
    const float* b_ = isQ ? qb : kb;
    const int L = isQ ? 1536 : 512;
    float s = 0.f, s2 = 0.f;
    for (int i = tid; i < L; i += 256) {
      float v = (float)x[i]; s += v; s2 += v * v;
    }
    #pragma unroll
    for (int off = 32; off; off >>= 1) {
      s  += __shfl_xor(s, off, 64);
      s2 += __shfl_xor(s2, off, 64);
    }
    if (lane == 0) { rs[w] = s; rs2[w] = s2; }
    __syncthreads();
    s  = rs[0] + rs[1] + rs[2] + rs[3];
    s2 = rs2[0] + rs2[1] + rs2[2] + rs2[3];
    float mean = s / L;
    float var = s2 / L - mean * mean;
    float inv = rsqrtf(var + 1e-5f);
    for (int i = tid; i < L; i += 256)
      o[i] = (_Float16)(((float)x[i] - mean) * inv * g_[i] + b_[i]);
    return;
  }
  bid -= 8192;
  if (bid < 512) {
    // rope_k: wave-task u
    int u = bid * 4 + w;
    int t = u & (T_ - 1), b = u >> 10;
    const int srow = 2 * t + 1;
    const _Float16* p = kvf16 + ((size_t)(b * S_ + srow)) * 576 + C_;
    float o1 = 0.f, o2 = 0.f;
    if (lane < 32) {
      float invf = expf(-(float)lane * (LN1E4 / 32.f));
      float ang = (float)(S_ - 1 + srow) * invf;
      float sn, cs; sincosf(ang, &sn, &cs);
      float x1 = (float)p[2 * lane], x2 = (float)p[2 * lane + 1];
      o1 = x1 * cs - x2 * sn;
      o2 = x1 * sn + x2 * cs;
    }
    float ss = o1 * o1 + o2 * o2;
    #pragma unroll
    for (int off = 32; off; off >>= 1) ss += __shfl_xor(ss, off, 64);
    float nrm = fmaxf(sqrtf(ss), 1e-12f);
    if (lane < 32) {
      _Float16 h1 = (_Float16)(o1 / nrm), h2 = (_Float16)(o2 / nrm);
      #pragma unroll
      for (int h = 0; h < H_; ++h) {
        _Float16* o = keff + ((size_t)((b * H_ + h) * T_) + t) * 192 + NOPE_;
        o[2 * lane] = h1; o[2 * lane + 1] = h2;
      }
    }
    return;
  }
  bid -= 512;
  {
    // PE row t = bid
    const int t = bid;
    float dv = expf(-(float)(2 * tid) * (LN1E4 / 512.f));
    float ang = (float)t * dv;
    float sn, cs; sincosf(ang, &sn, &cs);
    Cpe16[(size_t)t * C_ + 2 * tid]     = (_Float16)sn;
    Cpe16[(size_t)t * C_ + 2 * tid + 1] = (_Float16)cs;
  }
}

// ------- fused rope_q + gate -------
// blocks 0..4095: rope_q row; 4096..4607: gate (4 wave-tasks/block)
__global__ __launch_bounds__(256) void fused_rq_gate(
    _Float16* __restrict__ qb16, const float* __restrict__ ps_ptr,
    const _Float16* __restrict__ Ccat, const _Float16* __restrict__ kvnA,
    _Float16* __restrict__ pkv16)
{
  int bid = blockIdx.x;
  const int tid = threadIdx.x;
  const int lane = tid & 63, w = tid >> 6;
  if (bid < 4096) {
    const int row = bid;
    const int s = row & (S_ - 1);
    float sn = 0.f, cs = 0.f;
    if (lane < 32) {
      float invf = expf(-(float)lane * (LN1E4 / 32.f));
      float ang = (float)(S_ - 1 + s) * invf;
      sincosf(ang, &sn, &cs);
    }
    const float psc = ps_ptr[0] * SCALE_;
    #pragma unroll
    for (int hh = 0; hh < 4; ++hh) {
      const int h = w + hh * 4;
      _Float16* p = qb16 + (size_t)row * 3072 + h * 192 + NOPE_;
      float o1 = 0.f, o2 = 0.f;
      if (lane < 32) {
        float x1 = (float)p[2 * lane], x2 = (float)p[2 * lane + 1];
        o1 = x1 * cs - x2 * sn;
        o2 = x1 * sn + x2 * cs;
      }
      float ss = o1 * o1 + o2 * o2;
      #pragma unroll
      for (int off = 32; off; off >>= 1) ss += __shfl_xor(ss, off, 64);
      float inv = psc / fmaxf(sqrtf(ss), 1e-12f);
      if (lane < 32) {
        p[2 * lane]     = (_Float16)(o1 * inv);
        p[2 * lane + 1] = (_Float16)(o2 * inv);
      }
    }
    return;
  }
  bid -= 4096;
  {
    int u = bid * 4 + w;
    int t = u & (T_ - 1), b = u >> 10;
    const int j = lane;
    const _Float16* c2 = Ccat + (size_t)t * 256;
    const _Float16* p0 = Ccat + (size_t)(1024 + b * S_ + 2 * t) * 256 + 128;
    const _Float16* p1 = p0 + 256;
    float d0 = (float)c2[j] * (float)p0[j] + (float)c2[j + 64] * (float)p0[j + 64];
    float d1 = (float)c2[j] * (float)p1[j] + (float)c2[j + 64] * (float)p1[j + 64];
    #pragma unroll
    for (int off = 32; off; off >>= 1) {
      d0 += __shfl_xor(d0, off, 64);
      d1 += __shfl_xor(d1, off, 64);
    }
    float w0 = 1.f / (1.f + expf(-d0));
    float w1 = 1.f / (1.f + expf(-d1));
    const _Float16* k0 = kvnA + ((size_t)(b * S_ + 2 * t)) * C_;
    const _Float16* k1 = k0 + C_;
    _Float16* o = pkv16 + ((size_t)(b * T_ + t)) * C_;
    #pragma unroll
    for (int it = 0; it < 2; ++it) {
      int c = j * 4 + it * 256;
      half4 a = *(const half4*)(k0 + c);
      half4 bb = *(const half4*)(k1 + c);
      half4 r;
      #pragma unroll
      for (int uu = 0; uu < 4; ++uu)
        r[uu] = (_Float16)(w0 * (float)a[uu] + w1 * (float)bb[uu]);
      *(half4*)(o + c) = r;
    }
  }
}

// ------- flash attention, swapped-QK^T register softmax, T2-swizzled K/V LDS -------
__global__ __launch_bounds__(256, 3) void attn_flash(
    const _Float16* __restrict__ qb16, const _Float16* __restrict__ keff,
    const _Float16* __restrict__ vT, _Float16* __restrict__ x216)
{
  __shared__ __align__(16) _Float16 K_lds[64 * 192];  // 24 KB, chunk-XOR swizzled
  __shared__ __align__(16) _Float16 V_lds[128 * 64];  // 16 KB, chunk-XOR swizzled
  const int f = xcd_swizzle(blockIdx.x, 1024);
  const int st = f & 31, h = (f >> 5) & 15, b = f >> 9;
  const int tid = threadIdx.x, w = tid >> 6, lane = tid & 63;
  const int l15 = lane & 15, g = lane >> 4, l7 = lane & 7;
  const int rq = b * S_ + st * 64 + w * 16;
  const _Float16* qrow = qb16 + (size_t)(rq + l15) * 3072 + h * 192;
  half8 qB[6];
  #pragma unroll
  for (int kk = 0; kk < 6; ++kk) qB[kk] = *(const half8*)(qrow + kk * 32 + g * 8);
  floatx4 O[8];
  #pragma unroll
  for (int i = 0; i < 8; ++i) O[i] = (floatx4){0.f, 0.f, 0.f, 0.f};
  float m = -3e38f, l = 0.f;
  const _Float16* kb = keff + (size_t)(b * H_ + h) * T_ * 192;
  const _Float16* vb = vT   + (size_t)(b * H_ + h) * 128 * T_;

  int ksrc[6], ksw[6], vsrc[4], vsw[4];
  #pragma unroll
  for (int p = 0; p < 6; ++p) {
    int c = tid + p * 256;
    int r = c / 24, dc = c % 24;
    ksrc[p] = r * 192 + dc * 8;
    ksw[p]  = r * 192 + ((dc ^ (r & 7)) * 8);
  }
  #pragma unroll
  for (int p = 0; p < 4; ++p) {
    int c = tid + p * 256;
    int r = c >> 3, dc = c & 7;
    vsrc[p] = r * T_ + dc * 8;
    vsw[p]  = r * 64 + ((dc ^ (r & 7)) * 8);
  }
  int kswr[6], vswr[2];
  #pragma unroll
  for (int kk = 0; kk < 6; ++kk) kswr[kk] = ((kk * 4 + g) ^ l7) * 8;
  #pragma unroll
  for (int kc = 0; kc < 2; ++kc) vswr[kc] = ((kc * 4 + g) ^ l7) * 8;

  half8 kreg[6], vreg[4];
  #pragma unroll
  for (int p = 0; p < 6; ++p) kreg[p] = *(const half8*)(kb + ksrc[p]);
  #pragma unroll
  for (int p = 0; p < 4; ++p) vreg[p] = *(const half8*)(vb + vsrc[p]);
  #pragma unroll
  for (int p = 0; p < 6; ++p) *(half8*)&K_lds[ksw[p]] = kreg[p];
  #pragma unroll
  for (int p = 0; p < 4; ++p) *(half8*)&V_lds[vsw[p]] = vreg[p];
  __syncthreads();

  const int srcA = l15 + ((g & 1) << 5);
  const int srcB = srcA + 16;
  const bool hi = (g >> 1) != 0;

  for (int kt = 0; kt < 16; ++kt) {
    if (kt < 15) {
      const int t1 = (kt + 1) * 64;
      #pragma unroll
      for (int p = 0; p < 6; ++p)
        kreg[p] = *(const half8*)(kb + (size_t)t1 * 192 + ksrc[p]);
      #pragma unroll
      for (int p = 0; p < 4; ++p)
        vreg[p] = *(const half8*)(vb + t1 + vsrc[p]);
    }
    floatx4 sc[4];
    #pragma unroll
    for (int i = 0; i < 4; ++i) sc[i] = (floatx4){0.f, 0.f, 0.f, 0.f};
    __builtin_amdgcn_s_setprio(1);
    #pragma unroll
    for (int kk = 0; kk < 6; ++kk)
      #pragma unroll
      for (int ct = 0; ct < 4; ++ct)
        sc[ct] = MFMA16(
            *(const half8*)&K_lds[(ct * 16 + l15) * 192 + kswr[kk]],
            qB[kk], sc[ct]);
    __builtin_amdgcn_s_setprio(0);
    float pm = sc[0][0];
    #pragma unroll
    for (int ct = 0; ct < 4; ++ct)
      #pragma unroll
      for (int r = 0; r < 4; ++r) pm = fmaxf(pm, sc[ct][r]);
    pm = fmaxf(pm, __shfl_xor(pm, 16, 64));
    pm = fmaxf(pm, __shfl_xor(pm, 32, 64));
    int ok = pm <= m + 8.f;
    if (!__all(ok)) {
      float mn = fmaxf(m, pm);
      float sf = __expf(m - mn);
      m = mn; l *= sf;
      float sfO[4];
      #pragma unroll
      for (int r = 0; r < 4; ++r) sfO[r] = __shfl(sf, g * 4 + r, 64);
      #pragma unroll
      for (int cc = 0; cc < 8; ++cc) {
        O[cc][0] *= sfO[0]; O[cc][1] *= sfO[1];
        O[cc][2] *= sfO[2]; O[cc][3] *= sfO[3];
      }
    }
    float rs = 0.f;
    #pragma unroll
    for (int ct = 0; ct < 4; ++ct)
      #pragma unroll
      for (int r = 0; r < 4; ++r) {
        float e = __expf(sc[ct][r] - m);
        sc[ct][r] = e; rs += e;
      }
    rs += __shfl_xor(rs, 16, 64);
    rs += __shfl_xor(rs, 32, 64);
    l += rs;
    unsigned pk[4][2];
    #pragma unroll
    for (int ct = 0; ct < 4; ++ct) {
      union { fp16x2 h; unsigned u; } c0, c1;
      c0.h = __builtin_amdgcn_cvt_pkrtz(sc[ct][0], sc[ct][1]);
      c1.h = __builtin_amdgcn_cvt_pkrtz(sc[ct][2], sc[ct][3]);
      pk[ct][0] = c0.u; pk[ct][1] = c1.u;
    }
    __builtin_amdgcn_s_setprio(1);
    #pragma unroll
    for (int kc = 0; kc < 2; ++kc) {
      unsigned a0 = __shfl((int)pk[2 * kc][0], srcA, 64);
      unsigned b0 = __shfl((int)pk[2 * kc + 1][0], srcA, 64);
      unsigned a1 = __shfl((int)pk[2 * kc][1], srcA, 64);
      unsigned b1 = __shfl((int)pk[2 * kc + 1][1], srcA, 64);
      unsigned a2 = __shfl((int)pk[2 * kc][0], srcB, 64);
      unsigned b2 = __shfl((int)pk[2 * kc + 1][0], srcB, 64);
      unsigned a3 = __shfl((int)pk[2 * kc][1], srcB, 64);
      unsigned b3 = __shfl((int)pk[2 * kc + 1][1], srcB, 64);
      union { unsigned u[4]; half8 h; } pa;
      pa.u[0] = hi ? b0 : a0;
      pa.u[1] = hi ? b1 : a1;
      pa.u[2] = hi ? b2 : a2;
      pa.u[3] = hi ? b3 : a3;
      #pragma unroll
      for (int cc = 0; cc < 8; ++cc)
        O[cc] = MFMA16(pa.h,
            *(const half8*)&V_lds[(cc * 16 + l15) * 64 + vswr[kc]], O[cc]);
    }
    __builtin_amdgcn_s_setprio(0);
    if (kt < 15) {
      __syncthreads();
      #pragma unroll
      for (int p = 0; p < 6; ++p) *(half8*)&K_lds[ksw[p]] = kreg[p];
      #pragma unroll
      for (int p = 0; p < 4; ++p) *(half8*)&V_lds[vsw[p]] = vreg[p];
      __syncthreads();
    }
  }
  float il = 1.f / l;
  float ilO[4];
  #pragma unroll
  for (int r = 0; r < 4; ++r) ilO[r] = __shfl(il, g * 4 + r, 64);
  #pragma unroll
  for (int cc = 0; cc < 8; ++cc)
    #pragma unroll
    for (int r = 0; r < 4; ++r)
      x216[(size_t)(rq + g * 4 + r) * 2048 + h * 128 + cc * 16 + l15] =
          (_Float16)(O[cc][r] * ilO[r]);
}

extern "C" void kernel_launch(void* const* d_in, const int* in_sizes, int n_in,
                              void* d_out, int out_size, void* d_ws, size_t ws_size,
                              hipStream_t stream)
{
  (void)in_sizes; (void)n_in; (void)out_size; (void)ws_size;
  const float* query  = (const float*)d_in[0];
  const float* key    = (const float*)d_in[1];
  const float* wq_a   = (const float*)d_in[3];
  const float* q_ln_g = (const float*)d_in[4];
  const float* q_ln_b = (const float*)d_in[5];
  const float* wq_b   = (const float*)d_in[6];
  const float* wkv_a  = (const float*)d_in[7];
  const float* kv_ln_g= (const float*)d_in[8];
  const float* kv_ln_b= (const float*)d_in[9];
  const float* wkvb   = (const float*)d_in[10];
  const float* wo     = (const float*)d_in[11];
  const float* fc_c_w = (const float*)d_in[12];
  const float* fc_c_b = (const float*)d_in[13];
  const float* fc_p_w = (const float*)d_in[14];
  const float* fc_p_b = (const float*)d_in[15];
  const float* ps     = (const float*)d_in[16];
  float* out = (float*)d_out;

  const int M = B_ * S_; // 4096
  // ---- workspace layout (halves), ~111 MB ----
  _Float16* hws   = (_Float16*)d_ws;
  _Float16* q16   = hws;                      // 8,388,608 (-> Acat[Cpe|kvnA] -> x216)
  _Float16* key16 = q16   + (size_t)8388608;  // 8,388,608 (-> keff)
  _Float16* wqa16 = key16 + (size_t)8388608;  // 3,145,728 (-> Ccat 1,310,720)
  _Float16* wqb16 = wqa16 + (size_t)3145728;  // 4,718,592
  _Float16* wkva16= wqb16 + (size_t)4718592;  // 1,179,648 (-> pkv16 1,048,576)
  _Float16* wo16  = wkva16+ (size_t)1179648;  // 4,194,304
  _Float16* ql16  = wo16  + (size_t)4194304;  // 6,291,456 (-> vT 4,194,304)
  _Float16* qb16  = ql16  + (size_t)6291456;  // 12,582,912
  _Float16* kvf16 = qb16  + (size_t)12582912; // 2,359,296
  _Float16* kvn16 = kvf16 + (size_t)2359296;  // 2,097,152 (unused now)
  _Float16* fcc16 = kvn16 + (size_t)2097152;  // 65,536 (fcc||fcp adjacent)
  _Float16* fcp16 = fcc16 + (size_t)65536;    // 65,536
  _Float16* W1c   = fcp16 + (size_t)65536;    // 1,048,576
  _Float16* W2c   = W1c   + (size_t)1048576;  // 1,048,576
  // aliases
  _Float16* x216  = q16;
  _Float16* keff  = key16;
  _Float16* Cpe16 = q16;                      // Acat rows 0..1023
  _Float16* kvnA  = q16 + (size_t)524288;     // Acat rows 1024..5119 (ld 512)
  _Float16* Ccat  = wqa16;                    // 5120 x 256 merged C2|P2
  _Float16* pkv16 = wkva16;
  _Float16* vT    = ql16;

  // 1. all f32->f16 conversions + wkvb split
  conv_all<<<15744, 256, 0, stream>>>(query, key, wq_a, wq_b, wkv_a, wo, fc_c_w, fc_p_w,
                                      wkvb, q16, key16, wqa16, wqb16, wkva16, wo16,
                                      fcc16, fcp16, W1c, W2c);
  // 2. paired GEMM: ql16 = query@wq_a^T (384 blk) || kvf16 = key@wkv_a^T (160 blk)
  {
    GTask ta = {q16,   wqa16,  ql16,  nullptr, nullptr, 12, QR_, E_, E_, E_, QR_};
    GTask tb = {key16, wkva16, kvf16, nullptr, nullptr, 5,  576, E_, E_, E_, 576};
    gemm_pair<<<544, 256, 0, stream>>>(ta, tb, 384, 160);
  }
  // 3. fused LN(q in-place) + LN(kv -> kvnA) + rope_k(-> keff[:,128:192]) + PE(-> Cpe16)
  fused_ln<<<9728, 256, 0, stream>>>(ql16, kvf16, kvnA, q_ln_g, q_ln_b,
                                     kv_ln_g, kv_ln_b, keff, Cpe16);
  // 4. paired GEMM: qb16 = ql16@wq_b^T (768 blk) || Ccat = Acat@[fcc;fcp]^T+bias (80 blk)
  {
    GTask ta = {ql16,  wqb16, qb16, nullptr, nullptr, 24, 3072, QR_, QR_, QR_, 3072};
    GTask tb = {Cpe16, fcc16, Ccat, fc_c_b,  fc_p_b,  2,  256,  C_,  C_,  C_,  256};
    gemm_pair<<<848, 256, 0, stream>>>(ta, tb, 768, 80);
  }
  // 5. fused rope_q (qb16 in-place) + gate (-> pkv16)
  fused_rq_gate<<<4608, 256, 0, stream>>>(qb16, ps, Ccat, kvnA, pkv16);
  // 6. merged prep: z<32 -> keff[:,0:128] = pkv@W1c^T; z>=32 -> vT = (pkv@W2c^T)^T
  gemm16<true,false,false,false,true><<<dim3(1, T_/128, 64), 256, 0, stream>>>(
      pkv16, W1c, nullptr, (const float*)W2c, (float*)vT, keff,
      128, C_, C_, C_, 192, (long)T_*C_, 0L, 0L, 0L, 0L, 0L);
  // 7. flash attention -> x216 (Acat dead)
  attn_flash<<<dim3(1024), 256, 0, stream>>>(qb16, keff, vT, x216);
  // 8. out = x216 @ wo16^T (fp32 out)
  gemm16<false,false,false,false><<<dim3(E_/128, M/128), 256, 0, stream>>>(
      x216, wo16, nullptr, nullptr, out, nullptr, E_, E_, E_, E_, E_, 0,0,0,0,0,0);
}

// Round 15
// 322.141 us; speedup vs baseline: 1.3890x; 1.0149x over previous
//
#include <hip/hip_runtime.h>
#include <math.h>

#define S_ 2048
#define B_ 2
#define H_ 16
#define E_ 2048
#define QR_ 1536
#define NOPE_ 128
#define ROPE_ 64
#define C_ 512
#define VH_ 128
#define T_ 1024
#define LN1E4 9.210340371976184f
#define SCALE_ 0.07216878364870323f  // 192^-0.5

typedef _Float16 half8 __attribute__((ext_vector_type(8)));
typedef _Float16 half4 __attribute__((ext_vector_type(4)));
typedef __fp16 fp16x2 __attribute__((ext_vector_type(2)));
typedef float floatx4 __attribute__((ext_vector_type(4)));
#define MFMA16(a, b, c) __builtin_amdgcn_mfma_f32_16x16x32_f16(a, b, c, 0, 0, 0)

__device__ __forceinline__ void gload16(const _Float16* g, _Float16* l) {
  __builtin_amdgcn_global_load_lds(
      (__attribute__((address_space(1))) const void*)g,
      (__attribute__((address_space(3))) void*)l, 16, 0, 0);
}

// bijective XCD-chunked swizzle (m204)
__device__ __forceinline__ int xcd_swizzle(int orig, int nwg) {
  int q8 = nwg >> 3, r8 = nwg & 7, xcd = orig & 7, base = orig >> 3;
  return (xcd < r8 ? xcd * (q8 + 1) : r8 * (q8 + 1) + (xcd - r8) * q8) + base;
}

// ------- fused f32 -> f16 conversion for 8 tensors + wkvb split (W1c scaled, W2c) -------
__global__ __launch_bounds__(256) void conv_all(
    const float* __restrict__ q, const float* __restrict__ k,
    const float* __restrict__ wqa, const float* __restrict__ wqb,
    const float* __restrict__ wkva, const float* __restrict__ wo,
    const float* __restrict__ fcc, const float* __restrict__ fcp,
    const float* __restrict__ wkvb,
    _Float16* q16, _Float16* k16, _Float16* wqa16, _Float16* wqb16,
    _Float16* wkva16, _Float16* wo16, _Float16* fcc16, _Float16* fcp16,
    _Float16* W1c, _Float16* W2c)
{
  size_t i = (size_t)blockIdx.x * 256 + threadIdx.x;  // half8-chunk index
  if (i >= 3768320) {
    bool isW1 = i < 3899392;
    size_t j = i - (isW1 ? 3768320 : 3899392);
    int cch = j & 63, hd = (int)(j >> 6);
    int hh = hd >> 7, dd = hd & 127;
    const float* src = wkvb + ((size_t)(hh * 256 + (isW1 ? 0 : 128) + dd)) * 512 + cch * 8;
    float sc = isW1 ? SCALE_ : 1.f;
    float4 a = *(const float4*)src;
    float4 b = *(const float4*)(src + 4);
    half8 h = {(_Float16)(a.x * sc), (_Float16)(a.y * sc), (_Float16)(a.z * sc),
               (_Float16)(a.w * sc), (_Float16)(b.x * sc), (_Float16)(b.y * sc),
               (_Float16)(b.z * sc), (_Float16)(b.w * sc)};
    *(half8*)((isW1 ? W1c : W2c) + j * 8) = h;
    return;
  }
  const float* in; _Float16* out; size_t off;
  if      (i < 1048576) { in = q;    out = q16;    off = i; }
  else if (i < 2097152) { in = k;    out = k16;    off = i - 1048576; }
  else if (i < 2490368) { in = wqa;  out = wqa16;  off = i - 2097152; }
  else if (i < 3080192) { in = wqb;  out = wqb16;  off = i - 2490368; }
  else if (i < 3227648) { in = wkva; out = wkva16; off = i - 3080192; }
  else if (i < 3751936) { in = wo;   out = wo16;   off = i - 3227648; }
  else if (i < 3760128) { in = fcc;  out = fcc16;  off = i - 3751936; }
  else                  { in = fcp;  out = fcp16;  off = i - 3760128; }
  float4 a = ((const float4*)in)[2 * off];
  float4 b = ((const float4*)in)[2 * off + 1];
  half8 h = {(_Float16)a.x, (_Float16)a.y, (_Float16)a.z, (_Float16)a.w,
             (_Float16)b.x, (_Float16)b.y, (_Float16)b.z, (_Float16)b.w};
  *(half8*)(out + 8 * off) = h;
}

// ------- original f16 MFMA GEMM (used by prep DUAL + fp32-out final GEMM) -------
template<bool OUT16, bool NB, bool BIAS, bool TRANSC, bool DUAL = false>
__global__ __launch_bounds__(256) void gemm16(
    const _Float16* __restrict__ A, const _Float16* __restrict__ Bm,
    const float* __restrict__ bias, const float* __restrict__ bias2,
    float* __restrict__ Cf, _Float16* __restrict__ Ch,
    int N, int K, int lda, int ldb, int ldc,
    long sAb, long sAh, long sBb, long sBh, long sCb, long sCh)
{
  __shared__ __align__(16) _Float16 Asl[2][128 * 64];
  __shared__ __align__(16) _Float16 Bsl[2][128 * 64];
  int mode = 0;
  if (DUAL) {
    int zz = blockIdx.z;
    mode = zz >> 5;
    int z2 = zz & 31;
    int zb2 = z2 >> 4, zh2 = z2 & 15;
    A += (size_t)zb2 * sAb;
    const _Float16* Bsel = mode ? (const _Float16*)bias2 : Bm;
    Bm = Bsel + (size_t)zh2 * (128 * C_);
    if (mode) Ch = ((_Float16*)Cf) + ((size_t)(zb2 * H_ + zh2) * 128) * T_;
    else      Ch += ((size_t)(zb2 * H_ + zh2) * T_) * 192;
  } else {
    const int z = blockIdx.z, zb = z >> 4, zh = z & 15;
    A  += (size_t)zb * sAb + (size_t)zh * sAh;
    Bm += (size_t)zb * sBb + (size_t)zh * sBh;
    if (OUT16) Ch += (size_t)zb * sCb + (size_t)zh * sCh;
    else       Cf += (size_t)zb * sCb + (size_t)zh * sCh;
  }
  const int gx = gridDim.x;
  const int nwg = gx * gridDim.y;
  const int f = xcd_swizzle(blockIdx.y * gx + blockIdx.x, nwg);
  const int bm = (f / gx) * 128, bn = (f % gx) * 128;
  const int tid = threadIdx.x;
  const int w = tid >> 6, lane = tid & 63, l15 = lane & 15, g = lane >> 4;
  const int wm = (w >> 1) * 64, wn = (w & 1) * 64;
  const int srow = w * 32 + (lane >> 3);
  const int sch  = (lane & 7) ^ (lane >> 3);
  floatx4 acc[4][4];
  #pragma unroll
  for (int i = 0; i < 4; ++i)
    #pragma unroll
    for (int j = 0; j < 4; ++j) acc[i][j] = (floatx4){0.f, 0.f, 0.f, 0.f};

  auto STAGE = [&](int buf, int k0) {
    _Float16* al = &Asl[buf][w * 2048];
    _Float16* bl = &Bsl[buf][w * 2048];
    #pragma unroll
    for (int i = 0; i < 4; ++i)
      gload16(A + (size_t)(bm + srow + i * 8) * lda + k0 + sch * 8, al + i * 512);
    #pragma unroll
    for (int i = 0; i < 4; ++i)
      gload16(Bm + (size_t)(bn + srow + i * 8) * ldb + k0 + sch * 8, bl + i * 512);
  };

  STAGE(0, 0);
  int cur = 0;
  const int nIter = K >> 6;
  for (int it = 0; it < nIter; ++it) {
    const bool pf = (it + 1 < nIter);
    if (pf) STAGE(cur ^ 1, (it + 1) << 6);
    if (pf) asm volatile("s_waitcnt vmcnt(8)" ::: "memory");
    else    asm volatile("s_waitcnt vmcnt(0)" ::: "memory");
    __builtin_amdgcn_sched_barrier(0);
    __builtin_amdgcn_s_barrier();
    __builtin_amdgcn_sched_barrier(0);
    #pragma unroll
    for (int kk = 0; kk < 2; ++kk) {
      half8 af[4], bf[4];
      const int sw = ((kk * 4 + g) ^ (l15 & 7)) * 8;
      #pragma unroll
      for (int i = 0; i < 4; ++i) {
        af[i] = *(const half8*)&Asl[cur][(wm + i * 16 + l15) * 64 + sw];
        bf[i] = *(const half8*)&Bsl[cur][(wn + i * 16 + l15) * 64 + sw];
      }
      #pragma unroll
      for (int i = 0; i < 4; ++i)
        #pragma unroll
        for (int j = 0; j < 4; ++j)
          acc[i][j] = MFMA16(af[i], bf[j], acc[i][j]);
    }
    asm volatile("s_waitcnt lgkmcnt(0)" ::: "memory");
    __builtin_amdgcn_sched_barrier(0);
    __builtin_amdgcn_s_barrier();
    __builtin_amdgcn_sched_barrier(0);
    cur ^= 1;
  }

  if (DUAL) {
    if (mode) {
      #pragma unroll
      for (int i = 0; i < 4; ++i)
        #pragma unroll
        for (int j = 0; j < 4; ++j) {
          int row = bm + wm + i * 16 + g * 4;
          int col = wn + j * 16 + l15;
          half4 v = {(_Float16)acc[i][j][0], (_Float16)acc[i][j][1],
                     (_Float16)acc[i][j][2], (_Float16)acc[i][j][3]};
          *(half4*)(Ch + (size_t)col * T_ + row) = v;
        }
    } else {
      #pragma unroll
      for (int i = 0; i < 4; ++i)
        #pragma unroll
        for (int j = 0; j < 4; ++j)
          #pragma unroll
          for (int r = 0; r < 4; ++r) {
            int row = bm + wm + i * 16 + g * 4 + r;
            int col = wn + j * 16 + l15;
            Ch[(size_t)row * 192 + col] = (_Float16)acc[i][j][r];
          }
    }
  } else if (TRANSC) {
    #pragma unroll
    for (int i = 0; i < 4; ++i)
      #pragma unroll
      for (int j = 0; j < 4; ++j) {
        int row = bm + wm + i * 16 + g * 4;
        int col = bn + wn + j * 16 + l15;
        half4 v = {(_Float16)acc[i][j][0], (_Float16)acc[i][j][1],
                   (_Float16)acc[i][j][2], (_Float16)acc[i][j][3]};
        *(half4*)(Ch + (size_t)col * ldc + row) = v;
      }
  } else {
    #pragma unroll
    for (int i = 0; i < 4; ++i)
      #pragma unroll
      for (int j = 0; j < 4; ++j)
        #pragma unroll
        for (int r = 0; r < 4; ++r) {
          int row = bm + wm + i * 16 + g * 4 + r;
          int col = bn + wn + j * 16 + l15;
          if (!NB || col < N) {
            float v = acc[i][j][r];
            if (BIAS) v += (col < 128) ? bias[col] : bias2[col - 128];
            if (OUT16) Ch[(size_t)row * ldc + col] = (_Float16)v;
            else       Cf[(size_t)row * ldc + col] = v;
          }
        }
  }
}

// ------- paired GEMM: two independent GEMM tasks in one launch (f16 out) -------
struct GTask {
  const _Float16* A; const _Float16* B; _Float16* C;
  const float* b1; const float* b2;
  int gx, N, K, lda, ldb, ldc;
};

__global__ __launch_bounds__(256) void gemm_pair(GTask ta, GTask tb, int n0, int n1)
{
  __shared__ __align__(16) _Float16 Asl[2][128 * 64];
  __shared__ __align__(16) _Float16 Bsl[2][128 * 64];
  const bool second = blockIdx.x >= (unsigned)n0;
  GTask t = second ? tb : ta;
  const int fid = second ? blockIdx.x - n0 : blockIdx.x;
  const int nwg = second ? n1 : n0;
  const int f = xcd_swizzle(fid, nwg);
  const int bm = (f / t.gx) * 128, bn = (f % t.gx) * 128;
  const int tid = threadIdx.x;
  const int w = tid >> 6, lane = tid & 63, l15 = lane & 15, g = lane >> 4;
  const int wm = (w >> 1) * 64, wn = (w & 1) * 64;
  const int srow = w * 32 + (lane >> 3);
  const int sch  = (lane & 7) ^ (lane >> 3);
  floatx4 acc[4][4];
  #pragma unroll
  for (int i = 0; i < 4; ++i)
    #pragma unroll
    for (int j = 0; j < 4; ++j) acc[i][j] = (floatx4){0.f, 0.f, 0.f, 0.f};

  auto STAGE = [&](int buf, int k0) {
    _Float16* al = &Asl[buf][w * 2048];
    _Float16* bl = &Bsl[buf][w * 2048];
    #pragma unroll
    for (int i = 0; i < 4; ++i)
      gload16(t.A + (size_t)(bm + srow + i * 8) * t.lda + k0 + sch * 8, al + i * 512);
    #pragma unroll
    for (int i = 0; i < 4; ++i)
      gload16(t.B + (size_t)(bn + srow + i * 8) * t.ldb + k0 + sch * 8, bl + i * 512);
  };

  STAGE(0, 0);
  int cur = 0;
  const int nIter = t.K >> 6;
  for (int it = 0; it < nIter; ++it) {
    const bool pf = (it + 1 < nIter);
    if (pf) STAGE(cur ^ 1, (it + 1) << 6);
    if (pf) asm volatile("s_waitcnt vmcnt(8)" ::: "memory");
    else    asm volatile("s_waitcnt vmcnt(0)" ::: "memory");
    __builtin_amdgcn_sched_barrier(0);
    __builtin_amdgcn_s_barrier();
    __builtin_amdgcn_sched_barrier(0);
    #pragma unroll
    for (int kk = 0; kk < 2; ++kk) {
      half8 af[4], bf[4];
      const int sw = ((kk * 4 + g) ^ (l15 & 7)) * 8;
      #pragma unroll
      for (int i = 0; i < 4; ++i) {
        af[i] = *(const half8*)&Asl[cur][(wm + i * 16 + l15) * 64 + sw];
        bf[i] = *(const half8*)&Bsl[cur][(wn + i * 16 + l15) * 64 + sw];
      }
      #pragma unroll
      for (int i = 0; i < 4; ++i)
        #pragma unroll
        for (int j = 0; j < 4; ++j)
          acc[i][j] = MFMA16(af[i], bf[j], acc[i][j]);
    }
    asm volatile("s_waitcnt lgkmcnt(0)" ::: "memory");
    __builtin_amdgcn_sched_barrier(0);
    __builtin_amdgcn_s_barrier();
    __builtin_amdgcn_sched_barrier(0);
    cur ^= 1;
  }
  #pragma unroll
  for (int i = 0; i < 4; ++i)
    #pragma unroll
    for (int j = 0; j < 4; ++j)
      #pragma unroll
      for (int r = 0; r < 4; ++r) {
        int row = bm + wm + i * 16 + g * 4 + r;
        int col = bn + wn + j * 16 + l15;
        if (col < t.N) {
          float v = acc[i][j][r];
          if (t.b1) v += (col < 128) ? t.b1[col] : t.b2[col - 128];
          t.C[(size_t)row * t.ldc + col] = (_Float16)v;
        }
      }
}

// ------- fused LN(q) + LN(kv) + rope_k + PE table -------
__global__ __launch_bounds__(256) void fused_ln(
    _Float16* __restrict__ ql16, const _Float16* __restrict__ kvf16,
    _Float16* __restrict__ kvnA,
    const float* __restrict__ qg, const float* __restrict__ qb,
    const float* __restrict__ kg, const float* __restrict__ kb,
    _Float16* __restrict__ keff, _Float16* __restrict__ Cpe16)
{
  __shared__ float rs[4], rs2[4];
  int bid = blockIdx.x;
  const int tid = threadIdx.x;
  const int lane = tid & 63, w = tid >> 6;
  if (bid < 8192) {
    const bool isQ = bid < 4096;
    const int row = isQ ? bid : bid - 4096;
    const _Float16* x = isQ ? ql16 + (size_t)row * 1536 : kvf16 + (size_t)row * 576;
    _Float16* o = isQ ? ql16 + (size_t)row * 1536 : kvnA + (size_t)row * 512;
    const float* g_ = isQ ? qg : kg;
    const float* b_ = isQ ? qb : kb;
    const int L = isQ ? 1536 : 512;
    float s = 0.f, s2 = 0.f;
    for (int i = tid; i < L; i += 256) {
      float v = (float)x[i]; s += v; s2 += v * v;
    }
    #pragma unroll
    for (int off = 32; off; off >>= 1) {
      s  += __shfl_xor(s, off, 64);
      s2 += __shfl_xor(s2, off, 64);
    }
    if (lane == 0) { rs[w] = s; rs2[w] = s2; }
    __syncthreads();
    s  = rs[0] + rs[1] + rs[2] + rs[3];
    s2 = rs2[0] + rs2[1] + rs2[2] + rs2[3];
    float mean = s / L;
    float var = s2 / L - mean * mean;
    float inv = rsqrtf(var + 1e-5f);
    for (int i = tid; i < L; i += 256)
      o[i] = (_Float16)(((float)x[i] - mean) * inv * g_[i] + b_[i]);
    return;
  }
  bid -= 8192;
  if (bid < 512) {
    int u = bid * 4 + w;
    int t = u & (T_ - 1), b = u >> 10;
    const int srow = 2 * t + 1;
    const _Float16* p = kvf16 + ((size_t)(b * S_ + srow)) * 576 + C_;
    float o1 = 0.f, o2 = 0.f;
    if (lane < 32) {
      float invf = expf(-(float)lane * (LN1E4 / 32.f));
      float ang = (float)(S_ - 1 + srow) * invf;
      float sn, cs; sincosf(ang, &sn, &cs);
      float x1 = (float)p[2 * lane], x2 = (float)p[2 * lane + 1];
      o1 = x1 * cs - x2 * sn;
      o2 = x1 * sn + x2 * cs;
    }
    float ss = o1 * o1 + o2 * o2;
    #pragma unroll
    for (int off = 32; off; off >>= 1) ss += __shfl_xor(ss, off, 64);
    float nrm = fmaxf(sqrtf(ss), 1e-12f);
    if (lane < 32) {
      _Float16 h1 = (_Float16)(o1 / nrm), h2 = (_Float16)(o2 / nrm);
      #pragma unroll
      for (int h = 0; h < H_; ++h) {
        _Float16* o = keff + ((size_t)((b * H_ + h) * T_) + t) * 192 + NOPE_;
        o[2 * lane] = h1; o[2 * lane + 1] = h2;
      }
    }
    return;
  }
  bid -= 512;
  {
    const int t = bid;
    float dv = expf(-(float)(2 * tid) * (LN1E4 / 512.f));
    float ang = (float)t * dv;
    float sn, cs; sincosf(ang, &sn, &cs);
    Cpe16[(size_t)t * C_ + 2 * tid]     = (_Float16)sn;
    Cpe16[(size_t)t * C_ + 2 * tid + 1] = (_Float16)cs;
  }
}

// ------- fused rope_q + gate -------
__global__ __launch_bounds__(256) void fused_rq_gate(
    _Float16* __restrict__ qb16, const float* __restrict__ ps_ptr,
    const _Float16* __restrict__ Ccat, const _Float16* __restrict__ kvnA,
    _Float16* __restrict__ pkv16)
{
  int bid = blockIdx.x;
  const int tid = threadIdx.x;
  const int lane = tid & 63, w = tid >> 6;
  if (bid < 4096) {
    const int row = bid;
    const int s = row & (S_ - 1);
    float sn = 0.f, cs = 0.f;
    if (lane < 32) {
      float invf = expf(-(float)lane * (LN1E4 / 32.f));
      float ang = (float)(S_ - 1 + s) * invf;
      sincosf(ang, &sn, &cs);
    }
    const float psc = ps_ptr[0] * SCALE_;
    #pragma unroll
    for (int hh = 0; hh < 4; ++hh) {
      const int h = w + hh * 4;
      _Float16* p = qb16 + (size_t)row * 3072 + h * 192 + NOPE_;
      float o1 = 0.f, o2 = 0.f;
      if (lane < 32) {
        float x1 = (float)p[2 * lane], x2 = (float)p[2 * lane + 1];
        o1 = x1 * cs - x2 * sn;
        o2 = x1 * sn + x2 * cs;
      }
      float ss = o1 * o1 + o2 * o2;
      #pragma unroll
      for (int off = 32; off; off >>= 1) ss += __shfl_xor(ss, off, 64);
      float inv = psc / fmaxf(sqrtf(ss), 1e-12f);
      if (lane < 32) {
        p[2 * lane]     = (_Float16)(o1 * inv);
        p[2 * lane + 1] = (_Float16)(o2 * inv);
      }
    }
    return;
  }
  bid -= 4096;
  {
    int u = bid * 4 + w;
    int t = u & (T_ - 1), b = u >> 10;
    const int j = lane;
    const _Float16* c2 = Ccat + (size_t)t * 256;
    const _Float16* p0 = Ccat + (size_t)(1024 + b * S_ + 2 * t) * 256 + 128;
    const _Float16* p1 = p0 + 256;
    float d0 = (float)c2[j] * (float)p0[j] + (float)c2[j + 64] * (float)p0[j + 64];
    float d1 = (float)c2[j] * (float)p1[j] + (float)c2[j + 64] * (float)p1[j + 64];
    #pragma unroll
    for (int off = 32; off; off >>= 1) {
      d0 += __shfl_xor(d0, off, 64);
      d1 += __shfl_xor(d1, off, 64);
    }
    float w0 = 1.f / (1.f + expf(-d0));
    float w1 = 1.f / (1.f + expf(-d1));
    const _Float16* k0 = kvnA + ((size_t)(b * S_ + 2 * t)) * C_;
    const _Float16* k1 = k0 + C_;
    _Float16* o = pkv16 + ((size_t)(b * T_ + t)) * C_;
    #pragma unroll
    for (int it = 0; it < 2; ++it) {
      int c = j * 4 + it * 256;
      half4 a = *(const half4*)(k0 + c);
      half4 bb = *(const half4*)(k1 + c);
      half4 r;
      #pragma unroll
      for (int uu = 0; uu < 4; ++uu)
        r[uu] = (_Float16)(w0 * (float)a[uu] + w1 * (float)bb[uu]);
      *(half4*)(o + c) = r;
    }
  }
}

// ------- flash attention: double-buffered K/V LDS, ONE barrier per tile -------
__global__ __launch_bounds__(256, 2) void attn_flash(
    const _Float16* __restrict__ qb16, const _Float16* __restrict__ keff,
    const _Float16* __restrict__ vT, _Float16* __restrict__ x216)
{
  __shared__ __align__(16) _Float16 K_lds[2][64 * 192];  // 48 KB
  __shared__ __align__(16) _Float16 V_lds[2][128 * 64];  // 32 KB
  const int f = xcd_swizzle(blockIdx.x, 1024);
  const int st = f & 31, h = (f >> 5) & 15, b = f >> 9;
  const int tid = threadIdx.x, w = tid >> 6, lane = tid & 63;
  const int l15 = lane & 15, g = lane >> 4, l7 = lane & 7;
  const int rq = b * S_ + st * 64 + w * 16;
  const _Float16* qrow = qb16 + (size_t)(rq + l15) * 3072 + h * 192;
  half8 qB[6];
  #pragma unroll
  for (int kk = 0; kk < 6; ++kk) qB[kk] = *(const half8*)(qrow + kk * 32 + g * 8);
  floatx4 O[8];
  #pragma unroll
  for (int i = 0; i < 8; ++i) O[i] = (floatx4){0.f, 0.f, 0.f, 0.f};
  float m = -3e38f, l = 0.f;
  const _Float16* kb = keff + (size_t)(b * H_ + h) * T_ * 192;
  const _Float16* vb = vT   + (size_t)(b * H_ + h) * 128 * T_;

  int ksrc[6], ksw[6], vsrc[4], vsw[4];
  #pragma unroll
  for (int p = 0; p < 6; ++p) {
    int c = tid + p * 256;
    int r = c / 24, dc = c % 24;
    ksrc[p] = r * 192 + dc * 8;
    ksw[p]  = r * 192 + ((dc ^ (r & 7)) * 8);
  }
  #pragma unroll
  for (int p = 0; p < 4; ++p) {
    int c = tid + p * 256;
    int r = c >> 3, dc = c & 7;
    vsrc[p] = r * T_ + dc * 8;
    vsw[p]  = r * 64 + ((dc ^ (r & 7)) * 8);
  }
  int kswr[6], vswr[2];
  #pragma unroll
  for (int kk = 0; kk < 6; ++kk) kswr[kk] = ((kk * 4 + g) ^ l7) * 8;
  #pragma unroll
  for (int kc = 0; kc < 2; ++kc) vswr[kc] = ((kc * 4 + g) ^ l7) * 8;

  half8 kreg[6], vreg[4];
  #pragma unroll
  for (int p = 0; p < 6; ++p) kreg[p] = *(const half8*)(kb + ksrc[p]);
  #pragma unroll
  for (int p = 0; p < 4; ++p) vreg[p] = *(const half8*)(vb + vsrc[p]);
  #pragma unroll
  for (int p = 0; p < 6; ++p) *(half8*)&K_lds[0][ksw[p]] = kreg[p];
  #pragma unroll
  for (int p = 0; p < 4; ++p) *(half8*)&V_lds[0][vsw[p]] = vreg[p];
  __syncthreads();

  const int srcA = l15 + ((g & 1) << 5);
  const int srcB = srcA + 16;
  const bool hi = (g >> 1) != 0;

  int cur = 0;
  for (int kt = 0; kt < 16; ++kt) {
    if (kt < 15) {
      const int t1 = (kt + 1) * 64;
      #pragma unroll
      for (int p = 0; p < 6; ++p)
        kreg[p] = *(const half8*)(kb + (size_t)t1 * 192 + ksrc[p]);
      #pragma unroll
      for (int p = 0; p < 4; ++p)
        vreg[p] = *(const half8*)(vb + t1 + vsrc[p]);
    }
    floatx4 sc[4];
    #pragma unroll
    for (int i = 0; i < 4; ++i) sc[i] = (floatx4){0.f, 0.f, 0.f, 0.f};
    __builtin_amdgcn_s_setprio(1);
    #pragma unroll
    for (int kk = 0; kk < 6; ++kk)
      #pragma unroll
      for (int ct = 0; ct < 4; ++ct)
        sc[ct] = MFMA16(
            *(const half8*)&K_lds[cur][(ct * 16 + l15) * 192 + kswr[kk]],
            qB[kk], sc[ct]);
    __builtin_amdgcn_s_setprio(0);
    float pm = sc[0][0];
    #pragma unroll
    for (int ct = 0; ct < 4; ++ct)
      #pragma unroll
      for (int r = 0; r < 4; ++r) pm = fmaxf(pm, sc[ct][r]);
    pm = fmaxf(pm, __shfl_xor(pm, 16, 64));
    pm = fmaxf(pm, __shfl_xor(pm, 32, 64));
    int ok = pm <= m + 8.f;
    if (!__all(ok)) {
      float mn = fmaxf(m, pm);
      float sf = __expf(m - mn);
      m = mn; l *= sf;
      float sfO[4];
      #pragma unroll
      for (int r = 0; r < 4; ++r) sfO[r] = __shfl(sf, g * 4 + r, 64);
      #pragma unroll
      for (int cc = 0; cc < 8; ++cc) {
        O[cc][0] *= sfO[0]; O[cc][1] *= sfO[1];
        O[cc][2] *= sfO[2]; O[cc][3] *= sfO[3];
      }
    }
    float rs = 0.f;
    #pragma unroll
    for (int ct = 0; ct < 4; ++ct)
      #pragma unroll
      for (int r = 0; r < 4; ++r) {
        float e = __expf(sc[ct][r] - m);
        sc[ct][r] = e; rs += e;
      }
    rs += __shfl_xor(rs, 16, 64);
    rs += __shfl_xor(rs, 32, 64);
    l += rs;
    unsigned pk[4][2];
    #pragma unroll
    for (int ct = 0; ct < 4; ++ct) {
      union { fp16x2 h; unsigned u; } c0, c1;
      c0.h = __builtin_amdgcn_cvt_pkrtz(sc[ct][0], sc[ct][1]);
      c1.h = __builtin_amdgcn_cvt_pkrtz(sc[ct][2], sc[ct][3]);
      pk[ct][0] = c0.u; pk[ct][1] = c1.u;
    }
    __builtin_amdgcn_s_setprio(1);
    #pragma unroll
    for (int kc = 0; kc < 2; ++kc) {
      unsigned a0 = __shfl((int)pk[2 * kc][0], srcA, 64);
      unsigned b0 = __shfl((int)pk[2 * kc + 1][0], srcA, 64);
      unsigned a1 = __shfl((int)pk[2 * kc][1], srcA, 64);
      unsigned b1 = __shfl((int)pk[2 * kc + 1][1], srcA, 64);
      unsigned a2 = __shfl((int)pk[2 * kc][0], srcB, 64);
      unsigned b2 = __shfl((int)pk[2 * kc + 1][0], srcB, 64);
      unsigned a3 = __shfl((int)pk[2 * kc][1], srcB, 64);
      unsigned b3 = __shfl((int)pk[2 * kc + 1][1], srcB, 64);
      union { unsigned u[4]; half8 h; } pa;
      pa.u[0] = hi ? b0 : a0;
      pa.u[1] = hi ? b1 : a1;
      pa.u[2] = hi ? b2 : a2;
      pa.u[3] = hi ? b3 : a3;
      #pragma unroll
      for (int cc = 0; cc < 8; ++cc)
        O[cc] = MFMA16(pa.h,
            *(const half8*)&V_lds[cur][(cc * 16 + l15) * 64 + vswr[kc]], O[cc]);
    }
    __builtin_amdgcn_s_setprio(0);
    if (kt < 15) {
      // write next tile into the ALTERNATE buffer (no one reads it this iter),
      // then ONE barrier covers both write-visibility and read-completion.
      #pragma unroll
      for (int p = 0; p < 6; ++p) *(half8*)&K_lds[cur ^ 1][ksw[p]] = kreg[p];
      #pragma unroll
      for (int p = 0; p < 4; ++p) *(half8*)&V_lds[cur ^ 1][vsw[p]] = vreg[p];
      __syncthreads();
      cur ^= 1;
    }
  }
  float il = 1.f / l;
  float ilO[4];
  #pragma unroll
  for (int r = 0; r < 4; ++r) ilO[r] = __shfl(il, g * 4 + r, 64);
  #pragma unroll
  for (int cc = 0; cc < 8; ++cc)
    #pragma unroll
    for (int r = 0; r < 4; ++r)
      x216[(size_t)(rq + g * 4 + r) * 2048 + h * 128 + cc * 16 + l15] =
          (_Float16)(O[cc][r] * ilO[r]);
}

extern "C" void kernel_launch(void* const* d_in, const int* in_sizes, int n_in,
                              void* d_out, int out_size, void* d_ws, size_t ws_size,
                              hipStream_t stream)
{
  (void)in_sizes; (void)n_in; (void)out_size; (void)ws_size;
  const float* query  = (const float*)d_in[0];
  const float* key    = (const float*)d_in[1];
  const float* wq_a   = (const float*)d_in[3];
  const float* q_ln_g = (const float*)d_in[4];
  const float* q_ln_b = (const float*)d_in[5];
  const float* wq_b   = (const float*)d_in[6];
  const float* wkv_a  = (const float*)d_in[7];
  const float* kv_ln_g= (const float*)d_in[8];
  const float* kv_ln_b= (const float*)d_in[9];
  const float* wkvb   = (const float*)d_in[10];
  const float* wo     = (const float*)d_in[11];
  const float* fc_c_w = (const float*)d_in[12];
  const float* fc_c_b = (const float*)d_in[13];
  const float* fc_p_w = (const float*)d_in[14];
  const float* fc_p_b = (const float*)d_in[15];
  const float* ps     = (const float*)d_in[16];
  float* out = (float*)d_out;

  const int M = B_ * S_; // 4096
  _Float16* hws   = (_Float16*)d_ws;
  _Float16* q16   = hws;                      // (-> Acat[Cpe|kvnA] -> x216)
  _Float16* key16 = q16   + (size_t)8388608;  // (-> keff)
  _Float16* wqa16 = key16 + (size_t)8388608;  // (-> Ccat)
  _Float16* wqb16 = wqa16 + (size_t)3145728;
  _Float16* wkva16= wqb16 + (size_t)4718592;  // (-> pkv16)
  _Float16* wo16  = wkva16+ (size_t)1179648;
  _Float16* ql16  = wo16  + (size_t)4194304;  // (-> vT)
  _Float16* qb16  = ql16  + (size_t)6291456;
  _Float16* kvf16 = qb16  + (size_t)12582912;
  _Float16* kvn16 = kvf16 + (size_t)2359296;
  _Float16* fcc16 = kvn16 + (size_t)2097152;
  _Float16* fcp16 = fcc16 + (size_t)65536;
  _Float16* W1c   = fcp16 + (size_t)65536;
  _Float16* W2c   = W1c   + (size_t)1048576;
  // aliases
  _Float16* x216  = q16;
  _Float16* keff  = key16;
  _Float16* Cpe16 = q16;
  _Float16* kvnA  = q16 + (size_t)524288;
  _Float16* Ccat  = wqa16;
  _Float16* pkv16 = wkva16;
  _Float16* vT    = ql16;

  // 1. all f32->f16 conversions + wkvb split
  conv_all<<<15744, 256, 0, stream>>>(query, key, wq_a, wq_b, wkv_a, wo, fc_c_w, fc_p_w,
                                      wkvb, q16, key16, wqa16, wqb16, wkva16, wo16,
                                      fcc16, fcp16, W1c, W2c);
  // 2. paired GEMM: ql16 = query@wq_a^T || kvf16 = key@wkv_a^T
  {
    GTask ta = {q16,   wqa16,  ql16,  nullptr, nullptr, 12, QR_, E_, E_, E_, QR_};
    GTask tb = {key16, wkva16, kvf16, nullptr, nullptr, 5,  576, E_, E_, E_, 576};
    gemm_pair<<<544, 256, 0, stream>>>(ta, tb, 384, 160);
  }
  // 3. fused LN(q) + LN(kv) + rope_k + PE
  fused_ln<<<9728, 256, 0, stream>>>(ql16, kvf16, kvnA, q_ln_g, q_ln_b,
                                     kv_ln_g, kv_ln_b, keff, Cpe16);
  // 4. paired GEMM: qb16 = ql16@wq_b^T || Ccat = Acat@[fcc;fcp]^T+bias
  {
    GTask ta = {ql16,  wqb16, qb16, nullptr, nullptr, 24, 3072, QR_, QR_, QR_, 3072};
    GTask tb = {Cpe16, fcc16, Ccat, fc_c_b,  fc_p_b,  2,  256,  C_,  C_,  C_,  256};
    gemm_pair<<<848, 256, 0, stream>>>(ta, tb, 768, 80);
  }
  // 5. fused rope_q + gate
  fused_rq_gate<<<4608, 256, 0, stream>>>(qb16, ps, Ccat, kvnA, pkv16);
  // 6. merged prep: keff[:,0:128] = pkv@W1c^T || vT = (pkv@W2c^T)^T
  gemm16<true,false,false,false,true><<<dim3(1, T_/128, 64), 256, 0, stream>>>(
      pkv16, W1c, nullptr, (const float*)W2c, (float*)vT, keff,
      128, C_, C_, C_, 192, (long)T_*C_, 0L, 0L, 0L, 0L, 0L);
  // 7. flash attention (double-buffered, single barrier/tile) -> x216
  attn_flash<<<dim3(1024), 256, 0, stream>>>(qb16, keff, vT, x216);
  // 8. out = x216 @ wo16^T (fp32 out)
  gemm16<false,false,false,false><<<dim3(E_/128, M/128), 256, 0, stream>>>(
      x216, wo16, nullptr, nullptr, out, nullptr, E_, E_, E_, E_, E_, 0,0,0,0,0,0);
}

// Round 16
// 313.106 us; speedup vs baseline: 1.4291x; 1.0289x over previous
//
#include <hip/hip_runtime.h>
#include <math.h>

#define S_ 2048
#define B_ 2
#define H_ 16
#define E_ 2048
#define QR_ 1536
#define NOPE_ 128
#define ROPE_ 64
#define C_ 512
#define VH_ 128
#define T_ 1024
#define LN1E4 9.210340371976184f
#define SCALE_ 0.07216878364870323f  // 192^-0.5

typedef _Float16 half8 __attribute__((ext_vector_type(8)));
typedef _Float16 half4 __attribute__((ext_vector_type(4)));
typedef __fp16 fp16x2 __attribute__((ext_vector_type(2)));
typedef float floatx4 __attribute__((ext_vector_type(4)));
#define MFMA16(a, b, c) __builtin_amdgcn_mfma_f32_16x16x32_f16(a, b, c, 0, 0, 0)

__device__ __forceinline__ void gload16(const _Float16* g, _Float16* l) {
  __builtin_amdgcn_global_load_lds(
      (__attribute__((address_space(1))) const void*)g,
      (__attribute__((address_space(3))) void*)l, 16, 0, 0);
}

// bijective XCD-chunked swizzle (m204)
__device__ __forceinline__ int xcd_swizzle(int orig, int nwg) {
  int q8 = nwg >> 3, r8 = nwg & 7, xcd = orig & 7, base = orig >> 3;
  return (xcd < r8 ? xcd * (q8 + 1) : r8 * (q8 + 1) + (xcd - r8) * q8) + base;
}

// ------- conv part A: query/key/wqa/wkva only (deps of the first GEMM) -------
__global__ __launch_bounds__(256) void conv_a(
    const float* __restrict__ q, const float* __restrict__ k,
    const float* __restrict__ wqa, const float* __restrict__ wkva,
    _Float16* q16, _Float16* k16, _Float16* wqa16, _Float16* wkva16)
{
  size_t i = (size_t)blockIdx.x * 256 + threadIdx.x;  // half8-chunk index
  const float* in; _Float16* out; size_t off;
  if      (i < 1048576) { in = q;    out = q16;    off = i; }
  else if (i < 2097152) { in = k;    out = k16;    off = i - 1048576; }
  else if (i < 2490368) { in = wqa;  out = wqa16;  off = i - 2097152; }
  else                  { in = wkva; out = wkva16; off = i - 2490368; }
  float4 a = ((const float4*)in)[2 * off];
  float4 b = ((const float4*)in)[2 * off + 1];
  half8 h = {(_Float16)a.x, (_Float16)a.y, (_Float16)a.z, (_Float16)a.w,
             (_Float16)b.x, (_Float16)b.y, (_Float16)b.z, (_Float16)b.w};
  *(half8*)(out + 8 * off) = h;
}

// ------- original f16 MFMA GEMM (used by prep DUAL + fp32-out final GEMM) -------
template<bool OUT16, bool NB, bool BIAS, bool TRANSC, bool DUAL = false>
__global__ __launch_bounds__(256) void gemm16(
    const _Float16* __restrict__ A, const _Float16* __restrict__ Bm,
    const float* __restrict__ bias, const float* __restrict__ bias2,
    float* __restrict__ Cf, _Float16* __restrict__ Ch,
    int N, int K, int lda, int ldb, int ldc,
    long sAb, long sAh, long sBb, long sBh, long sCb, long sCh)
{
  __shared__ __align__(16) _Float16 Asl[2][128 * 64];
  __shared__ __align__(16) _Float16 Bsl[2][128 * 64];
  int mode = 0;
  if (DUAL) {
    int zz = blockIdx.z;
    mode = zz >> 5;
    int z2 = zz & 31;
    int zb2 = z2 >> 4, zh2 = z2 & 15;
    A += (size_t)zb2 * sAb;
    const _Float16* Bsel = mode ? (const _Float16*)bias2 : Bm;
    Bm = Bsel + (size_t)zh2 * (128 * C_);
    if (mode) Ch = ((_Float16*)Cf) + ((size_t)(zb2 * H_ + zh2) * 128) * T_;
    else      Ch += ((size_t)(zb2 * H_ + zh2) * T_) * 192;
  } else {
    const int z = blockIdx.z, zb = z >> 4, zh = z & 15;
    A  += (size_t)zb * sAb + (size_t)zh * sAh;
    Bm += (size_t)zb * sBb + (size_t)zh * sBh;
    if (OUT16) Ch += (size_t)zb * sCb + (size_t)zh * sCh;
    else       Cf += (size_t)zb * sCb + (size_t)zh * sCh;
  }
  const int gx = gridDim.x;
  const int nwg = gx * gridDim.y;
  const int f = xcd_swizzle(blockIdx.y * gx + blockIdx.x, nwg);
  const int bm = (f / gx) * 128, bn = (f % gx) * 128;
  const int tid = threadIdx.x;
  const int w = tid >> 6, lane = tid & 63, l15 = lane & 15, g = lane >> 4;
  const int wm = (w >> 1) * 64, wn = (w & 1) * 64;
  const int srow = w * 32 + (lane >> 3);
  const int sch  = (lane & 7) ^ (lane >> 3);
  floatx4 acc[4][4];
  #pragma unroll
  for (int i = 0; i < 4; ++i)
    #pragma unroll
    for (int j = 0; j < 4; ++j) acc[i][j] = (floatx4){0.f, 0.f, 0.f, 0.f};

  auto STAGE = [&](int buf, int k0) {
    _Float16* al = &Asl[buf][w * 2048];
    _Float16* bl = &Bsl[buf][w * 2048];
    #pragma unroll
    for (int i = 0; i < 4; ++i)
      gload16(A + (size_t)(bm + srow + i * 8) * lda + k0 + sch * 8, al + i * 512);
    #pragma unroll
    for (int i = 0; i < 4; ++i)
      gload16(Bm + (size_t)(bn + srow + i * 8) * ldb + k0 + sch * 8, bl + i * 512);
  };

  STAGE(0, 0);
  int cur = 0;
  const int nIter = K >> 6;
  for (int it = 0; it < nIter; ++it) {
    const bool pf = (it + 1 < nIter);
    if (pf) STAGE(cur ^ 1, (it + 1) << 6);
    if (pf) asm volatile("s_waitcnt vmcnt(8)" ::: "memory");
    else    asm volatile("s_waitcnt vmcnt(0)" ::: "memory");
    __builtin_amdgcn_sched_barrier(0);
    __builtin_amdgcn_s_barrier();
    __builtin_amdgcn_sched_barrier(0);
    #pragma unroll
    for (int kk = 0; kk < 2; ++kk) {
      half8 af[4], bf[4];
      const int sw = ((kk * 4 + g) ^ (l15 & 7)) * 8;
      #pragma unroll
      for (int i = 0; i < 4; ++i) {
        af[i] = *(const half8*)&Asl[cur][(wm + i * 16 + l15) * 64 + sw];
        bf[i] = *(const half8*)&Bsl[cur][(wn + i * 16 + l15) * 64 + sw];
      }
      #pragma unroll
      for (int i = 0; i < 4; ++i)
        #pragma unroll
        for (int j = 0; j < 4; ++j)
          acc[i][j] = MFMA16(af[i], bf[j], acc[i][j]);
    }
    asm volatile("s_waitcnt lgkmcnt(0)" ::: "memory");
    __builtin_amdgcn_sched_barrier(0);
    __builtin_amdgcn_s_barrier();
    __builtin_amdgcn_sched_barrier(0);
    cur ^= 1;
  }

  if (DUAL) {
    if (mode) {
      #pragma unroll
      for (int i = 0; i < 4; ++i)
        #pragma unroll
        for (int j = 0; j < 4; ++j) {
          int row = bm + wm + i * 16 + g * 4;
          int col = wn + j * 16 + l15;
          half4 v = {(_Float16)acc[i][j][0], (_Float16)acc[i][j][1],
                     (_Float16)acc[i][j][2], (_Float16)acc[i][j][3]};
          *(half4*)(Ch + (size_t)col * T_ + row) = v;
        }
    } else {
      #pragma unroll
      for (int i = 0; i < 4; ++i)
        #pragma unroll
        for (int j = 0; j < 4; ++j)
          #pragma unroll
          for (int r = 0; r < 4; ++r) {
            int row = bm + wm + i * 16 + g * 4 + r;
            int col = wn + j * 16 + l15;
            Ch[(size_t)row * 192 + col] = (_Float16)acc[i][j][r];
          }
    }
  } else if (TRANSC) {
    #pragma unroll
    for (int i = 0; i < 4; ++i)
      #pragma unroll
      for (int j = 0; j < 4; ++j) {
        int row = bm + wm + i * 16 + g * 4;
        int col = bn + wn + j * 16 + l15;
        half4 v = {(_Float16)acc[i][j][0], (_Float16)acc[i][j][1],
                   (_Float16)acc[i][j][2], (_Float16)acc[i][j][3]};
        *(half4*)(Ch + (size_t)col * ldc + row) = v;
      }
  } else {
    #pragma unroll
    for (int i = 0; i < 4; ++i)
      #pragma unroll
      for (int j = 0; j < 4; ++j)
        #pragma unroll
        for (int r = 0; r < 4; ++r) {
          int row = bm + wm + i * 16 + g * 4 + r;
          int col = bn + wn + j * 16 + l15;
          if (!NB || col < N) {
            float v = acc[i][j][r];
            if (BIAS) v += (col < 128) ? bias[col] : bias2[col - 128];
            if (OUT16) Ch[(size_t)row * ldc + col] = (_Float16)v;
            else       Cf[(size_t)row * ldc + col] = v;
          }
        }
  }
}

// ------- paired GEMM + deferred conversions: three task segments in one launch -------
struct GTask {
  const _Float16* A; const _Float16* B; _Float16* C;
  const float* b1; const float* b2;
  int gx, N, K, lda, ldb, ldc;
};
struct CTask {  // deferred f32->f16 conversions
  const float* wqb; const float* wo; const float* fcc; const float* fcp;
  const float* wkvb;
  _Float16* wqb16; _Float16* wo16; _Float16* fcc16; _Float16* fcp16;
  _Float16* W1c; _Float16* W2c;
};

__global__ __launch_bounds__(256) void gemm_pair(GTask ta, GTask tb, CTask tc,
                                                 int n0, int n1)
{
  __shared__ __align__(16) _Float16 Asl[2][128 * 64];
  __shared__ __align__(16) _Float16 Bsl[2][128 * 64];
  if ((int)blockIdx.x >= n0 + n1) {
    // conversion segment
    size_t j = (size_t)(blockIdx.x - n0 - n1) * 256 + threadIdx.x;
    const float* in; _Float16* out; size_t off; float sc = 1.f;
    if (j < 589824)       { in = tc.wqb; out = tc.wqb16; off = j; }
    else if (j < 1114112) { in = tc.wo;  out = tc.wo16;  off = j - 589824; }
    else if (j < 1122304) { in = tc.fcc; out = tc.fcc16; off = j - 1114112; }
    else if (j < 1130496) { in = tc.fcp; out = tc.fcp16; off = j - 1122304; }
    else {
      size_t j2 = j - 1130496;
      bool isW1 = j2 < 131072;
      size_t jj = isW1 ? j2 : j2 - 131072;
      int cch = jj & 63, hd = (int)(jj >> 6);
      int hh = hd >> 7, dd = hd & 127;
      in = tc.wkvb + ((size_t)(hh * 256 + (isW1 ? 0 : 128) + dd)) * 512 + cch * 8
           - 0;  // base handled below via off=0 trick
      out = (isW1 ? tc.W1c : tc.W2c) + jj * 8;
      sc = isW1 ? SCALE_ : 1.f;
      float4 a = *(const float4*)in;
      float4 b = *(const float4*)(in + 4);
      half8 h = {(_Float16)(a.x * sc), (_Float16)(a.y * sc), (_Float16)(a.z * sc),
                 (_Float16)(a.w * sc), (_Float16)(b.x * sc), (_Float16)(b.y * sc),
                 (_Float16)(b.z * sc), (_Float16)(b.w * sc)};
      *(half8*)out = h;
      return;
    }
    float4 a = ((const float4*)in)[2 * off];
    float4 b = ((const float4*)in)[2 * off + 1];
    half8 h = {(_Float16)a.x, (_Float16)a.y, (_Float16)a.z, (_Float16)a.w,
               (_Float16)b.x, (_Float16)b.y, (_Float16)b.z, (_Float16)b.w};
    *(half8*)(out + 8 * off) = h;
    return;
  }
  const bool second = (int)blockIdx.x >= n0;
  GTask t = second ? tb : ta;
  const int fid = second ? blockIdx.x - n0 : blockIdx.x;
  const int nwg = second ? n1 : n0;
  const int f = xcd_swizzle(fid, nwg);
  const int bm = (f / t.gx) * 128, bn = (f % t.gx) * 128;
  const int tid = threadIdx.x;
  const int w = tid >> 6, lane = tid & 63, l15 = lane & 15, g = lane >> 4;
  const int wm = (w >> 1) * 64, wn = (w & 1) * 64;
  const int srow = w * 32 + (lane >> 3);
  const int sch  = (lane & 7) ^ (lane >> 3);
  floatx4 acc[4][4];
  #pragma unroll
  for (int i = 0; i < 4; ++i)
    #pragma unroll
    for (int j = 0; j < 4; ++j) acc[i][j] = (floatx4){0.f, 0.f, 0.f, 0.f};

  auto STAGE = [&](int buf, int k0) {
    _Float16* al = &Asl[buf][w * 2048];
    _Float16* bl = &Bsl[buf][w * 2048];
    #pragma unroll
    for (int i = 0; i < 4; ++i)
      gload16(t.A + (size_t)(bm + srow + i * 8) * t.lda + k0 + sch * 8, al + i * 512);
    #pragma unroll
    for (int i = 0; i < 4; ++i)
      gload16(t.B + (size_t)(bn + srow + i * 8) * t.ldb + k0 + sch * 8, bl + i * 512);
  };

  STAGE(0, 0);
  int cur = 0;
  const int nIter = t.K >> 6;
  for (int it = 0; it < nIter; ++it) {
    const bool pf = (it + 1 < nIter);
    if (pf) STAGE(cur ^ 1, (it + 1) << 6);
    if (pf) asm volatile("s_waitcnt vmcnt(8)" ::: "memory");
    else    asm volatile("s_waitcnt vmcnt(0)" ::: "memory");
    __builtin_amdgcn_sched_barrier(0);
    __builtin_amdgcn_s_barrier();
    __builtin_amdgcn_sched_barrier(0);
    #pragma unroll
    for (int kk = 0; kk < 2; ++kk) {
      half8 af[4], bf[4];
      const int sw = ((kk * 4 + g) ^ (l15 & 7)) * 8;
      #pragma unroll
      for (int i = 0; i < 4; ++i) {
        af[i] = *(const half8*)&Asl[cur][(wm + i * 16 + l15) * 64 + sw];
        bf[i] = *(const half8*)&Bsl[cur][(wn + i * 16 + l15) * 64 + sw];
      }
      #pragma unroll
      for (int i = 0; i < 4; ++i)
        #pragma unroll
        for (int j = 0; j < 4; ++j)
          acc[i][j] = MFMA16(af[i], bf[j], acc[i][j]);
    }
    asm volatile("s_waitcnt lgkmcnt(0)" ::: "memory");
    __builtin_amdgcn_sched_barrier(0);
    __builtin_amdgcn_s_barrier();
    __builtin_amdgcn_sched_barrier(0);
    cur ^= 1;
  }
  #pragma unroll
  for (int i = 0; i < 4; ++i)
    #pragma unroll
    for (int j = 0; j < 4; ++j)
      #pragma unroll
      for (int r = 0; r < 4; ++r) {
        int row = bm + wm + i * 16 + g * 4 + r;
        int col = bn + wn + j * 16 + l15;
        if (col < t.N) {
          float v = acc[i][j][r];
          if (t.b1) v += (col < 128) ? t.b1[col] : t.b2[col - 128];
          t.C[(size_t)row * t.ldc + col] = (_Float16)v;
        }
      }
}

// ------- fused LN(q) + LN(kv) + rope_k + PE table -------
__global__ __launch_bounds__(256) void fused_ln(
    _Float16* __restrict__ ql16, const _Float16* __restrict__ kvf16,
    _Float16* __restrict__ kvnA,
    const float* __restrict__ qg, const float* __restrict__ qb,
    const float* __restrict__ kg, const float* __restrict__ kb,
    _Float16* __restrict__ keff, _Float16* __restrict__ Cpe16)
{
  __shared__ float rs[4], rs2[4];
  int bid = blockIdx.x;
  const int tid = threadIdx.x;
  const int lane = tid & 63, w = tid >> 6;
  if (bid < 8192) {
    const bool isQ = bid < 4096;
    const int row = isQ ? bid : bid - 4096;
    const _Float16* x = isQ ? ql16 + (size_t)row * 1536 : kvf16 + (size_t)row * 576;
    _Float16* o = isQ ? ql16 + (size_t)row * 1536 : kvnA + (size_t)row * 512;
    const float* g_ = isQ ? qg : kg;
    const float* b_ = isQ ? qb : kb;
    const int L = isQ ? 1536 : 512;
    float s = 0.f, s2 = 0.f;
    for (int i = tid; i < L; i += 256) {
      float v = (float)x[i]; s += v; s2 += v * v;
    }
    #pragma unroll
    for (int off = 32; off; off >>= 1) {
      s  += __shfl_xor(s, off, 64);
      s2 += __shfl_xor(s2, off, 64);
    }
    if (lane == 0) { rs[w] = s; rs2[w] = s2; }
    __syncthreads();
    s  = rs[0] + rs[1] + rs[2] + rs[3];
    s2 = rs2[0] + rs2[1] + rs2[2] + rs2[3];
    float mean = s / L;
    float var = s2 / L - mean * mean;
    float inv = rsqrtf(var + 1e-5f);
    for (int i = tid; i < L; i += 256)
      o[i] = (_Float16)(((float)x[i] - mean) * inv * g_[i] + b_[i]);
    return;
  }
  bid -= 8192;
  if (bid < 512) {
    int u = bid * 4 + w;
    int t = u & (T_ - 1), b = u >> 10;
    const int srow = 2 * t + 1;
    const _Float16* p = kvf16 + ((size_t)(b * S_ + srow)) * 576 + C_;
    float o1 = 0.f, o2 = 0.f;
    if (lane < 32) {
      float invf = expf(-(float)lane * (LN1E4 / 32.f));
      float ang = (float)(S_ - 1 + srow) * invf;
      float sn, cs; sincosf(ang, &sn, &cs);
      float x1 = (float)p[2 * lane], x2 = (float)p[2 * lane + 1];
      o1 = x1 * cs - x2 * sn;
      o2 = x1 * sn + x2 * cs;
    }
    float ss = o1 * o1 + o2 * o2;
    #pragma unroll
    for (int off = 32; off; off >>= 1) ss += __shfl_xor(ss, off, 64);
    float nrm = fmaxf(sqrtf(ss), 1e-12f);
    if (lane < 32) {
      _Float16 h1 = (_Float16)(o1 / nrm), h2 = (_Float16)(o2 / nrm);
      #pragma unroll
      for (int h = 0; h < H_; ++h) {
        _Float16* o = keff + ((size_t)((b * H_ + h) * T_) + t) * 192 + NOPE_;
        o[2 * lane] = h1; o[2 * lane + 1] = h2;
      }
    }
    return;
  }
  bid -= 512;
  {
    const int t = bid;
    float dv = expf(-(float)(2 * tid) * (LN1E4 / 512.f));
    float ang = (float)t * dv;
    float sn, cs; sincosf(ang, &sn, &cs);
    Cpe16[(size_t)t * C_ + 2 * tid]     = (_Float16)sn;
    Cpe16[(size_t)t * C_ + 2 * tid + 1] = (_Float16)cs;
  }
}

// ------- fused rope_q + gate -------
__global__ __launch_bounds__(256) void fused_rq_gate(
    _Float16* __restrict__ qb16, const float* __restrict__ ps_ptr,
    const _Float16* __restrict__ Ccat, const _Float16* __restrict__ kvnA,
    _Float16* __restrict__ pkv16)
{
  int bid = blockIdx.x;
  const int tid = threadIdx.x;
  const int lane = tid & 63, w = tid >> 6;
  if (bid < 4096) {
    const int row = bid;
    const int s = row & (S_ - 1);
    float sn = 0.f, cs = 0.f;
    if (lane < 32) {
      float invf = expf(-(float)lane * (LN1E4 / 32.f));
      float ang = (float)(S_ - 1 + s) * invf;
      sincosf(ang, &sn, &cs);
    }
    const float psc = ps_ptr[0] * SCALE_;
    #pragma unroll
    for (int hh = 0; hh < 4; ++hh) {
      const int h = w + hh * 4;
      _Float16* p = qb16 + (size_t)row * 3072 + h * 192 + NOPE_;
      float o1 = 0.f, o2 = 0.f;
      if (lane < 32) {
        float x1 = (float)p[2 * lane], x2 = (float)p[2 * lane + 1];
        o1 = x1 * cs - x2 * sn;
        o2 = x1 * sn + x2 * cs;
      }
      float ss = o1 * o1 + o2 * o2;
      #pragma unroll
      for (int off = 32; off; off >>= 1) ss += __shfl_xor(ss, off, 64);
      float inv = psc / fmaxf(sqrtf(ss), 1e-12f);
      if (lane < 32) {
        p[2 * lane]     = (_Float16)(o1 * inv);
        p[2 * lane + 1] = (_Float16)(o2 * inv);
      }
    }
    return;
  }
  bid -= 4096;
  {
    int u = bid * 4 + w;
    int t = u & (T_ - 1), b = u >> 10;
    const int j = lane;
    const _Float16* c2 = Ccat + (size_t)t * 256;
    const _Float16* p0 = Ccat + (size_t)(1024 + b * S_ + 2 * t) * 256 + 128;
    const _Float16* p1 = p0 + 256;
    float d0 = (float)c2[j] * (float)p0[j] + (float)c2[j + 64] * (float)p0[j + 64];
    float d1 = (float)c2[j] * (float)p1[j] + (float)c2[j + 64] * (float)p1[j + 64];
    #pragma unroll
    for (int off = 32; off; off >>= 1) {
      d0 += __shfl_xor(d0, off, 64);
      d1 += __shfl_xor(d1, off, 64);
    }
    float w0 = 1.f / (1.f + expf(-d0));
    float w1 = 1.f / (1.f + expf(-d1));
    const _Float16* k0 = kvnA + ((size_t)(b * S_ + 2 * t)) * C_;
    const _Float16* k1 = k0 + C_;
    _Float16* o = pkv16 + ((size_t)(b * T_ + t)) * C_;
    #pragma unroll
    for (int it = 0; it < 2; ++it) {
      int c = j * 4 + it * 256;
      half4 a = *(const half4*)(k0 + c);
      half4 bb = *(const half4*)(k1 + c);
      half4 r;
      #pragma unroll
      for (int uu = 0; uu < 4; ++uu)
        r[uu] = (_Float16)(w0 * (float)a[uu] + w1 * (float)bb[uu]);
      *(half4*)(o + c) = r;
    }
  }
}

// ------- flash attention: double-buffered K/V LDS, ONE barrier per tile -------
__global__ __launch_bounds__(256, 2) void attn_flash(
    const _Float16* __restrict__ qb16, const _Float16* __restrict__ keff,
    const _Float16* __restrict__ vT, _Float16* __restrict__ x216)
{
  __shared__ __align__(16) _Float16 K_lds[2][64 * 192];  // 48 KB
  __shared__ __align__(16) _Float16 V_lds[2][128 * 64];  // 32 KB
  const int f = xcd_swizzle(blockIdx.x, 1024);
  const int st = f & 31, h = (f >> 5) & 15, b = f >> 9;
  const int tid = threadIdx.x, w = tid >> 6, lane = tid & 63;
  const int l15 = lane & 15, g = lane >> 4, l7 = lane & 7;
  const int rq = b * S_ + st * 64 + w * 16;
  const _Float16* qrow = qb16 + (size_t)(rq + l15) * 3072 + h * 192;
  half8 qB[6];
  #pragma unroll
  for (int kk = 0; kk < 6; ++kk) qB[kk] = *(const half8*)(qrow + kk * 32 + g * 8);
  floatx4 O[8];
  #pragma unroll
  for (int i = 0; i < 8; ++i) O[i] = (floatx4){0.f, 0.f, 0.f, 0.f};
  float m = -3e38f, l = 0.f;
  const _Float16* kb = keff + (size_t)(b * H_ + h) * T_ * 192;
  const _Float16* vb = vT   + (size_t)(b * H_ + h) * 128 * T_;

  int ksrc[6], ksw[6], vsrc[4], vsw[4];
  #pragma unroll
  for (int p = 0; p < 6; ++p) {
    int c = tid + p * 256;
    int r = c / 24, dc = c % 24;
    ksrc[p] = r * 192 + dc * 8;
    ksw[p]  = r * 192 + ((dc ^ (r & 7)) * 8);
  }
  #pragma unroll
  for (int p = 0; p < 4; ++p) {
    int c = tid + p * 256;
    int r = c >> 3, dc = c & 7;
    vsrc[p] = r * T_ + dc * 8;
    vsw[p]  = r * 64 + ((dc ^ (r & 7)) * 8);
  }
  int kswr[6], vswr[2];
  #pragma unroll
  for (int kk = 0; kk < 6; ++kk) kswr[kk] = ((kk * 4 + g) ^ l7) * 8;
  #pragma unroll
  for (int kc = 0; kc < 2; ++kc) vswr[kc] = ((kc * 4 + g) ^ l7) * 8;

  half8 kreg[6], vreg[4];
  #pragma unroll
  for (int p = 0; p < 6; ++p) kreg[p] = *(const half8*)(kb + ksrc[p]);
  #pragma unroll
  for (int p = 0; p < 4; ++p) vreg[p] = *(const half8*)(vb + vsrc[p]);
  #pragma unroll
  for (int p = 0; p < 6; ++p) *(half8*)&K_lds[0][ksw[p]] = kreg[p];
  #pragma unroll
  for (int p = 0; p < 4; ++p) *(half8*)&V_lds[0][vsw[p]] = vreg[p];
  __syncthreads();

  const int srcA = l15 + ((g & 1) << 5);
  const int srcB = srcA + 16;
  const bool hi = (g >> 1) != 0;

  int cur = 0;
  for (int kt = 0; kt < 16; ++kt) {
    if (kt < 15) {
      const int t1 = (kt + 1) * 64;
      #pragma unroll
      for (int p = 0; p < 6; ++p)
        kreg[p] = *(const half8*)(kb + (size_t)t1 * 192 + ksrc[p]);
      #pragma unroll
      for (int p = 0; p < 4; ++p)
        vreg[p] = *(const half8*)(vb + t1 + vsrc[p]);
    }
    floatx4 sc[4];
    #pragma unroll
    for (int i = 0; i < 4; ++i) sc[i] = (floatx4){0.f, 0.f, 0.f, 0.f};
    __builtin_amdgcn_s_setprio(1);
    #pragma unroll
    for (int kk = 0; kk < 6; ++kk)
      #pragma unroll
      for (int ct = 0; ct < 4; ++ct)
        sc[ct] = MFMA16(
            *(const half8*)&K_lds[cur][(ct * 16 + l15) * 192 + kswr[kk]],
            qB[kk], sc[ct]);
    __builtin_amdgcn_s_setprio(0);
    float pm = sc[0][0];
    #pragma unroll
    for (int ct = 0; ct < 4; ++ct)
      #pragma unroll
      for (int r = 0; r < 4; ++r) pm = fmaxf(pm, sc[ct][r]);
    pm = fmaxf(pm, __shfl_xor(pm, 16, 64));
    pm = fmaxf(pm, __shfl_xor(pm, 32, 64));
    int ok = pm <= m + 8.f;
    if (!__all(ok)) {
      float mn = fmaxf(m, pm);
      float sf = __expf(m - mn);
      m = mn; l *= sf;
      float sfO[4];
      #pragma unroll
      for (int r = 0; r < 4; ++r) sfO[r] = __shfl(sf, g * 4 + r, 64);
      #pragma unroll
      for (int cc = 0; cc < 8; ++cc) {
        O[cc][0] *= sfO[0]; O[cc][1] *= sfO[1];
        O[cc][2] *= sfO[2]; O[cc][3] *= sfO[3];
      }
    }
    float rs = 0.f;
    #pragma unroll
    for (int ct = 0; ct < 4; ++ct)
      #pragma unroll
      for (int r = 0; r < 4; ++r) {
        float e = __expf(sc[ct][r] - m);
        sc[ct][r] = e; rs += e;
      }
    rs += __shfl_xor(rs, 16, 64);
    rs += __shfl_xor(rs, 32, 64);
    l += rs;
    unsigned pk[4][2];
    #pragma unroll
    for (int ct = 0; ct < 4; ++ct) {
      union { fp16x2 h; unsigned u; } c0, c1;
      c0.h = __builtin_amdgcn_cvt_pkrtz(sc[ct][0], sc[ct][1]);
      c1.h = __builtin_amdgcn_cvt_pkrtz(sc[ct][2], sc[ct][3]);
      pk[ct][0] = c0.u; pk[ct][1] = c1.u;
    }
    __builtin_amdgcn_s_setprio(1);
    #pragma unroll
    for (int kc = 0; kc < 2; ++kc) {
      unsigned a0 = __shfl((int)pk[2 * kc][0], srcA, 64);
      unsigned b0 = __shfl((int)pk[2 * kc + 1][0], srcA, 64);
      unsigned a1 = __shfl((int)pk[2 * kc][1], srcA, 64);
      unsigned b1 = __shfl((int)pk[2 * kc + 1][1], srcA, 64);
      unsigned a2 = __shfl((int)pk[2 * kc][0], srcB, 64);
      unsigned b2 = __shfl((int)pk[2 * kc + 1][0], srcB, 64);
      unsigned a3 = __shfl((int)pk[2 * kc][1], srcB, 64);
      unsigned b3 = __shfl((int)pk[2 * kc + 1][1], srcB, 64);
      union { unsigned u[4]; half8 h; } pa;
      pa.u[0] = hi ? b0 : a0;
      pa.u[1] = hi ? b1 : a1;
      pa.u[2] = hi ? b2 : a2;
      pa.u[3] = hi ? b3 : a3;
      #pragma unroll
      for (int cc = 0; cc < 8; ++cc)
        O[cc] = MFMA16(pa.h,
            *(const half8*)&V_lds[cur][(cc * 16 + l15) * 64 + vswr[kc]], O[cc]);
    }
    __builtin_amdgcn_s_setprio(0);
    if (kt < 15) {
      #pragma unroll
      for (int p = 0; p < 6; ++p) *(half8*)&K_lds[cur ^ 1][ksw[p]] = kreg[p];
      #pragma unroll
      for (int p = 0; p < 4; ++p) *(half8*)&V_lds[cur ^ 1][vsw[p]] = vreg[p];
      __syncthreads();
      cur ^= 1;
    }
  }
  float il = 1.f / l;
  float ilO[4];
  #pragma unroll
  for (int r = 0; r < 4; ++r) ilO[r] = __shfl(il, g * 4 + r, 64);
  #pragma unroll
  for (int cc = 0; cc < 8; ++cc)
    #pragma unroll
    for (int r = 0; r < 4; ++r)
      x216[(size_t)(rq + g * 4 + r) * 2048 + h * 128 + cc * 16 + l15] =
          (_Float16)(O[cc][r] * ilO[r]);
}

extern "C" void kernel_launch(void* const* d_in, const int* in_sizes, int n_in,
                              void* d_out, int out_size, void* d_ws, size_t ws_size,
                              hipStream_t stream)
{
  (void)in_sizes; (void)n_in; (void)out_size; (void)ws_size;
  const float* query  = (const float*)d_in[0];
  const float* key    = (const float*)d_in[1];
  const float* wq_a   = (const float*)d_in[3];
  const float* q_ln_g = (const float*)d_in[4];
  const float* q_ln_b = (const float*)d_in[5];
  const float* wq_b   = (const float*)d_in[6];
  const float* wkv_a  = (const float*)d_in[7];
  const float* kv_ln_g= (const float*)d_in[8];
  const float* kv_ln_b= (const float*)d_in[9];
  const float* wkvb   = (const float*)d_in[10];
  const float* wo     = (const float*)d_in[11];
  const float* fc_c_w = (const float*)d_in[12];
  const float* fc_c_b = (const float*)d_in[13];
  const float* fc_p_w = (const float*)d_in[14];
  const float* fc_p_b = (const float*)d_in[15];
  const float* ps     = (const float*)d_in[16];
  float* out = (float*)d_out;

  const int M = B_ * S_; // 4096
  _Float16* hws   = (_Float16*)d_ws;
  _Float16* q16   = hws;                      // (-> Acat[Cpe|kvnA] -> x216)
  _Float16* key16 = q16   + (size_t)8388608;  // (-> keff)
  _Float16* wqa16 = key16 + (size_t)8388608;  // (-> Ccat)
  _Float16* wqb16 = wqa16 + (size_t)3145728;
  _Float16* wkva16= wqb16 + (size_t)4718592;  // (-> pkv16)
  _Float16* wo16  = wkva16+ (size_t)1179648;
  _Float16* ql16  = wo16  + (size_t)4194304;  // (-> vT)
  _Float16* qb16  = ql16  + (size_t)6291456;
  _Float16* kvf16 = qb16  + (size_t)12582912;
  _Float16* kvn16 = kvf16 + (size_t)2359296;
  _Float16* fcc16 = kvn16 + (size_t)2097152;
  _Float16* fcp16 = fcc16 + (size_t)65536;
  _Float16* W1c   = fcp16 + (size_t)65536;
  _Float16* W2c   = W1c   + (size_t)1048576;
  // aliases
  _Float16* x216  = q16;
  _Float16* keff  = key16;
  _Float16* Cpe16 = q16;
  _Float16* kvnA  = q16 + (size_t)524288;
  _Float16* Ccat  = wqa16;
  _Float16* pkv16 = wkva16;
  _Float16* vT    = ql16;

  // 1. conv part A (deps of the first GEMM only)
  conv_a<<<10304, 256, 0, stream>>>(query, key, wq_a, wkv_a,
                                    q16, key16, wqa16, wkva16);
  // 2. paired GEMM + deferred conversions (wqb/wo/fcc/fcp/wkvb hidden under GEMM)
  {
    GTask ta = {q16,   wqa16,  ql16,  nullptr, nullptr, 12, QR_, E_, E_, E_, QR_};
    GTask tb = {key16, wkva16, kvf16, nullptr, nullptr, 5,  576, E_, E_, E_, 576};
    CTask tc = {wq_b, wo, fc_c_w, fc_p_w, wkvb,
                wqb16, wo16, fcc16, fcp16, W1c, W2c};
    gemm_pair<<<544 + 5440, 256, 0, stream>>>(ta, tb, tc, 384, 160);
  }
  // 3. fused LN(q) + LN(kv) + rope_k + PE
  fused_ln<<<9728, 256, 0, stream>>>(ql16, kvf16, kvnA, q_ln_g, q_ln_b,
                                     kv_ln_g, kv_ln_b, keff, Cpe16);
  // 4. paired GEMM: qb16 = ql16@wq_b^T || Ccat = Acat@[fcc;fcp]^T+bias
  {
    GTask ta = {ql16,  wqb16, qb16, nullptr, nullptr, 24, 3072, QR_, QR_, QR_, 3072};
    GTask tb = {Cpe16, fcc16, Ccat, fc_c_b,  fc_p_b,  2,  256,  C_,  C_,  C_,  256};
    CTask tc = {};
    gemm_pair<<<848, 256, 0, stream>>>(ta, tb, tc, 768, 80);
  }
  // 5. fused rope_q + gate
  fused_rq_gate<<<4608, 256, 0, stream>>>(qb16, ps, Ccat, kvnA, pkv16);
  // 6. merged prep: keff[:,0:128] = pkv@W1c^T || vT = (pkv@W2c^T)^T
  gemm16<true,false,false,false,true><<<dim3(1, T_/128, 64), 256, 0, stream>>>(
      pkv16, W1c, nullptr, (const float*)W2c, (float*)vT, keff,
      128, C_, C_, C_, 192, (long)T_*C_, 0L, 0L, 0L, 0L, 0L);
  // 7. flash attention (double-buffered, single barrier/tile) -> x216
  attn_flash<<<dim3(1024), 256, 0, stream>>>(qb16, keff, vT, x216);
  // 8. out = x216 @ wo16^T (fp32 out)
  gemm16<false,false,false,false><<<dim3(E_/128, M/128), 256, 0, stream>>>(
      x216, wo16, nullptr, nullptr, out, nullptr, E_, E_, E_, E_, E_, 0,0,0,0,0,0);
}

// Round 17
// 311.468 us; speedup vs baseline: 1.4366x; 1.0053x over previous
//
#include <hip/hip_runtime.h>
#include <math.h>

#define S_ 2048
#define B_ 2
#define H_ 16
#define E_ 2048
#define QR_ 1536
#define NOPE_ 128
#define ROPE_ 64
#define C_ 512
#define VH_ 128
#define T_ 1024
#define LN1E4 9.210340371976184f
#define SCALE_ 0.07216878364870323f  // 192^-0.5

typedef _Float16 half8 __attribute__((ext_vector_type(8)));
typedef _Float16 half4 __attribute__((ext_vector_type(4)));
typedef __fp16 fp16x2 __attribute__((ext_vector_type(2)));
typedef float floatx4 __attribute__((ext_vector_type(4)));
#define MFMA16(a, b, c) __builtin_amdgcn_mfma_f32_16x16x32_f16(a, b, c, 0, 0, 0)

__device__ __forceinline__ void gload16(const _Float16* g, _Float16* l) {
  __builtin_amdgcn_global_load_lds(
      (__attribute__((address_space(1))) const void*)g,
      (__attribute__((address_space(3))) void*)l, 16, 0, 0);
}

// bijective XCD-chunked swizzle (m204)
__device__ __forceinline__ int xcd_swizzle(int orig, int nwg) {
  int q8 = nwg >> 3, r8 = nwg & 7, xcd = orig & 7, base = orig >> 3;
  return (xcd < r8 ? xcd * (q8 + 1) : r8 * (q8 + 1) + (xcd - r8) * q8) + base;
}

// ------- conv part A: query/key/wqa/wkva only (deps of the first GEMM) -------
__global__ __launch_bounds__(256) void conv_a(
    const float* __restrict__ q, const float* __restrict__ k,
    const float* __restrict__ wqa, const float* __restrict__ wkva,
    _Float16* q16, _Float16* k16, _Float16* wqa16, _Float16* wkva16)
{
  size_t i = (size_t)blockIdx.x * 256 + threadIdx.x;  // half8-chunk index
  const float* in; _Float16* out; size_t off;
  if      (i < 1048576) { in = q;    out = q16;    off = i; }
  else if (i < 2097152) { in = k;    out = k16;    off = i - 1048576; }
  else if (i < 2490368) { in = wqa;  out = wqa16;  off = i - 2097152; }
  else                  { in = wkva; out = wkva16; off = i - 2490368; }
  float4 a = ((const float4*)in)[2 * off];
  float4 b = ((const float4*)in)[2 * off + 1];
  half8 h = {(_Float16)a.x, (_Float16)a.y, (_Float16)a.z, (_Float16)a.w,
             (_Float16)b.x, (_Float16)b.y, (_Float16)b.z, (_Float16)b.w};
  *(half8*)(out + 8 * off) = h;
}

// ------- original f16 MFMA GEMM (used by prep DUAL + fp32-out final GEMM) -------
template<bool OUT16, bool NB, bool BIAS, bool TRANSC, bool DUAL = false>
__global__ __launch_bounds__(256) void gemm16(
    const _Float16* __restrict__ A, const _Float16* __restrict__ Bm,
    const float* __restrict__ bias, const float* __restrict__ bias2,
    float* __restrict__ Cf, _Float16* __restrict__ Ch,
    int N, int K, int lda, int ldb, int ldc,
    long sAb, long sAh, long sBb, long sBh, long sCb, long sCh)
{
  __shared__ __align__(16) _Float16 Asl[2][128 * 64];
  __shared__ __align__(16) _Float16 Bsl[2][128 * 64];
  int mode = 0;
  if (DUAL) {
    int zz = blockIdx.z;
    mode = zz >> 5;
    int z2 = zz & 31;
    int zb2 = z2 >> 4, zh2 = z2 & 15;
    A += (size_t)zb2 * sAb;
    const _Float16* Bsel = mode ? (const _Float16*)bias2 : Bm;
    Bm = Bsel + (size_t)zh2 * (128 * C_);
    if (mode) Ch = ((_Float16*)Cf) + ((size_t)(zb2 * H_ + zh2) * 128) * T_;
    else      Ch += ((size_t)(zb2 * H_ + zh2) * T_) * 192;
  } else {
    const int z = blockIdx.z, zb = z >> 4, zh = z & 15;
    A  += (size_t)zb * sAb + (size_t)zh * sAh;
    Bm += (size_t)zb * sBb + (size_t)zh * sBh;
    if (OUT16) Ch += (size_t)zb * sCb + (size_t)zh * sCh;
    else       Cf += (size_t)zb * sCb + (size_t)zh * sCh;
  }
  const int gx = gridDim.x;
  const int nwg = gx * gridDim.y;
  const int f = xcd_swizzle(blockIdx.y * gx + blockIdx.x, nwg);
  const int bm = (f / gx) * 128, bn = (f % gx) * 128;
  const int tid = threadIdx.x;
  const int w = tid >> 6, lane = tid & 63, l15 = lane & 15, g = lane >> 4;
  const int wm = (w >> 1) * 64, wn = (w & 1) * 64;
  const int srow = w * 32 + (lane >> 3);
  const int sch  = (lane & 7) ^ (lane >> 3);
  floatx4 acc[4][4];
  #pragma unroll
  for (int i = 0; i < 4; ++i)
    #pragma unroll
    for (int j = 0; j < 4; ++j) acc[i][j] = (floatx4){0.f, 0.f, 0.f, 0.f};

  auto STAGE = [&](int buf, int k0) {
    _Float16* al = &Asl[buf][w * 2048];
    _Float16* bl = &Bsl[buf][w * 2048];
    #pragma unroll
    for (int i = 0; i < 4; ++i)
      gload16(A + (size_t)(bm + srow + i * 8) * lda + k0 + sch * 8, al + i * 512);
    #pragma unroll
    for (int i = 0; i < 4; ++i)
      gload16(Bm + (size_t)(bn + srow + i * 8) * ldb + k0 + sch * 8, bl + i * 512);
  };

  STAGE(0, 0);
  int cur = 0;
  const int nIter = K >> 6;
  for (int it = 0; it < nIter; ++it) {
    const bool pf = (it + 1 < nIter);
    if (pf) STAGE(cur ^ 1, (it + 1) << 6);
    if (pf) asm volatile("s_waitcnt vmcnt(8)" ::: "memory");
    else    asm volatile("s_waitcnt vmcnt(0)" ::: "memory");
    __builtin_amdgcn_sched_barrier(0);
    __builtin_amdgcn_s_barrier();
    __builtin_amdgcn_sched_barrier(0);
    #pragma unroll
    for (int kk = 0; kk < 2; ++kk) {
      half8 af[4], bf[4];
      const int sw = ((kk * 4 + g) ^ (l15 & 7)) * 8;
      #pragma unroll
      for (int i = 0; i < 4; ++i) {
        af[i] = *(const half8*)&Asl[cur][(wm + i * 16 + l15) * 64 + sw];
        bf[i] = *(const half8*)&Bsl[cur][(wn + i * 16 + l15) * 64 + sw];
      }
      #pragma unroll
      for (int i = 0; i < 4; ++i)
        #pragma unroll
        for (int j = 0; j < 4; ++j)
          acc[i][j] = MFMA16(af[i], bf[j], acc[i][j]);
    }
    asm volatile("s_waitcnt lgkmcnt(0)" ::: "memory");
    __builtin_amdgcn_sched_barrier(0);
    __builtin_amdgcn_s_barrier();
    __builtin_amdgcn_sched_barrier(0);
    cur ^= 1;
  }

  if (DUAL) {
    if (mode) {
      #pragma unroll
      for (int i = 0; i < 4; ++i)
        #pragma unroll
        for (int j = 0; j < 4; ++j) {
          int row = bm + wm + i * 16 + g * 4;
          int col = wn + j * 16 + l15;
          half4 v = {(_Float16)acc[i][j][0], (_Float16)acc[i][j][1],
                     (_Float16)acc[i][j][2], (_Float16)acc[i][j][3]};
          *(half4*)(Ch + (size_t)col * T_ + row) = v;
        }
    } else {
      #pragma unroll
      for (int i = 0; i < 4; ++i)
        #pragma unroll
        for (int j = 0; j < 4; ++j)
          #pragma unroll
          for (int r = 0; r < 4; ++r) {
            int row = bm + wm + i * 16 + g * 4 + r;
            int col = wn + j * 16 + l15;
            Ch[(size_t)row * 192 + col] = (_Float16)acc[i][j][r];
          }
    }
  } else if (TRANSC) {
    #pragma unroll
    for (int i = 0; i < 4; ++i)
      #pragma unroll
      for (int j = 0; j < 4; ++j) {
        int row = bm + wm + i * 16 + g * 4;
        int col = bn + wn + j * 16 + l15;
        half4 v = {(_Float16)acc[i][j][0], (_Float16)acc[i][j][1],
                   (_Float16)acc[i][j][2], (_Float16)acc[i][j][3]};
        *(half4*)(Ch + (size_t)col * ldc + row) = v;
      }
  } else {
    #pragma unroll
    for (int i = 0; i < 4; ++i)
      #pragma unroll
      for (int j = 0; j < 4; ++j)
        #pragma unroll
        for (int r = 0; r < 4; ++r) {
          int row = bm + wm + i * 16 + g * 4 + r;
          int col = bn + wn + j * 16 + l15;
          if (!NB || col < N) {
            float v = acc[i][j][r];
            if (BIAS) v += (col < 128) ? bias[col] : bias2[col - 128];
            if (OUT16) Ch[(size_t)row * ldc + col] = (_Float16)v;
            else       Cf[(size_t)row * ldc + col] = v;
          }
        }
  }
}

// ------- paired GEMM + deferred conversions: three task segments in one launch -------
struct GTask {
  const _Float16* A; const _Float16* B; _Float16* C;
  const float* b1; const float* b2;
  int gx, N, K, lda, ldb, ldc;
};
struct CTask {  // deferred f32->f16 conversions
  const float* wqb; const float* wo; const float* fcc; const float* fcp;
  const float* wkvb;
  _Float16* wqb16; _Float16* wo16; _Float16* fcc16; _Float16* fcp16;
  _Float16* W1c; _Float16* W2c;
};

__global__ __launch_bounds__(256) void gemm_pair(GTask ta, GTask tb, CTask tc,
                                                 int n0, int n1)
{
  __shared__ __align__(16) _Float16 Asl[2][128 * 64];
  __shared__ __align__(16) _Float16 Bsl[2][128 * 64];
  if ((int)blockIdx.x >= n0 + n1) {
    size_t j = (size_t)(blockIdx.x - n0 - n1) * 256 + threadIdx.x;
    const float* in; _Float16* out; size_t off; float sc = 1.f;
    if (j < 589824)       { in = tc.wqb; out = tc.wqb16; off = j; }
    else if (j < 1114112) { in = tc.wo;  out = tc.wo16;  off = j - 589824; }
    else if (j < 1122304) { in = tc.fcc; out = tc.fcc16; off = j - 1114112; }
    else if (j < 1130496) { in = tc.fcp; out = tc.fcp16; off = j - 1122304; }
    else {
      size_t j2 = j - 1130496;
      bool isW1 = j2 < 131072;
      size_t jj = isW1 ? j2 : j2 - 131072;
      int cch = jj & 63, hd = (int)(jj >> 6);
      int hh = hd >> 7, dd = hd & 127;
      in = tc.wkvb + ((size_t)(hh * 256 + (isW1 ? 0 : 128) + dd)) * 512 + cch * 8;
      out = (isW1 ? tc.W1c : tc.W2c) + jj * 8;
      sc = isW1 ? SCALE_ : 1.f;
      float4 a = *(const float4*)in;
      float4 b = *(const float4*)(in + 4);
      half8 h = {(_Float16)(a.x * sc), (_Float16)(a.y * sc), (_Float16)(a.z * sc),
                 (_Float16)(a.w * sc), (_Float16)(b.x * sc), (_Float16)(b.y * sc),
                 (_Float16)(b.z * sc), (_Float16)(b.w * sc)};
      *(half8*)out = h;
      return;
    }
    float4 a = ((const float4*)in)[2 * off];
    float4 b = ((const float4*)in)[2 * off + 1];
    half8 h = {(_Float16)a.x, (_Float16)a.y, (_Float16)a.z, (_Float16)a.w,
               (_Float16)b.x, (_Float16)b.y, (_Float16)b.z, (_Float16)b.w};
    *(half8*)(out + 8 * off) = h;
    return;
  }
  const bool second = (int)blockIdx.x >= n0;
  GTask t = second ? tb : ta;
  const int fid = second ? blockIdx.x - n0 : blockIdx.x;
  const int nwg = second ? n1 : n0;
  const int f = xcd_swizzle(fid, nwg);
  const int bm = (f / t.gx) * 128, bn = (f % t.gx) * 128;
  const int tid = threadIdx.x;
  const int w = tid >> 6, lane = tid & 63, l15 = lane & 15, g = lane >> 4;
  const int wm = (w >> 1) * 64, wn = (w & 1) * 64;
  const int srow = w * 32 + (lane >> 3);
  const int sch  = (lane & 7) ^ (lane >> 3);
  floatx4 acc[4][4];
  #pragma unroll
  for (int i = 0; i < 4; ++i)
    #pragma unroll
    for (int j = 0; j < 4; ++j) acc[i][j] = (floatx4){0.f, 0.f, 0.f, 0.f};

  auto STAGE = [&](int buf, int k0) {
    _Float16* al = &Asl[buf][w * 2048];
    _Float16* bl = &Bsl[buf][w * 2048];
    #pragma unroll
    for (int i = 0; i < 4; ++i)
      gload16(t.A + (size_t)(bm + srow + i * 8) * t.lda + k0 + sch * 8, al + i * 512);
    #pragma unroll
    for (int i = 0; i < 4; ++i)
      gload16(t.B + (size_t)(bn + srow + i * 8) * t.ldb + k0 + sch * 8, bl + i * 512);
  };

  STAGE(0, 0);
  int cur = 0;
  const int nIter = t.K >> 6;
  for (int it = 0; it < nIter; ++it) {
    const bool pf = (it + 1 < nIter);
    if (pf) STAGE(cur ^ 1, (it + 1) << 6);
    if (pf) asm volatile("s_waitcnt vmcnt(8)" ::: "memory");
    else    asm volatile("s_waitcnt vmcnt(0)" ::: "memory");
    __builtin_amdgcn_sched_barrier(0);
    __builtin_amdgcn_s_barrier();
    __builtin_amdgcn_sched_barrier(0);
    #pragma unroll
    for (int kk = 0; kk < 2; ++kk) {
      half8 af[4], bf[4];
      const int sw = ((kk * 4 + g) ^ (l15 & 7)) * 8;
      #pragma unroll
      for (int i = 0; i < 4; ++i) {
        af[i] = *(const half8*)&Asl[cur][(wm + i * 16 + l15) * 64 + sw];
        bf[i] = *(const half8*)&Bsl[cur][(wn + i * 16 + l15) * 64 + sw];
      }
      #pragma unroll
      for (int i = 0; i < 4; ++i)
        #pragma unroll
        for (int j = 0; j < 4; ++j)
          acc[i][j] = MFMA16(af[i], bf[j], acc[i][j]);
    }
    asm volatile("s_waitcnt lgkmcnt(0)" ::: "memory");
    __builtin_amdgcn_sched_barrier(0);
    __builtin_amdgcn_s_barrier();
    __builtin_amdgcn_sched_barrier(0);
    cur ^= 1;
  }
  #pragma unroll
  for (int i = 0; i < 4; ++i)
    #pragma unroll
    for (int j = 0; j < 4; ++j)
      #pragma unroll
      for (int r = 0; r < 4; ++r) {
        int row = bm + wm + i * 16 + g * 4 + r;
        int col = bn + wn + j * 16 + l15;
        if (col < t.N) {
          float v = acc[i][j][r];
          if (t.b1) v += (col < 128) ? t.b1[col] : t.b2[col - 128];
          t.C[(size_t)row * t.ldc + col] = (_Float16)v;
        }
      }
}

// ------- fused LN(q) + LN(kv) + rope_k + PE table (vectorized half8) -------
// blocks 0..4095: LN q row (192 active threads x half8); 4096..5119: LN kv (4 rows,
// one per wave, 64 lanes x half8, wave-local reduce); 5120..5631: rope_k;
// 5632..6655: PE row.
__global__ __launch_bounds__(256) void fused_ln(
    _Float16* __restrict__ ql16, const _Float16* __restrict__ kvf16,
    _Float16* __restrict__ kvnA,
    const float* __restrict__ qg, const float* __restrict__ qb,
    const float* __restrict__ kg, const float* __restrict__ kb,
    _Float16* __restrict__ keff, _Float16* __restrict__ Cpe16)
{
  __shared__ float rs[4], rs2[4];
  int bid = blockIdx.x;
  const int tid = threadIdx.x;
  const int lane = tid & 63, w = tid >> 6;
  if (bid < 4096) {
    // q-row LN in place, L=1536, one half8 chunk per thread (tid<192)
    _Float16* x = ql16 + (size_t)bid * 1536;
    half8 v = {};
    float s = 0.f, s2 = 0.f;
    if (tid < 192) {
      v = *(const half8*)(x + tid * 8);
      #pragma unroll
      for (int u = 0; u < 8; ++u) { float fv = (float)v[u]; s += fv; s2 += fv * fv; }
    }
    #pragma unroll
    for (int off = 32; off; off >>= 1) {
      s  += __shfl_xor(s, off, 64);
      s2 += __shfl_xor(s2, off, 64);
    }
    if (lane == 0) { rs[w] = s; rs2[w] = s2; }
    __syncthreads();
    s  = rs[0] + rs[1] + rs[2] + rs[3];
    s2 = rs2[0] + rs2[1] + rs2[2] + rs2[3];
    float mean = s / 1536.f;
    float var = s2 / 1536.f - mean * mean;
    float inv = rsqrtf(var + 1e-5f);
    if (tid < 192) {
      float4 g0 = *(const float4*)(qg + tid * 8);
      float4 g1 = *(const float4*)(qg + tid * 8 + 4);
      float4 b0 = *(const float4*)(qb + tid * 8);
      float4 b1 = *(const float4*)(qb + tid * 8 + 4);
      float gg[8] = {g0.x, g0.y, g0.z, g0.w, g1.x, g1.y, g1.z, g1.w};
      float bb2[8] = {b0.x, b0.y, b0.z, b0.w, b1.x, b1.y, b1.z, b1.w};
      half8 o;
      #pragma unroll
      for (int u = 0; u < 8; ++u)
        o[u] = (_Float16)(((float)v[u] - mean) * inv * gg[u] + bb2[u]);
      *(half8*)(x + tid * 8) = o;
    }
    return;
  }
  bid -= 4096;
  if (bid < 1024) {
    // kv LN: one row per wave, 64 lanes x half8 = 512 elems
    const int row = bid * 4 + w;
    const _Float16* x = kvf16 + (size_t)row * 576;
    half8 v = *(const half8*)(x + lane * 8);
    float s = 0.f, s2 = 0.f;
    #pragma unroll
    for (int u = 0; u < 8; ++u) { float fv = (float)v[u]; s += fv; s2 += fv * fv; }
    #pragma unroll
    for (int off = 32; off; off >>= 1) {
      s  += __shfl_xor(s, off, 64);
      s2 += __shfl_xor(s2, off, 64);
    }
    float mean = s / 512.f;
    float var = s2 / 512.f - mean * mean;
    float inv = rsqrtf(var + 1e-5f);
    float4 g0 = *(const float4*)(kg + lane * 8);
    float4 g1 = *(const float4*)(kg + lane * 8 + 4);
    float4 b0 = *(const float4*)(kb + lane * 8);
    float4 b1 = *(const float4*)(kb + lane * 8 + 4);
    float gg[8] = {g0.x, g0.y, g0.z, g0.w, g1.x, g1.y, g1.z, g1.w};
    float bb2[8] = {b0.x, b0.y, b0.z, b0.w, b1.x, b1.y, b1.z, b1.w};
    half8 o;
    #pragma unroll
    for (int u = 0; u < 8; ++u)
      o[u] = (_Float16)(((float)v[u] - mean) * inv * gg[u] + bb2[u]);
    *(half8*)(kvnA + (size_t)row * 512 + lane * 8) = o;
    return;
  }
  bid -= 1024;
  if (bid < 512) {
    int u = bid * 4 + w;
    int t = u & (T_ - 1), b = u >> 10;
    const int srow = 2 * t + 1;
    const _Float16* p = kvf16 + ((size_t)(b * S_ + srow)) * 576 + C_;
    float o1 = 0.f, o2 = 0.f;
    if (lane < 32) {
      float invf = expf(-(float)lane * (LN1E4 / 32.f));
      float ang = (float)(S_ - 1 + srow) * invf;
      float sn, cs; sincosf(ang, &sn, &cs);
      float x1 = (float)p[2 * lane], x2 = (float)p[2 * lane + 1];
      o1 = x1 * cs - x2 * sn;
      o2 = x1 * sn + x2 * cs;
    }
    float ss = o1 * o1 + o2 * o2;
    #pragma unroll
    for (int off = 32; off; off >>= 1) ss += __shfl_xor(ss, off, 64);
    float nrm = fmaxf(sqrtf(ss), 1e-12f);
    if (lane < 32) {
      _Float16 h1 = (_Float16)(o1 / nrm), h2 = (_Float16)(o2 / nrm);
      #pragma unroll
      for (int h = 0; h < H_; ++h) {
        _Float16* o = keff + ((size_t)((b * H_ + h) * T_) + t) * 192 + NOPE_;
        o[2 * lane] = h1; o[2 * lane + 1] = h2;
      }
    }
    return;
  }
  bid -= 512;
  {
    const int t = bid;
    float dv = expf(-(float)(2 * tid) * (LN1E4 / 512.f));
    float ang = (float)t * dv;
    float sn, cs; sincosf(ang, &sn, &cs);
    Cpe16[(size_t)t * C_ + 2 * tid]     = (_Float16)sn;
    Cpe16[(size_t)t * C_ + 2 * tid + 1] = (_Float16)cs;
  }
}

// ------- fused rope_q + gate -------
__global__ __launch_bounds__(256) void fused_rq_gate(
    _Float16* __restrict__ qb16, const float* __restrict__ ps_ptr,
    const _Float16* __restrict__ Ccat, const _Float16* __restrict__ kvnA,
    _Float16* __restrict__ pkv16)
{
  int bid = blockIdx.x;
  const int tid = threadIdx.x;
  const int lane = tid & 63, w = tid >> 6;
  if (bid < 4096) {
    const int row = bid;
    const int s = row & (S_ - 1);
    float sn = 0.f, cs = 0.f;
    if (lane < 32) {
      float invf = expf(-(float)lane * (LN1E4 / 32.f));
      float ang = (float)(S_ - 1 + s) * invf;
      sincosf(ang, &sn, &cs);
    }
    const float psc = ps_ptr[0] * SCALE_;
    #pragma unroll
    for (int hh = 0; hh < 4; ++hh) {
      const int h = w + hh * 4;
      _Float16* p = qb16 + (size_t)row * 3072 + h * 192 + NOPE_;
      float o1 = 0.f, o2 = 0.f;
      if (lane < 32) {
        float x1 = (float)p[2 * lane], x2 = (float)p[2 * lane + 1];
        o1 = x1 * cs - x2 * sn;
        o2 = x1 * sn + x2 * cs;
      }
      float ss = o1 * o1 + o2 * o2;
      #pragma unroll
      for (int off = 32; off; off >>= 1) ss += __shfl_xor(ss, off, 64);
      float inv = psc / fmaxf(sqrtf(ss), 1e-12f);
      if (lane < 32) {
        p[2 * lane]     = (_Float16)(o1 * inv);
        p[2 * lane + 1] = (_Float16)(o2 * inv);
      }
    }
    return;
  }
  bid -= 4096;
  {
    int u = bid * 4 + w;
    int t = u & (T_ - 1), b = u >> 10;
    const int j = lane;
    const _Float16* c2 = Ccat + (size_t)t * 256;
    const _Float16* p0 = Ccat + (size_t)(1024 + b * S_ + 2 * t) * 256 + 128;
    const _Float16* p1 = p0 + 256;
    float d0 = (float)c2[j] * (float)p0[j] + (float)c2[j + 64] * (float)p0[j + 64];
    float d1 = (float)c2[j] * (float)p1[j] + (float)c2[j + 64] * (float)p1[j + 64];
    #pragma unroll
    for (int off = 32; off; off >>= 1) {
      d0 += __shfl_xor(d0, off, 64);
      d1 += __shfl_xor(d1, off, 64);
    }
    float w0 = 1.f / (1.f + expf(-d0));
    float w1 = 1.f / (1.f + expf(-d1));
    const _Float16* k0 = kvnA + ((size_t)(b * S_ + 2 * t)) * C_;
    const _Float16* k1 = k0 + C_;
    _Float16* o = pkv16 + ((size_t)(b * T_ + t)) * C_;
    #pragma unroll
    for (int it = 0; it < 2; ++it) {
      int c = j * 4 + it * 256;
      half4 a = *(const half4*)(k0 + c);
      half4 bb = *(const half4*)(k1 + c);
      half4 r;
      #pragma unroll
      for (int uu = 0; uu < 4; ++uu)
        r[uu] = (_Float16)(w0 * (float)a[uu] + w1 * (float)bb[uu]);
      *(half4*)(o + c) = r;
    }
  }
}

// ------- flash attention: double-buffered K/V LDS, ONE barrier per tile -------
__global__ __launch_bounds__(256, 2) void attn_flash(
    const _Float16* __restrict__ qb16, const _Float16* __restrict__ keff,
    const _Float16* __restrict__ vT, _Float16* __restrict__ x216)
{
  __shared__ __align__(16) _Float16 K_lds[2][64 * 192];  // 48 KB
  __shared__ __align__(16) _Float16 V_lds[2][128 * 64];  // 32 KB
  const int f = xcd_swizzle(blockIdx.x, 1024);
  const int st = f & 31, h = (f >> 5) & 15, b = f >> 9;
  const int tid = threadIdx.x, w = tid >> 6, lane = tid & 63;
  const int l15 = lane & 15, g = lane >> 4, l7 = lane & 7;
  const int rq = b * S_ + st * 64 + w * 16;
  const _Float16* qrow = qb16 + (size_t)(rq + l15) * 3072 + h * 192;
  half8 qB[6];
  #pragma unroll
  for (int kk = 0; kk < 6; ++kk) qB[kk] = *(const half8*)(qrow + kk * 32 + g * 8);
  floatx4 O[8];
  #pragma unroll
  for (int i = 0; i < 8; ++i) O[i] = (floatx4){0.f, 0.f, 0.f, 0.f};
  float m = -3e38f, l = 0.f;
  const _Float16* kb = keff + (size_t)(b * H_ + h) * T_ * 192;
  const _Float16* vb = vT   + (size_t)(b * H_ + h) * 128 * T_;

  int ksrc[6], ksw[6], vsrc[4], vsw[4];
  #pragma unroll
  for (int p = 0; p < 6; ++p) {
    int c = tid + p * 256;
    int r = c / 24, dc = c % 24;
    ksrc[p] = r * 192 + dc * 8;
    ksw[p]  = r * 192 + ((dc ^ (r & 7)) * 8);
  }
  #pragma unroll
  for (int p = 0; p < 4; ++p) {
    int c = tid + p * 256;
    int r = c >> 3, dc = c & 7;
    vsrc[p] = r * T_ + dc * 8;
    vsw[p]  = r * 64 + ((dc ^ (r & 7)) * 8);
  }
  int kswr[6], vswr[2];
  #pragma unroll
  for (int kk = 0; kk < 6; ++kk) kswr[kk] = ((kk * 4 + g) ^ l7) * 8;
  #pragma unroll
  for (int kc = 0; kc < 2; ++kc) vswr[kc] = ((kc * 4 + g) ^ l7) * 8;

  half8 kreg[6], vreg[4];
  #pragma unroll
  for (int p = 0; p < 6; ++p) kreg[p] = *(const half8*)(kb + ksrc[p]);
  #pragma unroll
  for (int p = 0; p < 4; ++p) vreg[p] = *(const half8*)(vb + vsrc[p]);
  #pragma unroll
  for (int p = 0; p < 6; ++p) *(half8*)&K_lds[0][ksw[p]] = kreg[p];
  #pragma unroll
  for (int p = 0; p < 4; ++p) *(half8*)&V_lds[0][vsw[p]] = vreg[p];
  __syncthreads();

  const int srcA = l15 + ((g & 1) << 5);
  const int srcB = srcA + 16;
  const bool hi = (g >> 1) != 0;

  int cur = 0;
  for (int kt = 0; kt < 16; ++kt) {
    if (kt < 15) {
      const int t1 = (kt + 1) * 64;
      #pragma unroll
      for (int p = 0; p < 6; ++p)
        kreg[p] = *(const half8*)(kb + (size_t)t1 * 192 + ksrc[p]);
      #pragma unroll
      for (int p = 0; p < 4; ++p)
        vreg[p] = *(const half8*)(vb + t1 + vsrc[p]);
    }
    floatx4 sc[4];
    #pragma unroll
    for (int i = 0; i < 4; ++i) sc[i] = (floatx4){0.f, 0.f, 0.f, 0.f};
    __builtin_amdgcn_s_setprio(1);
    #pragma unroll
    for (int kk = 0; kk < 6; ++kk)
      #pragma unroll
      for (int ct = 0; ct < 4; ++ct)
        sc[ct] = MFMA16(
            *(const half8*)&K_lds[cur][(ct * 16 + l15) * 192 + kswr[kk]],
            qB[kk], sc[ct]);
    __builtin_amdgcn_s_setprio(0);
    float pm = sc[0][0];
    #pragma unroll
    for (int ct = 0; ct < 4; ++ct)
      #pragma unroll
      for (int r = 0; r < 4; ++r) pm = fmaxf(pm, sc[ct][r]);
    pm = fmaxf(pm, __shfl_xor(pm, 16, 64));
    pm = fmaxf(pm, __shfl_xor(pm, 32, 64));
    int ok = pm <= m + 8.f;
    if (!__all(ok)) {
      float mn = fmaxf(m, pm);
      float sf = __expf(m - mn);
      m = mn; l *= sf;
      float sfO[4];
      #pragma unroll
      for (int r = 0; r < 4; ++r) sfO[r] = __shfl(sf, g * 4 + r, 64);
      #pragma unroll
      for (int cc = 0; cc < 8; ++cc) {
        O[cc][0] *= sfO[0]; O[cc][1] *= sfO[1];
        O[cc][2] *= sfO[2]; O[cc][3] *= sfO[3];
      }
    }
    float rs = 0.f;
    #pragma unroll
    for (int ct = 0; ct < 4; ++ct)
      #pragma unroll
      for (int r = 0; r < 4; ++r) {
        float e = __expf(sc[ct][r] - m);
        sc[ct][r] = e; rs += e;
      }
    rs += __shfl_xor(rs, 16, 64);
    rs += __shfl_xor(rs, 32, 64);
    l += rs;
    unsigned pk[4][2];
    #pragma unroll
    for (int ct = 0; ct < 4; ++ct) {
      union { fp16x2 h; unsigned u; } c0, c1;
      c0.h = __builtin_amdgcn_cvt_pkrtz(sc[ct][0], sc[ct][1]);
      c1.h = __builtin_amdgcn_cvt_pkrtz(sc[ct][2], sc[ct][3]);
      pk[ct][0] = c0.u; pk[ct][1] = c1.u;
    }
    __builtin_amdgcn_s_setprio(1);
    #pragma unroll
    for (int kc = 0; kc < 2; ++kc) {
      unsigned a0 = __shfl((int)pk[2 * kc][0], srcA, 64);
      unsigned b0 = __shfl((int)pk[2 * kc + 1][0], srcA, 64);
      unsigned a1 = __shfl((int)pk[2 * kc][1], srcA, 64);
      unsigned b1 = __shfl((int)pk[2 * kc + 1][1], srcA, 64);
      unsigned a2 = __shfl((int)pk[2 * kc][0], srcB, 64);
      unsigned b2 = __shfl((int)pk[2 * kc + 1][0], srcB, 64);
      unsigned a3 = __shfl((int)pk[2 * kc][1], srcB, 64);
      unsigned b3 = __shfl((int)pk[2 * kc + 1][1], srcB, 64);
      union { unsigned u[4]; half8 h; } pa;
      pa.u[0] = hi ? b0 : a0;
      pa.u[1] = hi ? b1 : a1;
      pa.u[2] = hi ? b2 : a2;
      pa.u[3] = hi ? b3 : a3;
      #pragma unroll
      for (int cc = 0; cc < 8; ++cc)
        O[cc] = MFMA16(pa.h,
            *(const half8*)&V_lds[cur][(cc * 16 + l15) * 64 + vswr[kc]], O[cc]);
    }
    __builtin_amdgcn_s_setprio(0);
    if (kt < 15) {
      #pragma unroll
      for (int p = 0; p < 6; ++p) *(half8*)&K_lds[cur ^ 1][ksw[p]] = kreg[p];
      #pragma unroll
      for (int p = 0; p < 4; ++p) *(half8*)&V_lds[cur ^ 1][vsw[p]] = vreg[p];
      __syncthreads();
      cur ^= 1;
    }
  }
  float il = 1.f / l;
  float ilO[4];
  #pragma unroll
  for (int r = 0; r < 4; ++r) ilO[r] = __shfl(il, g * 4 + r, 64);
  #pragma unroll
  for (int cc = 0; cc < 8; ++cc)
    #pragma unroll
    for (int r = 0; r < 4; ++r)
      x216[(size_t)(rq + g * 4 + r) * 2048 + h * 128 + cc * 16 + l15] =
          (_Float16)(O[cc][r] * ilO[r]);
}

extern "C" void kernel_launch(void* const* d_in, const int* in_sizes, int n_in,
                              void* d_out, int out_size, void* d_ws, size_t ws_size,
                              hipStream_t stream)
{
  (void)in_sizes; (void)n_in; (void)out_size; (void)ws_size;
  const float* query  = (const float*)d_in[0];
  const float* key    = (const float*)d_in[1];
  const float* wq_a   = (const float*)d_in[3];
  const float* q_ln_g = (const float*)d_in[4];
  const float* q_ln_b = (const float*)d_in[5];
  const float* wq_b   = (const float*)d_in[6];
  const float* wkv_a  = (const float*)d_in[7];
  const float* kv_ln_g= (const float*)d_in[8];
  const float* kv_ln_b= (const float*)d_in[9];
  const float* wkvb   = (const float*)d_in[10];
  const float* wo     = (const float*)d_in[11];
  const float* fc_c_w = (const float*)d_in[12];
  const float* fc_c_b = (const float*)d_in[13];
  const float* fc_p_w = (const float*)d_in[14];
  const float* fc_p_b = (const float*)d_in[15];
  const float* ps     = (const float*)d_in[16];
  float* out = (float*)d_out;

  const int M = B_ * S_; // 4096
  _Float16* hws   = (_Float16*)d_ws;
  _Float16* q16   = hws;                      // (-> Acat[Cpe|kvnA] -> x216)
  _Float16* key16 = q16   + (size_t)8388608;  // (-> keff)
  _Float16* wqa16 = key16 + (size_t)8388608;  // (-> Ccat)
  _Float16* wqb16 = wqa16 + (size_t)3145728;
  _Float16* wkva16= wqb16 + (size_t)4718592;  // (-> pkv16)
  _Float16* wo16  = wkva16+ (size_t)1179648;
  _Float16* ql16  = wo16  + (size_t)4194304;  // (-> vT)
  _Float16* qb16  = ql16  + (size_t)6291456;
  _Float16* kvf16 = qb16  + (size_t)12582912;
  _Float16* kvn16 = kvf16 + (size_t)2359296;
  _Float16* fcc16 = kvn16 + (size_t)2097152;
  _Float16* fcp16 = fcc16 + (size_t)65536;
  _Float16* W1c   = fcp16 + (size_t)65536;
  _Float16* W2c   = W1c   + (size_t)1048576;
  // aliases
  _Float16* x216  = q16;
  _Float16* keff  = key16;
  _Float16* Cpe16 = q16;
  _Float16* kvnA  = q16 + (size_t)524288;
  _Float16* Ccat  = wqa16;
  _Float16* pkv16 = wkva16;
  _Float16* vT    = ql16;

  // 1. conv part A (deps of the first GEMM only)
  conv_a<<<10304, 256, 0, stream>>>(query, key, wq_a, wkv_a,
                                    q16, key16, wqa16, wkva16);
  // 2. paired GEMM + deferred conversions
  {
    GTask ta = {q16,   wqa16,  ql16,  nullptr, nullptr, 12, QR_, E_, E_, E_, QR_};
    GTask tb = {key16, wkva16, kvf16, nullptr, nullptr, 5,  576, E_, E_, E_, 576};
    CTask tc = {wq_b, wo, fc_c_w, fc_p_w, wkvb,
                wqb16, wo16, fcc16, fcp16, W1c, W2c};
    gemm_pair<<<544 + 5440, 256, 0, stream>>>(ta, tb, tc, 384, 160);
  }
  // 3. fused LN(q) + LN(kv) + rope_k + PE (vectorized)
  fused_ln<<<6656, 256, 0, stream>>>(ql16, kvf16, kvnA, q_ln_g, q_ln_b,
                                     kv_ln_g, kv_ln_b, keff, Cpe16);
  // 4. paired GEMM: qb16 = ql16@wq_b^T || Ccat = Acat@[fcc;fcp]^T+bias
  {
    GTask ta = {ql16,  wqb16, qb16, nullptr, nullptr, 24, 3072, QR_, QR_, QR_, 3072};
    GTask tb = {Cpe16, fcc16, Ccat, fc_c_b,  fc_p_b,  2,  256,  C_,  C_,  C_,  256};
    CTask tc = {};
    gemm_pair<<<848, 256, 0, stream>>>(ta, tb, tc, 768, 80);
  }
  // 5. fused rope_q + gate
  fused_rq_gate<<<4608, 256, 0, stream>>>(qb16, ps, Ccat, kvnA, pkv16);
  // 6. merged prep: keff[:,0:128] = pkv@W1c^T || vT = (pkv@W2c^T)^T
  gemm16<true,false,false,false,true><<<dim3(1, T_/128, 64), 256, 0, stream>>>(
      pkv16, W1c, nullptr, (const float*)W2c, (float*)vT, keff,
      128, C_, C_, C_, 192, (long)T_*C_, 0L, 0L, 0L, 0L, 0L);
  // 7. flash attention (double-buffered, single barrier/tile) -> x216
  attn_flash<<<dim3(1024), 256, 0, stream>>>(qb16, keff, vT, x216);
  // 8. out = x216 @ wo16^T (fp32 out)
  gemm16<false,false,false,false><<<dim3(E_/128, M/128), 256, 0, stream>>>(
      x216, wo16, nullptr, nullptr, out, nullptr, E_, E_, E_, E_, E_, 0,0,0,0,0,0);
}